// Round 10
// baseline (572.873 us; speedup 1.0000x reference)
//
#include <hip/hip_runtime.h>

typedef unsigned short u16;
typedef __bf16 bf16x8 __attribute__((ext_vector_type(8)));
typedef u16 u16x8 __attribute__((ext_vector_type(8)));
typedef float f32x4 __attribute__((ext_vector_type(4)));

#define BSZ_ 2
#define NQ_ 128
#define LSEQ_ 2048
#define DM_ 256
#define DI_ 512
#define NH_ 8
#define HD_ 64
#define DKEY_ 1034
#define DCV_ 514
#define NCHUNK_ 16
#define CT_ 128   // chunk length

__device__ __forceinline__ float bf2f(u16 u) {
  unsigned v = ((unsigned)u) << 16;
  return __builtin_bit_cast(float, v);
}
__device__ __forceinline__ u16 f2bf(float f) {
  unsigned u = __builtin_bit_cast(unsigned, f);
  u += 0x7fffu + ((u >> 16) & 1u);
  return (u16)(u >> 16);
}
__device__ __forceinline__ float sigmoidf_(float x) { return 1.f / (1.f + expf(-x)); }
__device__ __forceinline__ float softplusf_(float x) {
  return (x > 20.f) ? x : log1pf(expf(x));
}

template<bool F32>
__device__ __forceinline__ float ldi(const void* p, size_t i) {
  return F32 ? ((const float*)p)[i] : bf2f(((const u16*)p)[i]);
}
template<bool F32>
__device__ __forceinline__ void sto(void* p, size_t i, float v) {
  if (F32) ((float*)p)[i] = v;
  else ((u16*)p)[i] = f2bf(v);
}

// per-wave dtype detection (all waves read same 64 u16s -> uniform result)
__device__ __forceinline__ bool detect_f32(const void* feat) {
  int lane = threadIdx.x & 63;
  float a = fabsf(bf2f(((const u16*)feat)[2*lane]));
  bool plaus = (a > 1e-6f) && (a < 1e6f);
  unsigned long long m = __ballot(plaus);
  return __popcll(m) < 32;   // true => fp32 storage
}

// ---------------- workspace layout (float units) ----------------
constexpr size_t SZ_KP    = (size_t)BSZ_*LSEQ_*DKEY_;
constexpr size_t SZ_XACT  = (size_t)BSZ_*LSEQ_*DCV_;
constexpr size_t SZ_AW    = (size_t)BSZ_*NH_*LSEQ_*NQ_*2;
constexpr size_t SZ_CARR  = (size_t)BSZ_*LSEQ_*NQ_;
constexpr size_t SZ_QPROJ = (size_t)BSZ_*NQ_*DI_;
constexpr size_t SZ_YACC  = (size_t)BSZ_*LSEQ_*DI_;
constexpr size_t SZ_SEND  = (size_t)BSZ_*NH_*2*NCHUNK_*NQ_*HD_;
constexpr size_t SZ_PTOT  = (size_t)BSZ_*NH_*2*NCHUNK_*NQ_;
constexpr size_t SZ_H0    = SZ_SEND;
constexpr size_t SZ_HB    = (size_t)BSZ_*NH_*2*NQ_*HD_;
constexpr size_t SZ_GBUF  = (size_t)BSZ_*LSEQ_*DI_/2;
constexpr size_t SZ_OUTQF = (size_t)BSZ_*NQ_*DM_;
constexpr size_t SZ_WPREP = 2048;

constexpr size_t OFF_KP    = 0;
constexpr size_t OFF_XACT  = OFF_KP + SZ_KP;
constexpr size_t OFF_AW    = OFF_XACT + SZ_XACT;
constexpr size_t OFF_CARR  = OFF_AW + SZ_AW;
constexpr size_t OFF_QPROJ = OFF_CARR + SZ_CARR;
constexpr size_t OFF_YACC  = OFF_QPROJ + SZ_QPROJ;
constexpr size_t OFF_SEND  = OFF_YACC + SZ_YACC;
constexpr size_t OFF_PTOT  = OFF_SEND + SZ_SEND;
constexpr size_t OFF_H0    = OFF_PTOT + SZ_PTOT;
constexpr size_t OFF_HB    = OFF_H0 + SZ_H0;
constexpr size_t OFF_GBUF  = OFF_HB + SZ_HB;
constexpr size_t OFF_OUTQF = OFF_GBUF + SZ_GBUF;
constexpr size_t OFF_WPREP = OFF_OUTQF + SZ_OUTQF;
constexpr size_t WS_FLOATS = OFF_WPREP + SZ_WPREP;

// FFN/outq scratch aliases into AW (dead after s3):
constexpr size_t OFF_UG  = OFF_AW;                         // 256x1024 bf16
constexpr size_t OFF_LNQ = OFF_UG + (size_t)256*1024/2;    // 256x512 bf16
constexpr size_t OFF_LNF = OFF_LNQ + (size_t)256*512/2;    // 256x256 bf16

// Transient bf16 cast buffers alias SEND (dead until s1 writes it):
constexpr size_t OFF_ABUF = OFF_SEND;                         // 4096x256 bf16
constexpr size_t OFF_AQ   = OFF_ABUF + (size_t)4096*256/2;
constexpr size_t OFF_BKEY = OFF_AQ + (size_t)256*256/2;
constexpr size_t OFF_BQ   = OFF_BKEY + (size_t)(256*1034+1)/2 + 1;
// Late bf16 weight casts alias SEND (dead after s2):
constexpr size_t OFF_BOK  = OFF_SEND;
constexpr size_t OFF_BOQ  = OFF_BOK + (size_t)512*256/2;
constexpr size_t OFF_B1W  = OFF_BOQ + (size_t)512*256/2;
constexpr size_t OFF_B2W  = OFF_B1W + (size_t)256*2048/2;

// wprep layout: [0..7] A=-exp(A_log); [8..15] dt_bias; [32..287] w1b; [288..1311] w2;
// [1312..1343] bc_proj; [1344..1471] dt_proj
template<bool F32>
__device__ void prep_body(const void* A_log, const void* dt_bias,
                          const void* w1, const void* b1, const void* w2,
                          const void* bcw, const void* dtw, float* wp) {
  int t = threadIdx.x;
  if (t < 8) {
    wp[t]     = -expf(ldi<F32>(A_log, t));
    wp[8 + t] = ldi<F32>(dt_bias, t);
  }
  if (t < 64) {
    wp[32 + t*4 + 0] = ldi<F32>(w1, 0*64 + t);
    wp[32 + t*4 + 1] = ldi<F32>(w1, 1*64 + t);
    wp[32 + t*4 + 2] = ldi<F32>(w1, 2*64 + t);
    wp[32 + t*4 + 3] = ldi<F32>(b1, t);
  }
  for (int i = t; i < 1024; i += 256) wp[288 + i] = ldi<F32>(w2, i);
  if (t < 32)  wp[1312 + t] = ldi<F32>(bcw, t);
  if (t < 128) wp[1344 + t] = ldi<F32>(dtw, t);
}

// cast helper: d[i] = bf16(s0[i] (+ s1_[i]))
__device__ __forceinline__ void cast_job(bool F32, const void* s0, const void* s1_,
                                         u16* d, size_t n, size_t base, size_t stride) {
  for (size_t i = base; i < n; i += stride) {
    float v = F32 ? ((const float*)s0)[i] : bf2f(((const u16*)s0)[i]);
    if (s1_) v += F32 ? ((const float*)s1_)[i] : bf2f(((const u16*)s1_)[i]);
    d[i] = f2bf(v);
  }
}

// ---------------- setup: yacc zero + cast0 + detect/prep (fused) ----------------
__global__ __launch_bounds__(256) void setup_kernel(
    const void* feat, const void* pe, u16* abuf,
    const void* q, const void* qp, u16* aq,
    const void* kw, u16* bkey, const void* qw, u16* bq,
    const void* A_log, const void* dt_bias, const void* w1, const void* b1,
    const void* w2, const void* bcw, const void* dtw, float* wp,
    float* yacc, int* flag)
{
  int bx = blockIdx.x, tid = threadIdx.x;
  if (bx < 512) {                       // yacc zero: 512 blocks x 4096 floats
    size_t base = (size_t)bx * 4096 + tid;
#pragma unroll
    for (int k = 0; k < 16; ++k) yacc[base + (size_t)k*256] = 0.f;
    return;
  }
  bool F32 = detect_f32(feat);
  if (bx < 1024) {                      // abuf = bf16(features + pos_embed)
    cast_job(F32, feat, pe, abuf, (size_t)4096*256,
             (size_t)(bx-512)*256 + tid, (size_t)512*256);
  } else if (bx < 1056) {               // aq = bf16(queries + query_pos)
    cast_job(F32, q, qp, aq, (size_t)256*256,
             (size_t)(bx-1024)*256 + tid, (size_t)32*256);
  } else if (bx < 1184) {               // bkey = bf16(key_proj_w)
    cast_job(F32, kw, nullptr, bkey, (size_t)256*1034,
             (size_t)(bx-1056)*256 + tid, (size_t)128*256);
  } else if (bx < 1248) {               // bq = bf16(query_proj_w)
    cast_job(F32, qw, nullptr, bq, (size_t)256*512,
             (size_t)(bx-1184)*256 + tid, (size_t)64*256);
  } else {                              // detect-store + prep
    if (tid == 0) *flag = F32 ? 1 : 0;
    if (F32) prep_body<true>(A_log, dt_bias, w1, b1, w2, bcw, dtw, wp);
    else     prep_body<false>(A_log, dt_bias, w1, b1, w2, bcw, dtw, wp);
  }
}

// ---------------- MFMA GEMM body (bm/bn parameterized) ----------------
template<int A_MODE, int B_MODE, int OUT_EXT, int RES_EXT, int RES_F32, int BIAS, bool F32>
__device__ void gemm_body(int bm, int bn,
                          const void* A0, const void* A1, const void* Bw,
                          float* Cf, void* Cext, const void* ResE,
                          const float* ResF, const void* Bias,
                          int M, int N, int K) {
  __shared__ u16 As[64][40];
  __shared__ u16 Bs[64][40];
  int tid = threadIdx.x;
  int w = tid >> 6, lane = tid & 63;
  f32x4 acc[4];
#pragma unroll
  for (int j = 0; j < 4; ++j) acc[j] = (f32x4){0.f, 0.f, 0.f, 0.f};

  int arow = tid >> 2, aseg = (tid & 3) * 8;
  int bkl = tid >> 3, bns = (tid & 7) * 8;

  for (int k0 = 0; k0 < K; k0 += 32) {
    {
      size_t abase = (size_t)(bm + arow) * K + k0 + aseg;
      u16x8 tv;
      if (A_MODE == 0) {
#pragma unroll
        for (int i = 0; i < 8; ++i)
          tv[i] = f2bf(ldi<F32>(A0, abase + i) + ldi<F32>(A1, abase + i));
      } else {
        const u16* pa = (const u16*)A0 + abase;
#pragma unroll
        for (int i = 0; i < 8; ++i) tv[i] = pa[i];
      }
      *(u16x8*)&As[arow][aseg] = tv;
    }
    {
      size_t bbase = (size_t)(k0 + bkl) * N + bn + bns;
#pragma unroll
      for (int i = 0; i < 8; ++i) {
        u16 v;
        if (bn + bns + i < N) {
          if (B_MODE == 1) v = ((const u16*)Bw)[bbase + i];
          else             v = f2bf(ldi<F32>(Bw, bbase + i));
        } else v = (u16)0;
        Bs[bns + i][bkl] = v;
      }
    }
    __syncthreads();
    int mrow = w * 16 + (lane & 15);
    int kq = (lane >> 4) * 8;
    bf16x8 af = __builtin_bit_cast(bf16x8, *(const u16x8*)&As[mrow][kq]);
#pragma unroll
    for (int j = 0; j < 4; ++j) {
      bf16x8 bfv = __builtin_bit_cast(bf16x8, *(const u16x8*)&Bs[j*16 + (lane & 15)][kq]);
      acc[j] = __builtin_amdgcn_mfma_f32_16x16x32_bf16(af, bfv, acc[j], 0, 0, 0);
    }
    __syncthreads();
  }
  int col0 = lane & 15, rbase = (lane >> 4) * 4;
#pragma unroll
  for (int j = 0; j < 4; ++j) {
#pragma unroll
    for (int r = 0; r < 4; ++r) {
      int row = bm + w * 16 + rbase + r;
      int col = bn + j * 16 + col0;
      if (col < N) {
        size_t idx = (size_t)row * N + col;
        float v = acc[j][r];
        if (BIAS)    v += ldi<F32>(Bias, col);
        if (RES_EXT) v += ldi<F32>(ResE, idx);
        if (RES_F32) v += ResF[idx];
        if (OUT_EXT) sto<F32>(Cext, idx, v);
        else         Cf[idx] = v;
      }
    }
  }
}

// kp = abuf @ bkey (all-internal bf16, fp32 out)
__global__ __launch_bounds__(256) void kp_gemm_kernel(
    const u16* abuf, const u16* bkey, float* kp) {
  gemm_body<1,1,0,0,0,0,false>(blockIdx.x*64, blockIdx.y*64, abuf, nullptr, bkey,
                               kp, nullptr, nullptr, nullptr, nullptr,
                               4096, DKEY_, DM_);
}

// fc2: out_q = outqf + ug @ b2w + b2
template<bool F32>
__device__ void fc2_body(const u16* ug, const u16* b2w, void* out_q,
                         const float* outqf, const void* b2) {
  gemm_body<1,1,1,0,1,1,F32>((blockIdx.x&3)*64, (blockIdx.x>>2)*64, ug, nullptr,
                             b2w, nullptr, out_q, nullptr, outqf, b2,
                             BSZ_*NQ_, DM_, 1024);
}
__global__ __launch_bounds__(256) void fc2_kernel(
    const int* fl, const u16* ug, const u16* b2w, void* out_q,
    const float* outqf, const void* b2) {
  if (*fl) fc2_body<true>(ug, b2w, out_q, outqf, b2);
  else     fc2_body<false>(ug, b2w, out_q, outqf, b2);
}

// ---------------- conv + qproj GEMM (fused, independent blocks) ----------------
template<bool F32>
__device__ void conv_body(const float* kp, const void* cw, const void* cb,
                          float* xact) {
  int row = blockIdx.x;
  int l = row & (LSEQ_ - 1);
  for (int ch = threadIdx.x; ch < DCV_; ch += 256) {
    float acc = ldi<F32>(cb, ch);
#pragma unroll
    for (int k = 0; k < 4; ++k) {
      int ll = l - 3 + k;
      if (ll >= 0)
        acc = fmaf(ldi<F32>(cw, ch*4 + k), kp[(size_t)(row - 3 + k)*DKEY_ + DI_ + ch], acc);
    }
    xact[(size_t)row*DCV_ + ch] = acc * sigmoidf_(acc);
  }
}
__global__ __launch_bounds__(256) void convqp_kernel(
    const int* fl, const float* kp, const void* cw, const void* cb, float* xact,
    const u16* aq, const u16* bq, float* qproj)
{
  int bx = blockIdx.x;
  if (bx < 4096) {
    if (*fl) conv_body<true>(kp, cw, cb, xact);
    else     conv_body<false>(kp, cw, cb, xact);
  } else {
    int i = bx - 4096;   // 32 blocks: M=256 (4 tiles) x N=512 (8 tiles)
    gemm_body<1,1,0,0,0,0,false>((i&3)*64, (i>>2)*64, aq, nullptr, bq,
                                 qproj, nullptr, nullptr, nullptr, nullptr,
                                 BSZ_*NQ_, DI_, DM_);
  }
}

// ---------------- dist MLP -> a, w, c ----------------
template<bool F32>
__device__ void dist_body(const void* anchors, const void* key_pos,
                          const float* kp, const float* xact, const float* wp,
                          float* aw, float* carr) {
  int tid = threadIdx.x;
  int n = tid & 127;
  int idx = blockIdx.x;
  int b = idx >> 10;
  int l = ((idx & 1023) << 1) | (tid >> 7);
  size_t row = (size_t)b * LSEQ_ + l;

  float enc0, enc1, enc2;
  {
    float e[3];
#pragma unroll
    for (int d = 0; d < 3; ++d) {
      float delta = ldi<F32>(anchors, (b*NQ_ + n)*3 + d) - ldi<F32>(key_pos, row*3 + d);
      float s = delta < 0.f ? -1.f : 1.f;
      e[d] = s * log2f(fabsf(delta) * 20.f + 1.f) * (1.f/12.f);
    }
    enc0 = e[0]; enc1 = e[1]; enc2 = e[2];
  }
  float feat[16];
#pragma unroll
  for (int f = 0; f < 16; ++f) feat[f] = 0.f;
  for (int j = 0; j < 64; ++j) {
    float w0 = wp[32 + j*4], w1v = wp[33 + j*4], w2v = wp[34 + j*4], bb = wp[35 + j*4];
    float hj = fmaxf(fmaf(enc0, w0, fmaf(enc1, w1v, fmaf(enc2, w2v, bb))), 0.f);
#pragma unroll
    for (int f = 0; f < 16; ++f) feat[f] = fmaf(hj, wp[288 + j*16 + f], feat[f]);
  }
  float bc0 = 0.f, bc1 = 0.f;
#pragma unroll
  for (int f = 0; f < 16; ++f) {
    bc0 = fmaf(feat[f], wp[1312 + f*2], bc0);
    bc1 = fmaf(feat[f], wp[1313 + f*2], bc1);
  }
  float bb_ = xact[row*DCV_ + DI_];
  float cb_ = xact[row*DCV_ + DI_ + 1];
  float Bs = bc0 + bb_, Cs = bc1 + cb_;
  carr[row*NQ_ + n] = Cs;

  float dtb[8];
#pragma unroll
  for (int h = 0; h < 8; ++h) dtb[h] = 0.f;
#pragma unroll
  for (int f = 0; f < 16; ++f)
#pragma unroll
    for (int h = 0; h < 8; ++h) dtb[h] = fmaf(feat[f], wp[1344 + f*8 + h], dtb[h]);

#pragma unroll
  for (int h = 0; h < 8; ++h) {
    float xln = dtb[h] + kp[row*DKEY_ + (DI_*2 + 2) + h] + wp[8 + h];
    float dtv = softplusf_(xln);
    float a = expf(dtv * wp[h]);
    float wv = dtv * Bs;
    size_t o = (((size_t)(b*NH_ + h)*LSEQ_ + l)*NQ_ + n)*2;
    aw[o] = a;
    aw[o + 1] = wv;
  }
}
__global__ __launch_bounds__(256) void dist_kernel(
    const int* fl, const void* anchors, const void* key_pos, const float* kp,
    const float* xact, const float* wp, float* aw, float* carr) {
  if (*fl) dist_body<true>(anchors, key_pos, kp, xact, wp, aw, carr);
  else     dist_body<false>(anchors, key_pos, kp, xact, wp, aw, carr);
}

// ---------------- scan phase 1 MERGED (R6-proven) ----------------
__global__ __launch_bounds__(256) void s1m_kernel(
    const float* __restrict__ aw, const float* __restrict__ xact,
    float* __restrict__ send, float* __restrict__ ptot)
{
  int tid = threadIdx.x;
  int hd = tid & 63;
  int w = __builtin_amdgcn_readfirstlane(tid >> 6);
  int ns = blockIdx.x, q = blockIdx.y, z = blockIdx.z;
  int h = z & 7, b = z >> 3;
  int n0 = __builtin_amdgcn_readfirstlane(ns*32 + w*8);

  float hf[8], hb[8], pr[8];
#pragma unroll
  for (int i = 0; i < 8; ++i) { hf[i] = 0.f; hb[i] = 0.f; pr[i] = 1.f; }

  size_t awbase = (size_t)z * LSEQ_ * (NQ_*2);
  int t = q*CT_;
  for (int s = 0; s < CT_; ++s, ++t) {
    const float* awt = aw + awbase + (size_t)t*(NQ_*2) + n0*2;
    float xv = xact[((size_t)(b*LSEQ_ + t))*DCV_ + (h << 6) + hd];
#pragma unroll
    for (int i = 0; i < 8; ++i) {
      float a = awt[2*i], wv = awt[2*i + 1];
      float wx = wv * xv;
      hf[i] = fmaf(hf[i], a, wx);
      hb[i] = fmaf(pr[i], wx, hb[i]);
      pr[i] *= a;
    }
  }
  size_t cbf = (size_t)((z*2 + 0)*NCHUNK_ + q);
  size_t cbb = (size_t)((z*2 + 1)*NCHUNK_ + (NCHUNK_ - 1 - q));
#pragma unroll
  for (int i = 0; i < 8; ++i) {
    send[cbf*(NQ_*HD_) + (size_t)(n0 + i)*HD_ + hd] = hf[i];
    send[cbb*(NQ_*HD_) + (size_t)(n0 + i)*HD_ + hd] = hb[i];
  }
  if (hd == 0) {
#pragma unroll
    for (int i = 0; i < 8; ++i) {
      ptot[cbf*NQ_ + n0 + i] = pr[i];
      ptot[cbb*NQ_ + n0 + i] = pr[i];
    }
  }
}

// ---------------- scan phase 2 ----------------
__global__ __launch_bounds__(256) void s2_kernel(
    const float* __restrict__ qproj, const float* __restrict__ ptot,
    const float* __restrict__ send, float* __restrict__ h0buf,
    float* __restrict__ hbuf)
{
  int g = blockIdx.x*256 + threadIdx.x;
  int hd = g & 63;
  int n = (g >> 6) & 127;
  int dir = (g >> 13) & 1;
  int h = (g >> 14) & 7;
  int b = g >> 17;
  float hcur = qproj[((size_t)(b*NQ_ + n))*DI_ + h*HD_ + hd];
  size_t base = (size_t)((b*NH_ + h)*2 + dir) * NCHUNK_;
  for (int q = 0; q < NCHUNK_; ++q) {
    size_t cb = base + q;
    h0buf[cb*(NQ_*HD_) + (size_t)n*HD_ + hd] = hcur;
    hcur = fmaf(hcur, ptot[cb*NQ_ + n], send[cb*(NQ_*HD_) + (size_t)n*HD_ + hd]);
  }
  hbuf[((size_t)((b*NH_ + h)*2 + dir))*(NQ_*HD_) + (size_t)n*HD_ + hd] = hcur;
}

// ---------------- scan phase 3: R6 structure, barrier/LDS deleted ----------
// Each wave computes its partial ys over its 8 n's and atomically adds it
// directly to yacc (no cross-wave LDS reduction, no __syncthreads).
// cast1 blocks appended (same fusion as R9).
template<bool F32>
__device__ void cast1_part(const void* okw, u16* bok, const void* oqw, u16* boq,
                           const void* w1, u16* b1w, const void* w2, u16* b2w) {
  int i = blockIdx.x - 2048;
  int job = i >> 7, bj = i & 127;
  size_t base = (size_t)bj*256 + threadIdx.x, stride = (size_t)128*256;
  switch (job) {
    case 0: cast_job(F32, okw, nullptr, bok, (size_t)512*256, base, stride); break;
    case 1: cast_job(F32, oqw, nullptr, boq, (size_t)512*256, base, stride); break;
    case 2: cast_job(F32, w1, nullptr, b1w, (size_t)256*2048, base, stride); break;
    default: cast_job(F32, w2, nullptr, b2w, (size_t)1024*256, base, stride); break;
  }
}
__global__ __launch_bounds__(256) void s3cast_kernel(
    const int* fl, const float* __restrict__ aw, const float* __restrict__ carr,
    const float* __restrict__ xact, const float* __restrict__ h0buf,
    float* __restrict__ yacc,
    const void* okw, u16* bok, const void* oqw, u16* boq,
    const void* w1, u16* b1w, const void* w2, u16* b2w)
{
  int bx = blockIdx.x;
  if (bx >= 2048) {
    if (*fl) cast1_part<true>(okw, bok, oqw, boq, w1, b1w, w2, b2w);
    else     cast1_part<false>(okw, bok, oqw, boq, w1, b1w, w2, b2w);
    return;
  }
  int tid = threadIdx.x;
  int hd = tid & 63;
  int w = __builtin_amdgcn_readfirstlane(tid >> 6);
  int ns = bx & 3, q = (bx >> 2) & 15, zz = bx >> 6;
  int dir = zz & 1, h = (zz >> 1) & 7, b = zz >> 4;
  int n0 = __builtin_amdgcn_readfirstlane(ns*32 + w*8);

  float hst[8];
  size_t cb = (size_t)(((b*NH_ + h)*2 + dir)*NCHUNK_ + q);
#pragma unroll
  for (int i = 0; i < 8; ++i)
    hst[i] = h0buf[cb*(NQ_*HD_) + (size_t)(n0 + i)*HD_ + hd];

  size_t awbase = (size_t)(b*NH_ + h) * LSEQ_ * (NQ_*2);
  int tbase = dir ? (LSEQ_ - 1 - q*CT_) : (q*CT_);
  int tstep = dir ? -1 : 1;
  int t = tbase;
  for (int s = 0; s < CT_; ++s, t += tstep) {
    const float* awt = aw + awbase + (size_t)t*(NQ_*2) + n0*2;
    const float* ct = carr + ((size_t)(b*LSEQ_ + t))*NQ_ + n0;
    float xv = xact[((size_t)(b*LSEQ_ + t))*DCV_ + (h << 6) + hd];
    float ys = 0.f;
#pragma unroll
    for (int i = 0; i < 8; ++i) {
      hst[i] = fmaf(hst[i], awt[2*i], awt[2*i + 1] * xv);
      ys = fmaf(hst[i], ct[i], ys);
    }
    atomicAdd(&yacc[((size_t)(b*LSEQ_ + t))*DI_ + (h << 6) + hd], 0.5f * ys);
  }
}

// ---------------- block reduction helper ----------------
__device__ __forceinline__ float block_sum256(float v, float* red) {
#pragma unroll
  for (int off = 32; off; off >>= 1) v += __shfl_xor(v, off, 64);
  int wv = threadIdx.x >> 6;
  if ((threadIdx.x & 63) == 0) red[wv] = v;
  __syncthreads();
  float t = red[0] + red[1] + red[2] + red[3];
  __syncthreads();
  return t;
}

// ---------------- g (gated RMSNorm) + lnq (fused) ----------------
template<bool F32>
__device__ void g_body(const float* yacc, const float* xact, const float* kp,
                       const void* Dv, const void* knw, u16* gbuf) {
  int row = blockIdx.x, tid = threadIdx.x;
  __shared__ float red[4];
  float gg[2];
  float ss = 0.f;
#pragma unroll
  for (int ii = 0; ii < 2; ++ii) {
    int ch = tid + ii*256;
    float yv = yacc[(size_t)row*DI_ + ch];
    float xv = xact[(size_t)row*DCV_ + ch];
    float zv = kp[(size_t)row*DKEY_ + ch];
    float Dh = ldi<F32>(Dv, ch >> 6);
    float yf = yv + 2.f * Dh * xv;
    float g = yf * (zv * sigmoidf_(zv));
    gg[ii] = g;
    ss += g * g;
  }
  float tot = block_sum256(ss, red);
  float r = rsqrtf(tot / (float)DI_ + 1e-5f);
#pragma unroll
  for (int ii = 0; ii < 2; ++ii) {
    int ch = tid + ii*256;
    gbuf[(size_t)row*DI_ + ch] = f2bf(gg[ii] * r * ldi<F32>(knw, ch));
  }
}
template<bool F32>
__device__ void lnq_body(const float* hbuf, const void* qnw, const void* qnb,
                         u16* lnq) {
  int row = blockIdx.x - 4096;
  int b = row >> 7, n = row & 127;
  int tid = threadIdx.x;
  __shared__ float red[4];
  float hv[2];
  float s1 = 0.f, s2 = 0.f;
#pragma unroll
  for (int ii = 0; ii < 2; ++ii) {
    int ch = tid + ii*256;
    int h = ch >> 6, hd = ch & 63;
    size_t base = ((size_t)((b*NH_ + h)*2))*(NQ_*HD_) + (size_t)n*HD_ + hd;
    float v = 0.5f * (hbuf[base] + hbuf[base + (size_t)NQ_*HD_]);
    hv[ii] = v;
    s1 += v;
    s2 += v * v;
  }
  s1 = block_sum256(s1, red);
  s2 = block_sum256(s2, red);
  float mean = s1 / (float)DI_;
  float var = fmaxf(s2 / (float)DI_ - mean * mean, 0.f);
  float rstd = rsqrtf(var + 1e-5f);
#pragma unroll
  for (int ii = 0; ii < 2; ++ii) {
    int ch = tid + ii*256;
    lnq[(size_t)row*DI_ + ch] =
        f2bf((hv[ii] - mean) * rstd * ldi<F32>(qnw, ch) + ldi<F32>(qnb, ch));
  }
}
__global__ __launch_bounds__(256) void glnq_kernel(
    const int* fl, const float* yacc, const float* xact, const float* kp,
    const void* Dv, const void* knw, u16* gbuf,
    const float* hbuf, const void* qnw, const void* qnb, u16* lnq)
{
  if (blockIdx.x < 4096) {
    if (*fl) g_body<true>(yacc, xact, kp, Dv, knw, gbuf);
    else     g_body<false>(yacc, xact, kp, Dv, knw, gbuf);
  } else {
    if (*fl) lnq_body<true>(hbuf, qnw, qnb, lnq);
    else     lnq_body<false>(hbuf, qnw, qnb, lnq);
  }
}

// ---------------- out_feat GEMM + outq GEMM (fused) ----------------
template<bool F32>
__device__ void ofoq_body(const u16* gbuf, const u16* bok, void* out_feat,
                          const void* features, const u16* lnq, const u16* boq,
                          float* outqf, const void* queries) {
  int bx = blockIdx.x;
  if (bx < 256) {   // out_feat: M=4096 (64 tiles) x N=256 (4 tiles), K=512
    gemm_body<1,1,1,1,0,0,F32>((bx>>2)*64, (bx&3)*64, gbuf, nullptr, bok,
                               nullptr, out_feat, features, nullptr, nullptr,
                               4096, DM_, DI_);
  } else {          // outq: M=256 (4) x N=256 (4), K=512
    int i = bx - 256;
    gemm_body<1,1,0,1,0,0,F32>((i&3)*64, (i>>2)*64, lnq, nullptr, boq,
                               outqf, nullptr, queries, nullptr, nullptr,
                               BSZ_*NQ_, DM_, DI_);
  }
}
__global__ __launch_bounds__(256) void ofoq_kernel(
    const int* fl, const u16* gbuf, const u16* bok,
    void* out_feat_f32, void* out_feat_bf16, const void* features,
    const u16* lnq, const u16* boq, float* outqf, const void* queries) {
  if (*fl) ofoq_body<true>(gbuf, bok, out_feat_f32, features, lnq, boq, outqf, queries);
  else     ofoq_body<false>(gbuf, bok, out_feat_bf16, features, lnq, boq, outqf, queries);
}

// ---------------- FFN LN -> lnf ----------------
template<bool F32>
__device__ void lnf_body(const float* outqf, const void* fnw, const void* fnb,
                         u16* lnf) {
  int row = blockIdx.x, tid = threadIdx.x;
  __shared__ float red[4];
  float x = outqf[(size_t)row*DM_ + tid];
  float s1 = block_sum256(x, red);
  float s2 = block_sum256(x * x, red);
  float mean = s1 / (float)DM_;
  float var = fmaxf(s2 / (float)DM_ - mean * mean, 0.f);
  float rstd = rsqrtf(var + 1e-5f);
  lnf[(size_t)row*DM_ + tid] =
      f2bf((x - mean) * rstd * ldi<F32>(fnw, tid) + ldi<F32>(fnb, tid));
}
__global__ __launch_bounds__(256) void lnf_kernel(
    const int* fl, const float* outqf, const void* fnw, const void* fnb, u16* lnf) {
  if (*fl) lnf_body<true>(outqf, fnw, fnb, lnf);
  else     lnf_body<false>(outqf, fnw, fnb, lnf);
}

// ---------------- fc1 + gelu fused: ug = gelu(lnf@W1a + b1a) * (lnf@W1v + b1v) ----
template<bool F32>
__device__ void fc1g_body(const u16* lnf, const u16* b1w, const void* b1, u16* ug) {
  __shared__ u16 As[64][40];
  __shared__ u16 BsA[64][40];
  __shared__ u16 BsV[64][40];
  int tid = threadIdx.x;
  int w = tid >> 6, lane = tid & 63;
  int bm = blockIdx.x * 64, bn = blockIdx.y * 64;   // bn in [0,1024)
  f32x4 accA[4], accV[4];
#pragma unroll
  for (int j = 0; j < 4; ++j) {
    accA[j] = (f32x4){0.f, 0.f, 0.f, 0.f};
    accV[j] = (f32x4){0.f, 0.f, 0.f, 0.f};
  }
  int arow = tid >> 2, aseg = (tid & 3) * 8;
  int bkl = tid >> 3, bns = (tid & 7) * 8;

  for (int k0 = 0; k0 < DM_; k0 += 32) {
    {
      size_t abase = (size_t)(bm + arow) * DM_ + k0 + aseg;
      const u16* pa = lnf + abase;
      u16x8 tv;
#pragma unroll
      for (int i = 0; i < 8; ++i) tv[i] = pa[i];
      *(u16x8*)&As[arow][aseg] = tv;
    }
    {
      size_t bbase = (size_t)(k0 + bkl) * 2048 + bn + bns;
#pragma unroll
      for (int i = 0; i < 8; ++i) {
        BsA[bns + i][bkl] = b1w[bbase + i];
        BsV[bns + i][bkl] = b1w[bbase + 1024 + i];
      }
    }
    __syncthreads();
    int mrow = w * 16 + (lane & 15);
    int kq = (lane >> 4) * 8;
    bf16x8 af = __builtin_bit_cast(bf16x8, *(const u16x8*)&As[mrow][kq]);
#pragma unroll
    for (int j = 0; j < 4; ++j) {
      bf16x8 ba = __builtin_bit_cast(bf16x8, *(const u16x8*)&BsA[j*16 + (lane & 15)][kq]);
      bf16x8 bv = __builtin_bit_cast(bf16x8, *(const u16x8*)&BsV[j*16 + (lane & 15)][kq]);
      accA[j] = __builtin_amdgcn_mfma_f32_16x16x32_bf16(af, ba, accA[j], 0, 0, 0);
      accV[j] = __builtin_amdgcn_mfma_f32_16x16x32_bf16(af, bv, accV[j], 0, 0, 0);
    }
    __syncthreads();
  }
  int col0 = lane & 15, rbase = (lane >> 4) * 4;
#pragma unroll
  for (int j = 0; j < 4; ++j) {
#pragma unroll
    for (int r = 0; r < 4; ++r) {
      int row = bm + w * 16 + rbase + r;
      int col = bn + j * 16 + col0;
      float a = accA[j][r] + ldi<F32>(b1, col);
      float v = accV[j][r] + ldi<F32>(b1, col + 1024);
      float ge = 0.5f * a * (1.f + erff(a * 0.70710678118f));
      ug[(size_t)row*1024 + col] = f2bf(ge * v);
    }
  }
}
__global__ __launch_bounds__(256) void fc1g_kernel(
    const int* fl, const u16* lnf, const u16* b1w, const void* b1, u16* ug) {
  if (*fl) fc1g_body<true>(lnf, b1w, b1, ug);
  else     fc1g_body<false>(lnf, b1w, b1, ug);
}

// ---------------- launch ----------------
extern "C" void kernel_launch(void* const* d_in, const int* in_sizes, int n_in,
                              void* d_out, int out_size, void* d_ws, size_t ws_size,
                              hipStream_t stream) {
  const void* queries        = d_in[0];
  const void* anchors        = d_in[1];
  const void* features       = d_in[2];
  const void* pos_embed      = d_in[3];
  const void* key_pos        = d_in[4];
  const void* query_pos      = d_in[5];
  const void* key_proj_w     = d_in[6];
  const void* key_conv_w     = d_in[7];
  const void* key_conv_b     = d_in[8];
  const void* query_proj_w   = d_in[9];
  const void* dist_w1        = d_in[10];
  const void* dist_b1        = d_in[11];
  const void* dist_w2        = d_in[12];
  const void* bc_proj_w      = d_in[13];
  const void* dt_proj_w      = d_in[14];
  const void* dt_bias        = d_in[15];
  const void* A_log          = d_in[16];
  const void* Dvec           = d_in[17];
  const void* key_norm_w     = d_in[18];
  const void* out_key_proj_w = d_in[19];
  const void* query_norm_w   = d_in[20];
  const void* query_norm_b   = d_in[21];
  const void* out_query_proj_w = d_in[22];
  const void* ffn_norm_w     = d_in[23];
  const void* ffn_norm_b     = d_in[24];
  const void* ffn_fc1_w      = d_in[25];
  const void* ffn_fc1_b      = d_in[26];
  const void* ffn_fc2_w      = d_in[27];
  const void* ffn_fc2_b      = d_in[28];

  if (ws_size < WS_FLOATS * sizeof(float)) return;

  float* ws    = (float*)d_ws;
  float* kp    = ws + OFF_KP;
  float* xact  = ws + OFF_XACT;
  float* aw    = ws + OFF_AW;
  float* carr  = ws + OFF_CARR;
  float* qproj = ws + OFF_QPROJ;
  float* yacc  = ws + OFF_YACC;
  float* send  = ws + OFF_SEND;
  float* ptot  = ws + OFF_PTOT;
  float* h0buf = ws + OFF_H0;
  float* hbuf  = ws + OFF_HB;
  u16*   gbuf  = (u16*)(ws + OFF_GBUF);
  float* outqf = ws + OFF_OUTQF;
  float* wprep = ws + OFF_WPREP;
  int*   flag  = (int*)(wprep + 1536);
  u16*   ugbuf = (u16*)(ws + OFF_UG);
  u16*   lnq   = (u16*)(ws + OFF_LNQ);
  u16*   lnf   = (u16*)(ws + OFF_LNF);
  u16*   abuf  = (u16*)(ws + OFF_ABUF);
  u16*   aq    = (u16*)(ws + OFF_AQ);
  u16*   bkey  = (u16*)(ws + OFF_BKEY);
  u16*   bq    = (u16*)(ws + OFF_BQ);
  u16*   bok   = (u16*)(ws + OFF_BOK);
  u16*   boq   = (u16*)(ws + OFF_BOQ);
  u16*   b1w   = (u16*)(ws + OFF_B1W);
  u16*   b2w   = (u16*)(ws + OFF_B2W);

  void* out_q = d_out;
  void* out_feat_bf16 = (void*)((u16*)d_out + (size_t)BSZ_*NQ_*DM_);
  void* out_feat_f32  = (void*)((float*)d_out + (size_t)BSZ_*NQ_*DM_);

  // 1. setup: yacc zero + cast0 + detect/prep
  setup_kernel<<<1249, 256, 0, stream>>>(
      features, pos_embed, abuf, queries, query_pos, aq,
      key_proj_w, bkey, query_proj_w, bq,
      A_log, dt_bias, dist_w1, dist_b1, dist_w2, bc_proj_w, dt_proj_w, wprep,
      yacc, flag);

  // 2. kp = abuf @ bkey : (4096 x 1034), K=256
  kp_gemm_kernel<<<dim3(64, 17), 256, 0, stream>>>(abuf, bkey, kp);

  // 3. conv + qproj GEMM
  convqp_kernel<<<4096 + 32, 256, 0, stream>>>(
      flag, kp, key_conv_w, key_conv_b, xact, aq, bq, qproj);

  // 4. dist
  dist_kernel<<<BSZ_*LSEQ_/2, 256, 0, stream>>>(flag, anchors, key_pos, kp, xact,
                                                wprep, aw, carr);

  // 5. s1 merged
  s1m_kernel<<<dim3(4, NCHUNK_, BSZ_*NH_), 256, 0, stream>>>(aw, xact, send, ptot);

  // 6. s2
  s2_kernel<<<1024, 256, 0, stream>>>(qproj, ptot, send, h0buf, hbuf);

  // 7. s3 (barrier-free per-wave atomics) + cast1
  s3cast_kernel<<<2048 + 512, 256, 0, stream>>>(
      flag, aw, carr, xact, h0buf, yacc,
      out_key_proj_w, bok, out_query_proj_w, boq, ffn_fc1_w, b1w, ffn_fc2_w, b2w);

  // 8. g + lnq
  glnq_kernel<<<4096 + 256, 256, 0, stream>>>(
      flag, yacc, xact, kp, Dvec, key_norm_w, gbuf,
      hbuf, query_norm_w, query_norm_b, lnq);

  // 9. out_feat GEMM + outq GEMM
  ofoq_kernel<<<256 + 16, 256, 0, stream>>>(
      flag, gbuf, bok, out_feat_f32, out_feat_bf16, features,
      lnq, boq, outqf, queries);

  // 10. lnf
  lnf_kernel<<<BSZ_*NQ_, 256, 0, stream>>>(flag, outqf, ffn_norm_w, ffn_norm_b, lnf);

  // 11. fc1 + gelu fused: ug = gelu(a)*v
  fc1g_kernel<<<dim3(4, 16), 256, 0, stream>>>(flag, lnf, b1w, ffn_fc1_b, ugbuf);

  // 12. fc2: out_q = outqf + ug @ b2w + b2
  fc2_kernel<<<16, 256, 0, stream>>>(flag, ugbuf, b2w, out_q, outqf, ffn_fc2_b);
}

// Round 11
// 463.115 us; speedup vs baseline: 1.2370x; 1.2370x over previous
//
#include <hip/hip_runtime.h>

typedef unsigned short u16;
typedef __bf16 bf16x8 __attribute__((ext_vector_type(8)));
typedef u16 u16x8 __attribute__((ext_vector_type(8)));
typedef float f32x4 __attribute__((ext_vector_type(4)));

#define BSZ_ 2
#define NQ_ 128
#define LSEQ_ 2048
#define DM_ 256
#define DI_ 512
#define NH_ 8
#define HD_ 64
#define DKEY_ 1034
#define DCV_ 514
#define NCHUNK_ 16
#define CT_ 128   // chunk length

__device__ __forceinline__ float bf2f(u16 u) {
  unsigned v = ((unsigned)u) << 16;
  return __builtin_bit_cast(float, v);
}
__device__ __forceinline__ u16 f2bf(float f) {
  unsigned u = __builtin_bit_cast(unsigned, f);
  u += 0x7fffu + ((u >> 16) & 1u);
  return (u16)(u >> 16);
}
__device__ __forceinline__ float sigmoidf_(float x) { return 1.f / (1.f + expf(-x)); }
__device__ __forceinline__ float softplusf_(float x) {
  return (x > 20.f) ? x : log1pf(expf(x));
}

template<bool F32>
__device__ __forceinline__ float ldi(const void* p, size_t i) {
  return F32 ? ((const float*)p)[i] : bf2f(((const u16*)p)[i]);
}
template<bool F32>
__device__ __forceinline__ void sto(void* p, size_t i, float v) {
  if (F32) ((float*)p)[i] = v;
  else ((u16*)p)[i] = f2bf(v);
}

// per-wave dtype detection (all waves read same 64 u16s -> uniform result)
__device__ __forceinline__ bool detect_f32(const void* feat) {
  int lane = threadIdx.x & 63;
  float a = fabsf(bf2f(((const u16*)feat)[2*lane]));
  bool plaus = (a > 1e-6f) && (a < 1e6f);
  unsigned long long m = __ballot(plaus);
  return __popcll(m) < 32;   // true => fp32 storage
}

// ---------------- workspace layout (float units) ----------------
constexpr size_t SZ_KP    = (size_t)BSZ_*LSEQ_*DKEY_;
constexpr size_t SZ_XACT  = (size_t)BSZ_*LSEQ_*DCV_;
constexpr size_t SZ_AW    = (size_t)BSZ_*NH_*LSEQ_*NQ_*2;
constexpr size_t SZ_CARR  = (size_t)BSZ_*LSEQ_*NQ_;
constexpr size_t SZ_QPROJ = (size_t)BSZ_*NQ_*DI_;
constexpr size_t SZ_YACC  = (size_t)BSZ_*LSEQ_*DI_;
constexpr size_t SZ_SEND  = (size_t)BSZ_*NH_*2*NCHUNK_*NQ_*HD_;
constexpr size_t SZ_PTOT  = (size_t)BSZ_*NH_*2*NCHUNK_*NQ_;
constexpr size_t SZ_H0    = SZ_SEND;
constexpr size_t SZ_HB    = (size_t)BSZ_*NH_*2*NQ_*HD_;
constexpr size_t SZ_GBUF  = (size_t)BSZ_*LSEQ_*DI_/2;
constexpr size_t SZ_OUTQF = (size_t)BSZ_*NQ_*DM_;
constexpr size_t SZ_WPREP = 2048;

constexpr size_t OFF_KP    = 0;
constexpr size_t OFF_XACT  = OFF_KP + SZ_KP;
constexpr size_t OFF_AW    = OFF_XACT + SZ_XACT;
constexpr size_t OFF_CARR  = OFF_AW + SZ_AW;
constexpr size_t OFF_QPROJ = OFF_CARR + SZ_CARR;
constexpr size_t OFF_YACC  = OFF_QPROJ + SZ_QPROJ;
constexpr size_t OFF_SEND  = OFF_YACC + SZ_YACC;
constexpr size_t OFF_PTOT  = OFF_SEND + SZ_SEND;
constexpr size_t OFF_H0    = OFF_PTOT + SZ_PTOT;
constexpr size_t OFF_HB    = OFF_H0 + SZ_H0;
constexpr size_t OFF_GBUF  = OFF_HB + SZ_HB;
constexpr size_t OFF_OUTQF = OFF_GBUF + SZ_GBUF;
constexpr size_t OFF_WPREP = OFF_OUTQF + SZ_OUTQF;
constexpr size_t WS_FLOATS = OFF_WPREP + SZ_WPREP;

// FFN/outq scratch aliases into AW (dead after s3):
constexpr size_t OFF_UG  = OFF_AW;                         // 256x1024 bf16
constexpr size_t OFF_LNQ = OFF_UG + (size_t)256*1024/2;    // 256x512 bf16
constexpr size_t OFF_LNF = OFF_LNQ + (size_t)256*512/2;    // 256x256 bf16

// Transient bf16 cast buffers alias SEND (dead until s1 writes it):
constexpr size_t OFF_ABUF = OFF_SEND;                         // 4096x256 bf16
constexpr size_t OFF_AQ   = OFF_ABUF + (size_t)4096*256/2;
constexpr size_t OFF_BKEY = OFF_AQ + (size_t)256*256/2;
constexpr size_t OFF_BQ   = OFF_BKEY + (size_t)(256*1034+1)/2 + 1;
// Late bf16 weight casts alias SEND (dead after s2):
constexpr size_t OFF_BOK  = OFF_SEND;
constexpr size_t OFF_BOQ  = OFF_BOK + (size_t)512*256/2;
constexpr size_t OFF_B1W  = OFF_BOQ + (size_t)512*256/2;
constexpr size_t OFF_B2W  = OFF_B1W + (size_t)256*2048/2;

// wprep layout: [0..7] A=-exp(A_log); [8..15] dt_bias; [32..287] w1b; [288..1311] w2;
// [1312..1343] bc_proj; [1344..1471] dt_proj
template<bool F32>
__device__ void prep_body(const void* A_log, const void* dt_bias,
                          const void* w1, const void* b1, const void* w2,
                          const void* bcw, const void* dtw, float* wp) {
  int t = threadIdx.x;
  if (t < 8) {
    wp[t]     = -expf(ldi<F32>(A_log, t));
    wp[8 + t] = ldi<F32>(dt_bias, t);
  }
  if (t < 64) {
    wp[32 + t*4 + 0] = ldi<F32>(w1, 0*64 + t);
    wp[32 + t*4 + 1] = ldi<F32>(w1, 1*64 + t);
    wp[32 + t*4 + 2] = ldi<F32>(w1, 2*64 + t);
    wp[32 + t*4 + 3] = ldi<F32>(b1, t);
  }
  for (int i = t; i < 1024; i += 256) wp[288 + i] = ldi<F32>(w2, i);
  if (t < 32)  wp[1312 + t] = ldi<F32>(bcw, t);
  if (t < 128) wp[1344 + t] = ldi<F32>(dtw, t);
}

// cast helper: d[i] = bf16(s0[i] (+ s1_[i]))
__device__ __forceinline__ void cast_job(bool F32, const void* s0, const void* s1_,
                                         u16* d, size_t n, size_t base, size_t stride) {
  for (size_t i = base; i < n; i += stride) {
    float v = F32 ? ((const float*)s0)[i] : bf2f(((const u16*)s0)[i]);
    if (s1_) v += F32 ? ((const float*)s1_)[i] : bf2f(((const u16*)s1_)[i]);
    d[i] = f2bf(v);
  }
}

// ---------------- setup: yacc zero + cast0 + detect/prep (fused) ----------------
__global__ __launch_bounds__(256) void setup_kernel(
    const void* feat, const void* pe, u16* abuf,
    const void* q, const void* qp, u16* aq,
    const void* kw, u16* bkey, const void* qw, u16* bq,
    const void* A_log, const void* dt_bias, const void* w1, const void* b1,
    const void* w2, const void* bcw, const void* dtw, float* wp,
    float* yacc, int* flag)
{
  int bx = blockIdx.x, tid = threadIdx.x;
  if (bx < 512) {                       // yacc zero: 512 blocks x 4096 floats
    size_t base = (size_t)bx * 4096 + tid;
#pragma unroll
    for (int k = 0; k < 16; ++k) yacc[base + (size_t)k*256] = 0.f;
    return;
  }
  bool F32 = detect_f32(feat);
  if (bx < 1024) {                      // abuf = bf16(features + pos_embed)
    cast_job(F32, feat, pe, abuf, (size_t)4096*256,
             (size_t)(bx-512)*256 + tid, (size_t)512*256);
  } else if (bx < 1056) {               // aq = bf16(queries + query_pos)
    cast_job(F32, q, qp, aq, (size_t)256*256,
             (size_t)(bx-1024)*256 + tid, (size_t)32*256);
  } else if (bx < 1184) {               // bkey = bf16(key_proj_w)
    cast_job(F32, kw, nullptr, bkey, (size_t)256*1034,
             (size_t)(bx-1056)*256 + tid, (size_t)128*256);
  } else if (bx < 1248) {               // bq = bf16(query_proj_w)
    cast_job(F32, qw, nullptr, bq, (size_t)256*512,
             (size_t)(bx-1184)*256 + tid, (size_t)64*256);
  } else {                              // detect-store + prep
    if (tid == 0) *flag = F32 ? 1 : 0;
    if (F32) prep_body<true>(A_log, dt_bias, w1, b1, w2, bcw, dtw, wp);
    else     prep_body<false>(A_log, dt_bias, w1, b1, w2, bcw, dtw, wp);
  }
}

// ---------------- MFMA GEMM body (bm/bn parameterized) ----------------
template<int A_MODE, int B_MODE, int OUT_EXT, int RES_EXT, int RES_F32, int BIAS, bool F32>
__device__ void gemm_body(int bm, int bn,
                          const void* A0, const void* A1, const void* Bw,
                          float* Cf, void* Cext, const void* ResE,
                          const float* ResF, const void* Bias,
                          int M, int N, int K) {
  __shared__ u16 As[64][40];
  __shared__ u16 Bs[64][40];
  int tid = threadIdx.x;
  int w = tid >> 6, lane = tid & 63;
  f32x4 acc[4];
#pragma unroll
  for (int j = 0; j < 4; ++j) acc[j] = (f32x4){0.f, 0.f, 0.f, 0.f};

  int arow = tid >> 2, aseg = (tid & 3) * 8;
  int bkl = tid >> 3, bns = (tid & 7) * 8;

  for (int k0 = 0; k0 < K; k0 += 32) {
    {
      size_t abase = (size_t)(bm + arow) * K + k0 + aseg;
      u16x8 tv;
      if (A_MODE == 0) {
#pragma unroll
        for (int i = 0; i < 8; ++i)
          tv[i] = f2bf(ldi<F32>(A0, abase + i) + ldi<F32>(A1, abase + i));
      } else {
        const u16* pa = (const u16*)A0 + abase;
#pragma unroll
        for (int i = 0; i < 8; ++i) tv[i] = pa[i];
      }
      *(u16x8*)&As[arow][aseg] = tv;
    }
    {
      size_t bbase = (size_t)(k0 + bkl) * N + bn + bns;
#pragma unroll
      for (int i = 0; i < 8; ++i) {
        u16 v;
        if (bn + bns + i < N) {
          if (B_MODE == 1) v = ((const u16*)Bw)[bbase + i];
          else             v = f2bf(ldi<F32>(Bw, bbase + i));
        } else v = (u16)0;
        Bs[bns + i][bkl] = v;
      }
    }
    __syncthreads();
    int mrow = w * 16 + (lane & 15);
    int kq = (lane >> 4) * 8;
    bf16x8 af = __builtin_bit_cast(bf16x8, *(const u16x8*)&As[mrow][kq]);
#pragma unroll
    for (int j = 0; j < 4; ++j) {
      bf16x8 bfv = __builtin_bit_cast(bf16x8, *(const u16x8*)&Bs[j*16 + (lane & 15)][kq]);
      acc[j] = __builtin_amdgcn_mfma_f32_16x16x32_bf16(af, bfv, acc[j], 0, 0, 0);
    }
    __syncthreads();
  }
  int col0 = lane & 15, rbase = (lane >> 4) * 4;
#pragma unroll
  for (int j = 0; j < 4; ++j) {
#pragma unroll
    for (int r = 0; r < 4; ++r) {
      int row = bm + w * 16 + rbase + r;
      int col = bn + j * 16 + col0;
      if (col < N) {
        size_t idx = (size_t)row * N + col;
        float v = acc[j][r];
        if (BIAS)    v += ldi<F32>(Bias, col);
        if (RES_EXT) v += ldi<F32>(ResE, idx);
        if (RES_F32) v += ResF[idx];
        if (OUT_EXT) sto<F32>(Cext, idx, v);
        else         Cf[idx] = v;
      }
    }
  }
}

// kp = abuf @ bkey (all-internal bf16, fp32 out)
__global__ __launch_bounds__(256) void kp_gemm_kernel(
    const u16* abuf, const u16* bkey, float* kp) {
  gemm_body<1,1,0,0,0,0,false>(blockIdx.x*64, blockIdx.y*64, abuf, nullptr, bkey,
                               kp, nullptr, nullptr, nullptr, nullptr,
                               4096, DKEY_, DM_);
}

// fc2: out_q = outqf + ug @ b2w + b2
template<bool F32>
__device__ void fc2_body(const u16* ug, const u16* b2w, void* out_q,
                         const float* outqf, const void* b2) {
  gemm_body<1,1,1,0,1,1,F32>((blockIdx.x&3)*64, (blockIdx.x>>2)*64, ug, nullptr,
                             b2w, nullptr, out_q, nullptr, outqf, b2,
                             BSZ_*NQ_, DM_, 1024);
}
__global__ __launch_bounds__(256) void fc2_kernel(
    const int* fl, const u16* ug, const u16* b2w, void* out_q,
    const float* outqf, const void* b2) {
  if (*fl) fc2_body<true>(ug, b2w, out_q, outqf, b2);
  else     fc2_body<false>(ug, b2w, out_q, outqf, b2);
}

// ---------------- conv + qproj GEMM (fused, independent blocks) ----------------
template<bool F32>
__device__ void conv_body(const float* kp, const void* cw, const void* cb,
                          float* xact) {
  int row = blockIdx.x;
  int l = row & (LSEQ_ - 1);
  for (int ch = threadIdx.x; ch < DCV_; ch += 256) {
    float acc = ldi<F32>(cb, ch);
#pragma unroll
    for (int k = 0; k < 4; ++k) {
      int ll = l - 3 + k;
      if (ll >= 0)
        acc = fmaf(ldi<F32>(cw, ch*4 + k), kp[(size_t)(row - 3 + k)*DKEY_ + DI_ + ch], acc);
    }
    xact[(size_t)row*DCV_ + ch] = acc * sigmoidf_(acc);
  }
}
__global__ __launch_bounds__(256) void convqp_kernel(
    const int* fl, const float* kp, const void* cw, const void* cb, float* xact,
    const u16* aq, const u16* bq, float* qproj)
{
  int bx = blockIdx.x;
  if (bx < 4096) {
    if (*fl) conv_body<true>(kp, cw, cb, xact);
    else     conv_body<false>(kp, cw, cb, xact);
  } else {
    int i = bx - 4096;   // 32 blocks: M=256 (4 tiles) x N=512 (8 tiles)
    gemm_body<1,1,0,0,0,0,false>((i&3)*64, (i>>2)*64, aq, nullptr, bq,
                                 qproj, nullptr, nullptr, nullptr, nullptr,
                                 BSZ_*NQ_, DI_, DM_);
  }
}

// ---------------- dist MLP -> a, w, c ----------------
template<bool F32>
__device__ void dist_body(const void* anchors, const void* key_pos,
                          const float* kp, const float* xact, const float* wp,
                          float* aw, float* carr) {
  int tid = threadIdx.x;
  int n = tid & 127;
  int idx = blockIdx.x;
  int b = idx >> 10;
  int l = ((idx & 1023) << 1) | (tid >> 7);
  size_t row = (size_t)b * LSEQ_ + l;

  float enc0, enc1, enc2;
  {
    float e[3];
#pragma unroll
    for (int d = 0; d < 3; ++d) {
      float delta = ldi<F32>(anchors, (b*NQ_ + n)*3 + d) - ldi<F32>(key_pos, row*3 + d);
      float s = delta < 0.f ? -1.f : 1.f;
      e[d] = s * log2f(fabsf(delta) * 20.f + 1.f) * (1.f/12.f);
    }
    enc0 = e[0]; enc1 = e[1]; enc2 = e[2];
  }
  float feat[16];
#pragma unroll
  for (int f = 0; f < 16; ++f) feat[f] = 0.f;
  for (int j = 0; j < 64; ++j) {
    float w0 = wp[32 + j*4], w1v = wp[33 + j*4], w2v = wp[34 + j*4], bb = wp[35 + j*4];
    float hj = fmaxf(fmaf(enc0, w0, fmaf(enc1, w1v, fmaf(enc2, w2v, bb))), 0.f);
#pragma unroll
    for (int f = 0; f < 16; ++f) feat[f] = fmaf(hj, wp[288 + j*16 + f], feat[f]);
  }
  float bc0 = 0.f, bc1 = 0.f;
#pragma unroll
  for (int f = 0; f < 16; ++f) {
    bc0 = fmaf(feat[f], wp[1312 + f*2], bc0);
    bc1 = fmaf(feat[f], wp[1313 + f*2], bc1);
  }
  float bb_ = xact[row*DCV_ + DI_];
  float cb_ = xact[row*DCV_ + DI_ + 1];
  float Bs = bc0 + bb_, Cs = bc1 + cb_;
  carr[row*NQ_ + n] = Cs;

  float dtb[8];
#pragma unroll
  for (int h = 0; h < 8; ++h) dtb[h] = 0.f;
#pragma unroll
  for (int f = 0; f < 16; ++f)
#pragma unroll
    for (int h = 0; h < 8; ++h) dtb[h] = fmaf(feat[f], wp[1344 + f*8 + h], dtb[h]);

#pragma unroll
  for (int h = 0; h < 8; ++h) {
    float xln = dtb[h] + kp[row*DKEY_ + (DI_*2 + 2) + h] + wp[8 + h];
    float dtv = softplusf_(xln);
    float a = expf(dtv * wp[h]);
    float wv = dtv * Bs;
    size_t o = (((size_t)(b*NH_ + h)*LSEQ_ + l)*NQ_ + n)*2;
    aw[o] = a;
    aw[o + 1] = wv;
  }
}
__global__ __launch_bounds__(256) void dist_kernel(
    const int* fl, const void* anchors, const void* key_pos, const float* kp,
    const float* xact, const float* wp, float* aw, float* carr) {
  if (*fl) dist_body<true>(anchors, key_pos, kp, xact, wp, aw, carr);
  else     dist_body<false>(anchors, key_pos, kp, xact, wp, aw, carr);
}

// ---------------- scan phase 1 MERGED (R6-proven) ----------------
__global__ __launch_bounds__(256) void s1m_kernel(
    const float* __restrict__ aw, const float* __restrict__ xact,
    float* __restrict__ send, float* __restrict__ ptot)
{
  int tid = threadIdx.x;
  int hd = tid & 63;
  int w = __builtin_amdgcn_readfirstlane(tid >> 6);
  int ns = blockIdx.x, q = blockIdx.y, z = blockIdx.z;
  int h = z & 7, b = z >> 3;
  int n0 = __builtin_amdgcn_readfirstlane(ns*32 + w*8);

  float hf[8], hb[8], pr[8];
#pragma unroll
  for (int i = 0; i < 8; ++i) { hf[i] = 0.f; hb[i] = 0.f; pr[i] = 1.f; }

  size_t awbase = (size_t)z * LSEQ_ * (NQ_*2);
  int t = q*CT_;
  for (int s = 0; s < CT_; ++s, ++t) {
    const float* awt = aw + awbase + (size_t)t*(NQ_*2) + n0*2;
    float xv = xact[((size_t)(b*LSEQ_ + t))*DCV_ + (h << 6) + hd];
#pragma unroll
    for (int i = 0; i < 8; ++i) {
      float a = awt[2*i], wv = awt[2*i + 1];
      float wx = wv * xv;
      hf[i] = fmaf(hf[i], a, wx);
      hb[i] = fmaf(pr[i], wx, hb[i]);
      pr[i] *= a;
    }
  }
  size_t cbf = (size_t)((z*2 + 0)*NCHUNK_ + q);
  size_t cbb = (size_t)((z*2 + 1)*NCHUNK_ + (NCHUNK_ - 1 - q));
#pragma unroll
  for (int i = 0; i < 8; ++i) {
    send[cbf*(NQ_*HD_) + (size_t)(n0 + i)*HD_ + hd] = hf[i];
    send[cbb*(NQ_*HD_) + (size_t)(n0 + i)*HD_ + hd] = hb[i];
  }
  if (hd == 0) {
#pragma unroll
    for (int i = 0; i < 8; ++i) {
      ptot[cbf*NQ_ + n0 + i] = pr[i];
      ptot[cbb*NQ_ + n0 + i] = pr[i];
    }
  }
}

// ---------------- scan phase 2 ----------------
__global__ __launch_bounds__(256) void s2_kernel(
    const float* __restrict__ qproj, const float* __restrict__ ptot,
    const float* __restrict__ send, float* __restrict__ h0buf,
    float* __restrict__ hbuf)
{
  int g = blockIdx.x*256 + threadIdx.x;
  int hd = g & 63;
  int n = (g >> 6) & 127;
  int dir = (g >> 13) & 1;
  int h = (g >> 14) & 7;
  int b = g >> 17;
  float hcur = qproj[((size_t)(b*NQ_ + n))*DI_ + h*HD_ + hd];
  size_t base = (size_t)((b*NH_ + h)*2 + dir) * NCHUNK_;
  for (int q = 0; q < NCHUNK_; ++q) {
    size_t cb = base + q;
    h0buf[cb*(NQ_*HD_) + (size_t)n*HD_ + hd] = hcur;
    hcur = fmaf(hcur, ptot[cb*NQ_ + n], send[cb*(NQ_*HD_) + (size_t)n*HD_ + hd]);
  }
  hbuf[((size_t)((b*NH_ + h)*2 + dir))*(NQ_*HD_) + (size_t)n*HD_ + hd] = hcur;
}

// ---------------- scan phase 3: R9 scalar-load loop, barrier per 8 t ----------
// Waves write per-t partials to ybuf[8][4][64]; one barrier per 8-t group,
// cooperative flush (256 threads cover 8x64, 1 atomic each x2), barrier, next.
// cast1 blocks appended (same fusion as R9).
template<bool F32>
__device__ void cast1_part(const void* okw, u16* bok, const void* oqw, u16* boq,
                           const void* w1, u16* b1w, const void* w2, u16* b2w) {
  int i = blockIdx.x - 2048;
  int job = i >> 7, bj = i & 127;
  size_t base = (size_t)bj*256 + threadIdx.x, stride = (size_t)128*256;
  switch (job) {
    case 0: cast_job(F32, okw, nullptr, bok, (size_t)512*256, base, stride); break;
    case 1: cast_job(F32, oqw, nullptr, boq, (size_t)512*256, base, stride); break;
    case 2: cast_job(F32, w1, nullptr, b1w, (size_t)256*2048, base, stride); break;
    default: cast_job(F32, w2, nullptr, b2w, (size_t)1024*256, base, stride); break;
  }
}
__global__ __launch_bounds__(256) void s3cast_kernel(
    const int* fl, const float* __restrict__ aw, const float* __restrict__ carr,
    const float* __restrict__ xact, const float* __restrict__ h0buf,
    float* __restrict__ yacc,
    const void* okw, u16* bok, const void* oqw, u16* boq,
    const void* w1, u16* b1w, const void* w2, u16* b2w)
{
  int bx = blockIdx.x;
  if (bx >= 2048) {
    if (*fl) cast1_part<true>(okw, bok, oqw, boq, w1, b1w, w2, b2w);
    else     cast1_part<false>(okw, bok, oqw, boq, w1, b1w, w2, b2w);
    return;
  }
  __shared__ float ybuf[8][4][64];   // 8 KB
  int tid = threadIdx.x;
  int hd = tid & 63;
  int w = __builtin_amdgcn_readfirstlane(tid >> 6);
  int ns = bx & 3, q = (bx >> 2) & 15, zz = bx >> 6;
  int dir = zz & 1, h = (zz >> 1) & 7, b = zz >> 4;
  int n0 = __builtin_amdgcn_readfirstlane(ns*32 + w*8);

  float hst[8];
  size_t cb = (size_t)(((b*NH_ + h)*2 + dir)*NCHUNK_ + q);
#pragma unroll
  for (int i = 0; i < 8; ++i)
    hst[i] = h0buf[cb*(NQ_*HD_) + (size_t)(n0 + i)*HD_ + hd];

  size_t awbase = (size_t)(b*NH_ + h) * LSEQ_ * (NQ_*2);
  int tbase = dir ? (LSEQ_ - 1 - q*CT_) : (q*CT_);
  int tstep = dir ? -1 : 1;

  for (int g0 = 0; g0 < CT_; g0 += 8) {
#pragma unroll
    for (int s8 = 0; s8 < 8; ++s8) {
      int t = tbase + tstep * (g0 + s8);
      const float* awt = aw + awbase + (size_t)t*(NQ_*2) + n0*2;
      const float* ct = carr + ((size_t)(b*LSEQ_ + t))*NQ_ + n0;
      float xv = xact[((size_t)(b*LSEQ_ + t))*DCV_ + (h << 6) + hd];
      float ys = 0.f;
#pragma unroll
      for (int i = 0; i < 8; ++i) {
        hst[i] = fmaf(hst[i], awt[2*i], awt[2*i + 1] * xv);
        ys = fmaf(hst[i], ct[i], ys);
      }
      ybuf[s8][w][hd] = ys;
    }
    __syncthreads();
#pragma unroll
    for (int rep = 0; rep < 2; ++rep) {
      int s8 = (tid >> 6) + rep*4;
      int tt = tbase + tstep * (g0 + s8);
      float yv = ybuf[s8][0][hd] + ybuf[s8][1][hd] +
                 ybuf[s8][2][hd] + ybuf[s8][3][hd];
      atomicAdd(&yacc[((size_t)(b*LSEQ_ + tt))*DI_ + (h << 6) + hd], 0.5f * yv);
    }
    __syncthreads();
  }
}

// ---------------- block reduction helper ----------------
__device__ __forceinline__ float block_sum256(float v, float* red) {
#pragma unroll
  for (int off = 32; off; off >>= 1) v += __shfl_xor(v, off, 64);
  int wv = threadIdx.x >> 6;
  if ((threadIdx.x & 63) == 0) red[wv] = v;
  __syncthreads();
  float t = red[0] + red[1] + red[2] + red[3];
  __syncthreads();
  return t;
}

// ---------------- g (gated RMSNorm) + lnq (fused) ----------------
template<bool F32>
__device__ void g_body(const float* yacc, const float* xact, const float* kp,
                       const void* Dv, const void* knw, u16* gbuf) {
  int row = blockIdx.x, tid = threadIdx.x;
  __shared__ float red[4];
  float gg[2];
  float ss = 0.f;
#pragma unroll
  for (int ii = 0; ii < 2; ++ii) {
    int ch = tid + ii*256;
    float yv = yacc[(size_t)row*DI_ + ch];
    float xv = xact[(size_t)row*DCV_ + ch];
    float zv = kp[(size_t)row*DKEY_ + ch];
    float Dh = ldi<F32>(Dv, ch >> 6);
    float yf = yv + 2.f * Dh * xv;
    float g = yf * (zv * sigmoidf_(zv));
    gg[ii] = g;
    ss += g * g;
  }
  float tot = block_sum256(ss, red);
  float r = rsqrtf(tot / (float)DI_ + 1e-5f);
#pragma unroll
  for (int ii = 0; ii < 2; ++ii) {
    int ch = tid + ii*256;
    gbuf[(size_t)row*DI_ + ch] = f2bf(gg[ii] * r * ldi<F32>(knw, ch));
  }
}
template<bool F32>
__device__ void lnq_body(const float* hbuf, const void* qnw, const void* qnb,
                         u16* lnq) {
  int row = blockIdx.x - 4096;
  int b = row >> 7, n = row & 127;
  int tid = threadIdx.x;
  __shared__ float red[4];
  float hv[2];
  float s1 = 0.f, s2 = 0.f;
#pragma unroll
  for (int ii = 0; ii < 2; ++ii) {
    int ch = tid + ii*256;
    int h = ch >> 6, hd = ch & 63;
    size_t base = ((size_t)((b*NH_ + h)*2))*(NQ_*HD_) + (size_t)n*HD_ + hd;
    float v = 0.5f * (hbuf[base] + hbuf[base + (size_t)NQ_*HD_]);
    hv[ii] = v;
    s1 += v;
    s2 += v * v;
  }
  s1 = block_sum256(s1, red);
  s2 = block_sum256(s2, red);
  float mean = s1 / (float)DI_;
  float var = fmaxf(s2 / (float)DI_ - mean * mean, 0.f);
  float rstd = rsqrtf(var + 1e-5f);
#pragma unroll
  for (int ii = 0; ii < 2; ++ii) {
    int ch = tid + ii*256;
    lnq[(size_t)row*DI_ + ch] =
        f2bf((hv[ii] - mean) * rstd * ldi<F32>(qnw, ch) + ldi<F32>(qnb, ch));
  }
}
__global__ __launch_bounds__(256) void glnq_kernel(
    const int* fl, const float* yacc, const float* xact, const float* kp,
    const void* Dv, const void* knw, u16* gbuf,
    const float* hbuf, const void* qnw, const void* qnb, u16* lnq)
{
  if (blockIdx.x < 4096) {
    if (*fl) g_body<true>(yacc, xact, kp, Dv, knw, gbuf);
    else     g_body<false>(yacc, xact, kp, Dv, knw, gbuf);
  } else {
    if (*fl) lnq_body<true>(hbuf, qnw, qnb, lnq);
    else     lnq_body<false>(hbuf, qnw, qnb, lnq);
  }
}

// ---------------- out_feat GEMM + outq GEMM (fused) ----------------
template<bool F32>
__device__ void ofoq_body(const u16* gbuf, const u16* bok, void* out_feat,
                          const void* features, const u16* lnq, const u16* boq,
                          float* outqf, const void* queries) {
  int bx = blockIdx.x;
  if (bx < 256) {   // out_feat: M=4096 (64 tiles) x N=256 (4 tiles), K=512
    gemm_body<1,1,1,1,0,0,F32>((bx>>2)*64, (bx&3)*64, gbuf, nullptr, bok,
                               nullptr, out_feat, features, nullptr, nullptr,
                               4096, DM_, DI_);
  } else {          // outq: M=256 (4) x N=256 (4), K=512
    int i = bx - 256;
    gemm_body<1,1,0,1,0,0,F32>((i&3)*64, (i>>2)*64, lnq, nullptr, boq,
                               outqf, nullptr, queries, nullptr, nullptr,
                               BSZ_*NQ_, DM_, DI_);
  }
}
__global__ __launch_bounds__(256) void ofoq_kernel(
    const int* fl, const u16* gbuf, const u16* bok,
    void* out_feat_f32, void* out_feat_bf16, const void* features,
    const u16* lnq, const u16* boq, float* outqf, const void* queries) {
  if (*fl) ofoq_body<true>(gbuf, bok, out_feat_f32, features, lnq, boq, outqf, queries);
  else     ofoq_body<false>(gbuf, bok, out_feat_bf16, features, lnq, boq, outqf, queries);
}

// ---------------- FFN LN -> lnf ----------------
template<bool F32>
__device__ void lnf_body(const float* outqf, const void* fnw, const void* fnb,
                         u16* lnf) {
  int row = blockIdx.x, tid = threadIdx.x;
  __shared__ float red[4];
  float x = outqf[(size_t)row*DM_ + tid];
  float s1 = block_sum256(x, red);
  float s2 = block_sum256(x * x, red);
  float mean = s1 / (float)DM_;
  float var = fmaxf(s2 / (float)DM_ - mean * mean, 0.f);
  float rstd = rsqrtf(var + 1e-5f);
  lnf[(size_t)row*DM_ + tid] =
      f2bf((x - mean) * rstd * ldi<F32>(fnw, tid) + ldi<F32>(fnb, tid));
}
__global__ __launch_bounds__(256) void lnf_kernel(
    const int* fl, const float* outqf, const void* fnw, const void* fnb, u16* lnf) {
  if (*fl) lnf_body<true>(outqf, fnw, fnb, lnf);
  else     lnf_body<false>(outqf, fnw, fnb, lnf);
}

// ---------------- fc1 + gelu fused: ug = gelu(lnf@W1a + b1a) * (lnf@W1v + b1v) ----
template<bool F32>
__device__ void fc1g_body(const u16* lnf, const u16* b1w, const void* b1, u16* ug) {
  __shared__ u16 As[64][40];
  __shared__ u16 BsA[64][40];
  __shared__ u16 BsV[64][40];
  int tid = threadIdx.x;
  int w = tid >> 6, lane = tid & 63;
  int bm = blockIdx.x * 64, bn = blockIdx.y * 64;   // bn in [0,1024)
  f32x4 accA[4], accV[4];
#pragma unroll
  for (int j = 0; j < 4; ++j) {
    accA[j] = (f32x4){0.f, 0.f, 0.f, 0.f};
    accV[j] = (f32x4){0.f, 0.f, 0.f, 0.f};
  }
  int arow = tid >> 2, aseg = (tid & 3) * 8;
  int bkl = tid >> 3, bns = (tid & 7) * 8;

  for (int k0 = 0; k0 < DM_; k0 += 32) {
    {
      size_t abase = (size_t)(bm + arow) * DM_ + k0 + aseg;
      const u16* pa = lnf + abase;
      u16x8 tv;
#pragma unroll
      for (int i = 0; i < 8; ++i) tv[i] = pa[i];
      *(u16x8*)&As[arow][aseg] = tv;
    }
    {
      size_t bbase = (size_t)(k0 + bkl) * 2048 + bn + bns;
#pragma unroll
      for (int i = 0; i < 8; ++i) {
        BsA[bns + i][bkl] = b1w[bbase + i];
        BsV[bns + i][bkl] = b1w[bbase + 1024 + i];
      }
    }
    __syncthreads();
    int mrow = w * 16 + (lane & 15);
    int kq = (lane >> 4) * 8;
    bf16x8 af = __builtin_bit_cast(bf16x8, *(const u16x8*)&As[mrow][kq]);
#pragma unroll
    for (int j = 0; j < 4; ++j) {
      bf16x8 ba = __builtin_bit_cast(bf16x8, *(const u16x8*)&BsA[j*16 + (lane & 15)][kq]);
      bf16x8 bv = __builtin_bit_cast(bf16x8, *(const u16x8*)&BsV[j*16 + (lane & 15)][kq]);
      accA[j] = __builtin_amdgcn_mfma_f32_16x16x32_bf16(af, ba, accA[j], 0, 0, 0);
      accV[j] = __builtin_amdgcn_mfma_f32_16x16x32_bf16(af, bv, accV[j], 0, 0, 0);
    }
    __syncthreads();
  }
  int col0 = lane & 15, rbase = (lane >> 4) * 4;
#pragma unroll
  for (int j = 0; j < 4; ++j) {
#pragma unroll
    for (int r = 0; r < 4; ++r) {
      int row = bm + w * 16 + rbase + r;
      int col = bn + j * 16 + col0;
      float a = accA[j][r] + ldi<F32>(b1, col);
      float v = accV[j][r] + ldi<F32>(b1, col + 1024);
      float ge = 0.5f * a * (1.f + erff(a * 0.70710678118f));
      ug[(size_t)row*1024 + col] = f2bf(ge * v);
    }
  }
}
__global__ __launch_bounds__(256) void fc1g_kernel(
    const int* fl, const u16* lnf, const u16* b1w, const void* b1, u16* ug) {
  if (*fl) fc1g_body<true>(lnf, b1w, b1, ug);
  else     fc1g_body<false>(lnf, b1w, b1, ug);
}

// ---------------- launch ----------------
extern "C" void kernel_launch(void* const* d_in, const int* in_sizes, int n_in,
                              void* d_out, int out_size, void* d_ws, size_t ws_size,
                              hipStream_t stream) {
  const void* queries        = d_in[0];
  const void* anchors        = d_in[1];
  const void* features       = d_in[2];
  const void* pos_embed      = d_in[3];
  const void* key_pos        = d_in[4];
  const void* query_pos      = d_in[5];
  const void* key_proj_w     = d_in[6];
  const void* key_conv_w     = d_in[7];
  const void* key_conv_b     = d_in[8];
  const void* query_proj_w   = d_in[9];
  const void* dist_w1        = d_in[10];
  const void* dist_b1        = d_in[11];
  const void* dist_w2        = d_in[12];
  const void* bc_proj_w      = d_in[13];
  const void* dt_proj_w      = d_in[14];
  const void* dt_bias        = d_in[15];
  const void* A_log          = d_in[16];
  const void* Dvec           = d_in[17];
  const void* key_norm_w     = d_in[18];
  const void* out_key_proj_w = d_in[19];
  const void* query_norm_w   = d_in[20];
  const void* query_norm_b   = d_in[21];
  const void* out_query_proj_w = d_in[22];
  const void* ffn_norm_w     = d_in[23];
  const void* ffn_norm_b     = d_in[24];
  const void* ffn_fc1_w      = d_in[25];
  const void* ffn_fc1_b      = d_in[26];
  const void* ffn_fc2_w      = d_in[27];
  const void* ffn_fc2_b      = d_in[28];

  if (ws_size < WS_FLOATS * sizeof(float)) return;

  float* ws    = (float*)d_ws;
  float* kp    = ws + OFF_KP;
  float* xact  = ws + OFF_XACT;
  float* aw    = ws + OFF_AW;
  float* carr  = ws + OFF_CARR;
  float* qproj = ws + OFF_QPROJ;
  float* yacc  = ws + OFF_YACC;
  float* send  = ws + OFF_SEND;
  float* ptot  = ws + OFF_PTOT;
  float* h0buf = ws + OFF_H0;
  float* hbuf  = ws + OFF_HB;
  u16*   gbuf  = (u16*)(ws + OFF_GBUF);
  float* outqf = ws + OFF_OUTQF;
  float* wprep = ws + OFF_WPREP;
  int*   flag  = (int*)(wprep + 1536);
  u16*   ugbuf = (u16*)(ws + OFF_UG);
  u16*   lnq   = (u16*)(ws + OFF_LNQ);
  u16*   lnf   = (u16*)(ws + OFF_LNF);
  u16*   abuf  = (u16*)(ws + OFF_ABUF);
  u16*   aq    = (u16*)(ws + OFF_AQ);
  u16*   bkey  = (u16*)(ws + OFF_BKEY);
  u16*   bq    = (u16*)(ws + OFF_BQ);
  u16*   bok   = (u16*)(ws + OFF_BOK);
  u16*   boq   = (u16*)(ws + OFF_BOQ);
  u16*   b1w   = (u16*)(ws + OFF_B1W);
  u16*   b2w   = (u16*)(ws + OFF_B2W);

  void* out_q = d_out;
  void* out_feat_bf16 = (void*)((u16*)d_out + (size_t)BSZ_*NQ_*DM_);
  void* out_feat_f32  = (void*)((float*)d_out + (size_t)BSZ_*NQ_*DM_);

  // 1. setup: yacc zero + cast0 + detect/prep
  setup_kernel<<<1249, 256, 0, stream>>>(
      features, pos_embed, abuf, queries, query_pos, aq,
      key_proj_w, bkey, query_proj_w, bq,
      A_log, dt_bias, dist_w1, dist_b1, dist_w2, bc_proj_w, dt_proj_w, wprep,
      yacc, flag);

  // 2. kp = abuf @ bkey : (4096 x 1034), K=256
  kp_gemm_kernel<<<dim3(64, 17), 256, 0, stream>>>(abuf, bkey, kp);

  // 3. conv + qproj GEMM
  convqp_kernel<<<4096 + 32, 256, 0, stream>>>(
      flag, kp, key_conv_w, key_conv_b, xact, aq, bq, qproj);

  // 4. dist
  dist_kernel<<<BSZ_*LSEQ_/2, 256, 0, stream>>>(flag, anchors, key_pos, kp, xact,
                                                wprep, aw, carr);

  // 5. s1 merged
  s1m_kernel<<<dim3(4, NCHUNK_, BSZ_*NH_), 256, 0, stream>>>(aw, xact, send, ptot);

  // 6. s2
  s2_kernel<<<1024, 256, 0, stream>>>(qproj, ptot, send, h0buf, hbuf);

  // 7. s3 (scalar loads, 8-t batched barrier) + cast1
  s3cast_kernel<<<2048 + 512, 256, 0, stream>>>(
      flag, aw, carr, xact, h0buf, yacc,
      out_key_proj_w, bok, out_query_proj_w, boq, ffn_fc1_w, b1w, ffn_fc2_w, b2w);

  // 8. g + lnq
  glnq_kernel<<<4096 + 256, 256, 0, stream>>>(
      flag, yacc, xact, kp, Dvec, key_norm_w, gbuf,
      hbuf, query_norm_w, query_norm_b, lnq);

  // 9. out_feat GEMM + outq GEMM
  ofoq_kernel<<<256 + 16, 256, 0, stream>>>(
      flag, gbuf, bok, out_feat_f32, out_feat_bf16, features,
      lnq, boq, outqf, queries);

  // 10. lnf
  lnf_kernel<<<BSZ_*NQ_, 256, 0, stream>>>(flag, outqf, ffn_norm_w, ffn_norm_b, lnf);

  // 11. fc1 + gelu fused: ug = gelu(a)*v
  fc1g_kernel<<<dim3(4, 16), 256, 0, stream>>>(flag, lnf, b1w, ffn_fc1_b, ugbuf);

  // 12. fc2: out_q = outqf + ug @ b2w + b2
  fc2_kernel<<<16, 256, 0, stream>>>(flag, ugbuf, b2w, out_q, outqf, ffn_fc2_b);
}

// Round 12
// 446.668 us; speedup vs baseline: 1.2825x; 1.0368x over previous
//
#include <hip/hip_runtime.h>

typedef unsigned short u16;
typedef __bf16 bf16x8 __attribute__((ext_vector_type(8)));
typedef u16 u16x8 __attribute__((ext_vector_type(8)));
typedef float f32x4 __attribute__((ext_vector_type(4)));

#define BSZ_ 2
#define NQ_ 128
#define LSEQ_ 2048
#define DM_ 256
#define DI_ 512
#define NH_ 8
#define HD_ 64
#define DKEY_ 1034
#define DCV_ 514
#define NCHUNK_ 16
#define CT_ 128   // chunk length

__device__ __forceinline__ float bf2f(u16 u) {
  unsigned v = ((unsigned)u) << 16;
  return __builtin_bit_cast(float, v);
}
__device__ __forceinline__ u16 f2bf(float f) {
  unsigned u = __builtin_bit_cast(unsigned, f);
  u += 0x7fffu + ((u >> 16) & 1u);
  return (u16)(u >> 16);
}
__device__ __forceinline__ float sigmoidf_(float x) { return 1.f / (1.f + expf(-x)); }
__device__ __forceinline__ float softplusf_(float x) {
  return (x > 20.f) ? x : log1pf(expf(x));
}

template<bool F32>
__device__ __forceinline__ float ldi(const void* p, size_t i) {
  return F32 ? ((const float*)p)[i] : bf2f(((const u16*)p)[i]);
}
template<bool F32>
__device__ __forceinline__ void sto(void* p, size_t i, float v) {
  if (F32) ((float*)p)[i] = v;
  else ((u16*)p)[i] = f2bf(v);
}

// per-wave dtype detection (all waves read same 64 u16s -> uniform result)
__device__ __forceinline__ bool detect_f32(const void* feat) {
  int lane = threadIdx.x & 63;
  float a = fabsf(bf2f(((const u16*)feat)[2*lane]));
  bool plaus = (a > 1e-6f) && (a < 1e6f);
  unsigned long long m = __ballot(plaus);
  return __popcll(m) < 32;   // true => fp32 storage
}

// ---------------- workspace layout (float units) ----------------
constexpr size_t SZ_KP    = (size_t)BSZ_*LSEQ_*DKEY_;
constexpr size_t SZ_XACT  = (size_t)BSZ_*LSEQ_*DCV_;
constexpr size_t SZ_AW    = (size_t)BSZ_*NH_*LSEQ_*NQ_*2;
constexpr size_t SZ_CARR  = (size_t)BSZ_*LSEQ_*NQ_;
constexpr size_t SZ_QPROJ = (size_t)BSZ_*NQ_*DI_;
constexpr size_t SZ_YACC  = (size_t)BSZ_*LSEQ_*DI_;
constexpr size_t SZ_SEND  = (size_t)BSZ_*NH_*2*NCHUNK_*NQ_*HD_;
constexpr size_t SZ_PTOT  = (size_t)BSZ_*NH_*2*NCHUNK_*NQ_;
constexpr size_t SZ_H0    = SZ_SEND;
constexpr size_t SZ_HB    = (size_t)BSZ_*NH_*2*NQ_*HD_;
constexpr size_t SZ_GBUF  = (size_t)BSZ_*LSEQ_*DI_/2;
constexpr size_t SZ_OUTQF = (size_t)BSZ_*NQ_*DM_;
constexpr size_t SZ_WPREP = 2048;

constexpr size_t OFF_KP    = 0;
constexpr size_t OFF_XACT  = OFF_KP + SZ_KP;
constexpr size_t OFF_AW    = OFF_XACT + SZ_XACT;
constexpr size_t OFF_CARR  = OFF_AW + SZ_AW;
constexpr size_t OFF_QPROJ = OFF_CARR + SZ_CARR;
constexpr size_t OFF_YACC  = OFF_QPROJ + SZ_QPROJ;
constexpr size_t OFF_SEND  = OFF_YACC + SZ_YACC;
constexpr size_t OFF_PTOT  = OFF_SEND + SZ_SEND;
constexpr size_t OFF_H0    = OFF_PTOT + SZ_PTOT;
constexpr size_t OFF_HB    = OFF_H0 + SZ_H0;
constexpr size_t OFF_GBUF  = OFF_HB + SZ_HB;
constexpr size_t OFF_OUTQF = OFF_GBUF + SZ_GBUF;
constexpr size_t OFF_WPREP = OFF_OUTQF + SZ_OUTQF;
constexpr size_t WS_FLOATS = OFF_WPREP + SZ_WPREP;

// FFN/outq scratch aliases into AW (dead after s3):
constexpr size_t OFF_UG  = OFF_AW;                         // 256x1024 bf16
constexpr size_t OFF_LNQ = OFF_UG + (size_t)256*1024/2;    // 256x512 bf16
constexpr size_t OFF_LNF = OFF_LNQ + (size_t)256*512/2;    // 256x256 bf16

// Transient bf16 cast buffers alias SEND (dead until s1 writes it):
constexpr size_t OFF_ABUF = OFF_SEND;                         // 4096x256 bf16
constexpr size_t OFF_AQ   = OFF_ABUF + (size_t)4096*256/2;
constexpr size_t OFF_BKEY = OFF_AQ + (size_t)256*256/2;
constexpr size_t OFF_BQ   = OFF_BKEY + (size_t)(256*1034+1)/2 + 1;
// Late bf16 weight casts alias SEND (dead after s2):
constexpr size_t OFF_BOK  = OFF_SEND;
constexpr size_t OFF_BOQ  = OFF_BOK + (size_t)512*256/2;
constexpr size_t OFF_B1W  = OFF_BOQ + (size_t)512*256/2;
constexpr size_t OFF_B2W  = OFF_B1W + (size_t)256*2048/2;

// wprep layout: [0..7] A=-exp(A_log); [8..15] dt_bias; [32..287] w1b; [288..1311] w2;
// [1312..1343] bc_proj; [1344..1471] dt_proj
template<bool F32>
__device__ void prep_body(const void* A_log, const void* dt_bias,
                          const void* w1, const void* b1, const void* w2,
                          const void* bcw, const void* dtw, float* wp) {
  int t = threadIdx.x;
  if (t < 8) {
    wp[t]     = -expf(ldi<F32>(A_log, t));
    wp[8 + t] = ldi<F32>(dt_bias, t);
  }
  if (t < 64) {
    wp[32 + t*4 + 0] = ldi<F32>(w1, 0*64 + t);
    wp[32 + t*4 + 1] = ldi<F32>(w1, 1*64 + t);
    wp[32 + t*4 + 2] = ldi<F32>(w1, 2*64 + t);
    wp[32 + t*4 + 3] = ldi<F32>(b1, t);
  }
  for (int i = t; i < 1024; i += 256) wp[288 + i] = ldi<F32>(w2, i);
  if (t < 32)  wp[1312 + t] = ldi<F32>(bcw, t);
  if (t < 128) wp[1344 + t] = ldi<F32>(dtw, t);
}

// cast helper: d[i] = bf16(s0[i] (+ s1_[i]))
__device__ __forceinline__ void cast_job(bool F32, const void* s0, const void* s1_,
                                         u16* d, size_t n, size_t base, size_t stride) {
  for (size_t i = base; i < n; i += stride) {
    float v = F32 ? ((const float*)s0)[i] : bf2f(((const u16*)s0)[i]);
    if (s1_) v += F32 ? ((const float*)s1_)[i] : bf2f(((const u16*)s1_)[i]);
    d[i] = f2bf(v);
  }
}

// ---------------- setup: yacc zero + cast0 + detect/prep (fused) ----------------
__global__ __launch_bounds__(256) void setup_kernel(
    const void* feat, const void* pe, u16* abuf,
    const void* q, const void* qp, u16* aq,
    const void* kw, u16* bkey, const void* qw, u16* bq,
    const void* A_log, const void* dt_bias, const void* w1, const void* b1,
    const void* w2, const void* bcw, const void* dtw, float* wp,
    float* yacc, int* flag)
{
  int bx = blockIdx.x, tid = threadIdx.x;
  if (bx < 512) {                       // yacc zero: 512 blocks x 4096 floats
    size_t base = (size_t)bx * 4096 + tid;
#pragma unroll
    for (int k = 0; k < 16; ++k) yacc[base + (size_t)k*256] = 0.f;
    return;
  }
  bool F32 = detect_f32(feat);
  if (bx < 1024) {                      // abuf = bf16(features + pos_embed)
    cast_job(F32, feat, pe, abuf, (size_t)4096*256,
             (size_t)(bx-512)*256 + tid, (size_t)512*256);
  } else if (bx < 1056) {               // aq = bf16(queries + query_pos)
    cast_job(F32, q, qp, aq, (size_t)256*256,
             (size_t)(bx-1024)*256 + tid, (size_t)32*256);
  } else if (bx < 1184) {               // bkey = bf16(key_proj_w)
    cast_job(F32, kw, nullptr, bkey, (size_t)256*1034,
             (size_t)(bx-1056)*256 + tid, (size_t)128*256);
  } else if (bx < 1248) {               // bq = bf16(query_proj_w)
    cast_job(F32, qw, nullptr, bq, (size_t)256*512,
             (size_t)(bx-1184)*256 + tid, (size_t)64*256);
  } else {                              // detect-store + prep
    if (tid == 0) *flag = F32 ? 1 : 0;
    if (F32) prep_body<true>(A_log, dt_bias, w1, b1, w2, bcw, dtw, wp);
    else     prep_body<false>(A_log, dt_bias, w1, b1, w2, bcw, dtw, wp);
  }
}

// ---------------- MFMA GEMM body (bm/bn parameterized) ----------------
template<int A_MODE, int B_MODE, int OUT_EXT, int RES_EXT, int RES_F32, int BIAS, bool F32>
__device__ void gemm_body(int bm, int bn,
                          const void* A0, const void* A1, const void* Bw,
                          float* Cf, void* Cext, const void* ResE,
                          const float* ResF, const void* Bias,
                          int M, int N, int K) {
  __shared__ u16 As[64][40];
  __shared__ u16 Bs[64][40];
  int tid = threadIdx.x;
  int w = tid >> 6, lane = tid & 63;
  f32x4 acc[4];
#pragma unroll
  for (int j = 0; j < 4; ++j) acc[j] = (f32x4){0.f, 0.f, 0.f, 0.f};

  int arow = tid >> 2, aseg = (tid & 3) * 8;
  int bkl = tid >> 3, bns = (tid & 7) * 8;

  for (int k0 = 0; k0 < K; k0 += 32) {
    {
      size_t abase = (size_t)(bm + arow) * K + k0 + aseg;
      u16x8 tv;
      if (A_MODE == 0) {
#pragma unroll
        for (int i = 0; i < 8; ++i)
          tv[i] = f2bf(ldi<F32>(A0, abase + i) + ldi<F32>(A1, abase + i));
      } else {
        const u16* pa = (const u16*)A0 + abase;
#pragma unroll
        for (int i = 0; i < 8; ++i) tv[i] = pa[i];
      }
      *(u16x8*)&As[arow][aseg] = tv;
    }
    {
      size_t bbase = (size_t)(k0 + bkl) * N + bn + bns;
#pragma unroll
      for (int i = 0; i < 8; ++i) {
        u16 v;
        if (bn + bns + i < N) {
          if (B_MODE == 1) v = ((const u16*)Bw)[bbase + i];
          else             v = f2bf(ldi<F32>(Bw, bbase + i));
        } else v = (u16)0;
        Bs[bns + i][bkl] = v;
      }
    }
    __syncthreads();
    int mrow = w * 16 + (lane & 15);
    int kq = (lane >> 4) * 8;
    bf16x8 af = __builtin_bit_cast(bf16x8, *(const u16x8*)&As[mrow][kq]);
#pragma unroll
    for (int j = 0; j < 4; ++j) {
      bf16x8 bfv = __builtin_bit_cast(bf16x8, *(const u16x8*)&Bs[j*16 + (lane & 15)][kq]);
      acc[j] = __builtin_amdgcn_mfma_f32_16x16x32_bf16(af, bfv, acc[j], 0, 0, 0);
    }
    __syncthreads();
  }
  int col0 = lane & 15, rbase = (lane >> 4) * 4;
#pragma unroll
  for (int j = 0; j < 4; ++j) {
#pragma unroll
    for (int r = 0; r < 4; ++r) {
      int row = bm + w * 16 + rbase + r;
      int col = bn + j * 16 + col0;
      if (col < N) {
        size_t idx = (size_t)row * N + col;
        float v = acc[j][r];
        if (BIAS)    v += ldi<F32>(Bias, col);
        if (RES_EXT) v += ldi<F32>(ResE, idx);
        if (RES_F32) v += ResF[idx];
        if (OUT_EXT) sto<F32>(Cext, idx, v);
        else         Cf[idx] = v;
      }
    }
  }
}

// kp = abuf @ bkey (all-internal bf16, fp32 out)
__global__ __launch_bounds__(256) void kp_gemm_kernel(
    const u16* abuf, const u16* bkey, float* kp) {
  gemm_body<1,1,0,0,0,0,false>(blockIdx.x*64, blockIdx.y*64, abuf, nullptr, bkey,
                               kp, nullptr, nullptr, nullptr, nullptr,
                               4096, DKEY_, DM_);
}

// fc2: out_q = outqf + ug @ b2w + b2
template<bool F32>
__device__ void fc2_body(const u16* ug, const u16* b2w, void* out_q,
                         const float* outqf, const void* b2) {
  gemm_body<1,1,1,0,1,1,F32>((blockIdx.x&3)*64, (blockIdx.x>>2)*64, ug, nullptr,
                             b2w, nullptr, out_q, nullptr, outqf, b2,
                             BSZ_*NQ_, DM_, 1024);
}
__global__ __launch_bounds__(256) void fc2_kernel(
    const int* fl, const u16* ug, const u16* b2w, void* out_q,
    const float* outqf, const void* b2) {
  if (*fl) fc2_body<true>(ug, b2w, out_q, outqf, b2);
  else     fc2_body<false>(ug, b2w, out_q, outqf, b2);
}

// ---------------- conv + qproj GEMM (fused, independent blocks) ----------------
template<bool F32>
__device__ void conv_body(const float* kp, const void* cw, const void* cb,
                          float* xact) {
  int row = blockIdx.x;
  int l = row & (LSEQ_ - 1);
  for (int ch = threadIdx.x; ch < DCV_; ch += 256) {
    float acc = ldi<F32>(cb, ch);
#pragma unroll
    for (int k = 0; k < 4; ++k) {
      int ll = l - 3 + k;
      if (ll >= 0)
        acc = fmaf(ldi<F32>(cw, ch*4 + k), kp[(size_t)(row - 3 + k)*DKEY_ + DI_ + ch], acc);
    }
    xact[(size_t)row*DCV_ + ch] = acc * sigmoidf_(acc);
  }
}
__global__ __launch_bounds__(256) void convqp_kernel(
    const int* fl, const float* kp, const void* cw, const void* cb, float* xact,
    const u16* aq, const u16* bq, float* qproj)
{
  int bx = blockIdx.x;
  if (bx < 4096) {
    if (*fl) conv_body<true>(kp, cw, cb, xact);
    else     conv_body<false>(kp, cw, cb, xact);
  } else {
    int i = bx - 4096;   // 32 blocks: M=256 (4 tiles) x N=512 (8 tiles)
    gemm_body<1,1,0,0,0,0,false>((i&3)*64, (i>>2)*64, aq, nullptr, bq,
                                 qproj, nullptr, nullptr, nullptr, nullptr,
                                 BSZ_*NQ_, DI_, DM_);
  }
}

// ---------------- dist MLP -> a, w, c ----------------
template<bool F32>
__device__ void dist_body(const void* anchors, const void* key_pos,
                          const float* kp, const float* xact, const float* wp,
                          float* aw, float* carr) {
  int tid = threadIdx.x;
  int n = tid & 127;
  int idx = blockIdx.x;
  int b = idx >> 10;
  int l = ((idx & 1023) << 1) | (tid >> 7);
  size_t row = (size_t)b * LSEQ_ + l;

  float enc0, enc1, enc2;
  {
    float e[3];
#pragma unroll
    for (int d = 0; d < 3; ++d) {
      float delta = ldi<F32>(anchors, (b*NQ_ + n)*3 + d) - ldi<F32>(key_pos, row*3 + d);
      float s = delta < 0.f ? -1.f : 1.f;
      e[d] = s * log2f(fabsf(delta) * 20.f + 1.f) * (1.f/12.f);
    }
    enc0 = e[0]; enc1 = e[1]; enc2 = e[2];
  }
  float feat[16];
#pragma unroll
  for (int f = 0; f < 16; ++f) feat[f] = 0.f;
  for (int j = 0; j < 64; ++j) {
    float w0 = wp[32 + j*4], w1v = wp[33 + j*4], w2v = wp[34 + j*4], bb = wp[35 + j*4];
    float hj = fmaxf(fmaf(enc0, w0, fmaf(enc1, w1v, fmaf(enc2, w2v, bb))), 0.f);
#pragma unroll
    for (int f = 0; f < 16; ++f) feat[f] = fmaf(hj, wp[288 + j*16 + f], feat[f]);
  }
  float bc0 = 0.f, bc1 = 0.f;
#pragma unroll
  for (int f = 0; f < 16; ++f) {
    bc0 = fmaf(feat[f], wp[1312 + f*2], bc0);
    bc1 = fmaf(feat[f], wp[1313 + f*2], bc1);
  }
  float bb_ = xact[row*DCV_ + DI_];
  float cb_ = xact[row*DCV_ + DI_ + 1];
  float Bs = bc0 + bb_, Cs = bc1 + cb_;
  carr[row*NQ_ + n] = Cs;

  float dtb[8];
#pragma unroll
  for (int h = 0; h < 8; ++h) dtb[h] = 0.f;
#pragma unroll
  for (int f = 0; f < 16; ++f)
#pragma unroll
    for (int h = 0; h < 8; ++h) dtb[h] = fmaf(feat[f], wp[1344 + f*8 + h], dtb[h]);

#pragma unroll
  for (int h = 0; h < 8; ++h) {
    float xln = dtb[h] + kp[row*DKEY_ + (DI_*2 + 2) + h] + wp[8 + h];
    float dtv = softplusf_(xln);
    float a = expf(dtv * wp[h]);
    float wv = dtv * Bs;
    size_t o = (((size_t)(b*NH_ + h)*LSEQ_ + l)*NQ_ + n)*2;
    aw[o] = a;
    aw[o + 1] = wv;
  }
}
__global__ __launch_bounds__(256) void dist_kernel(
    const int* fl, const void* anchors, const void* key_pos, const float* kp,
    const float* xact, const float* wp, float* aw, float* carr) {
  if (*fl) dist_body<true>(anchors, key_pos, kp, xact, wp, aw, carr);
  else     dist_body<false>(anchors, key_pos, kp, xact, wp, aw, carr);
}

// ---------------- scan phase 1 MERGED (R6-proven) ----------------
__global__ __launch_bounds__(256) void s1m_kernel(
    const float* __restrict__ aw, const float* __restrict__ xact,
    float* __restrict__ send, float* __restrict__ ptot)
{
  int tid = threadIdx.x;
  int hd = tid & 63;
  int w = __builtin_amdgcn_readfirstlane(tid >> 6);
  int ns = blockIdx.x, q = blockIdx.y, z = blockIdx.z;
  int h = z & 7, b = z >> 3;
  int n0 = __builtin_amdgcn_readfirstlane(ns*32 + w*8);

  float hf[8], hb[8], pr[8];
#pragma unroll
  for (int i = 0; i < 8; ++i) { hf[i] = 0.f; hb[i] = 0.f; pr[i] = 1.f; }

  size_t awbase = (size_t)z * LSEQ_ * (NQ_*2);
  int t = q*CT_;
  for (int s = 0; s < CT_; ++s, ++t) {
    const float* awt = aw + awbase + (size_t)t*(NQ_*2) + n0*2;
    float xv = xact[((size_t)(b*LSEQ_ + t))*DCV_ + (h << 6) + hd];
#pragma unroll
    for (int i = 0; i < 8; ++i) {
      float a = awt[2*i], wv = awt[2*i + 1];
      float wx = wv * xv;
      hf[i] = fmaf(hf[i], a, wx);
      hb[i] = fmaf(pr[i], wx, hb[i]);
      pr[i] *= a;
    }
  }
  size_t cbf = (size_t)((z*2 + 0)*NCHUNK_ + q);
  size_t cbb = (size_t)((z*2 + 1)*NCHUNK_ + (NCHUNK_ - 1 - q));
#pragma unroll
  for (int i = 0; i < 8; ++i) {
    send[cbf*(NQ_*HD_) + (size_t)(n0 + i)*HD_ + hd] = hf[i];
    send[cbb*(NQ_*HD_) + (size_t)(n0 + i)*HD_ + hd] = hb[i];
  }
  if (hd == 0) {
#pragma unroll
    for (int i = 0; i < 8; ++i) {
      ptot[cbf*NQ_ + n0 + i] = pr[i];
      ptot[cbb*NQ_ + n0 + i] = pr[i];
    }
  }
}

// ---------------- scan phase 2 ----------------
__global__ __launch_bounds__(256) void s2_kernel(
    const float* __restrict__ qproj, const float* __restrict__ ptot,
    const float* __restrict__ send, float* __restrict__ h0buf,
    float* __restrict__ hbuf)
{
  int g = blockIdx.x*256 + threadIdx.x;
  int hd = g & 63;
  int n = (g >> 6) & 127;
  int dir = (g >> 13) & 1;
  int h = (g >> 14) & 7;
  int b = g >> 17;
  float hcur = qproj[((size_t)(b*NQ_ + n))*DI_ + h*HD_ + hd];
  size_t base = (size_t)((b*NH_ + h)*2 + dir) * NCHUNK_;
  for (int q = 0; q < NCHUNK_; ++q) {
    size_t cb = base + q;
    h0buf[cb*(NQ_*HD_) + (size_t)n*HD_ + hd] = hcur;
    hcur = fmaf(hcur, ptot[cb*NQ_ + n], send[cb*(NQ_*HD_) + (size_t)n*HD_ + hd]);
  }
  hbuf[((size_t)((b*NH_ + h)*2 + dir))*(NQ_*HD_) + (size_t)n*HD_ + hd] = hcur;
}

// ---------------- scan phase 3: R9 inner loop, fwd+bwd co-located per block ----
// 512 threads: waves 0-3 = fwd chunk q (t ascending), waves 4-7 = bwd chunk
// 15-q (t descending) -- SAME t-range [q*128, q*128+127], so aw/carr/xact
// slices are read from both ends and the second toucher hits L1/L2.
// Per-t: each wave writes its partial to ybuf[p][wave][hd]; one barrier;
// wave0 reduces+atomics fwd at its t, wave4 reduces+atomics bwd at its t.
// cast1 blocks appended (512-thread variant).
__device__ __forceinline__ void cast1_part512(bool F32,
    const void* okw, u16* bok, const void* oqw, u16* boq,
    const void* w1, u16* b1w, const void* w2, u16* b2w) {
  int i = blockIdx.x - 1024;
  int job = i >> 6, bj = i & 63;
  size_t base = (size_t)bj*512 + threadIdx.x, stride = (size_t)64*512;
  switch (job) {
    case 0: cast_job(F32, okw, nullptr, bok, (size_t)512*256, base, stride); break;
    case 1: cast_job(F32, oqw, nullptr, boq, (size_t)512*256, base, stride); break;
    case 2: cast_job(F32, w1, nullptr, b1w, (size_t)256*2048, base, stride); break;
    default: cast_job(F32, w2, nullptr, b2w, (size_t)1024*256, base, stride); break;
  }
}
__global__ __launch_bounds__(512) void s3cast_kernel(
    const int* fl, const float* __restrict__ aw, const float* __restrict__ carr,
    const float* __restrict__ xact, const float* __restrict__ h0buf,
    float* __restrict__ yacc,
    const void* okw, u16* bok, const void* oqw, u16* boq,
    const void* w1, u16* b1w, const void* w2, u16* b2w)
{
  int bx = blockIdx.x;
  if (bx >= 1024) {
    cast1_part512(*fl != 0, okw, bok, oqw, boq, w1, b1w, w2, b2w);
    return;
  }
  __shared__ float ybuf[2][8][64];   // 4 KB
  int tid = threadIdx.x;
  int hd = tid & 63;
  int wave = __builtin_amdgcn_readfirstlane(tid >> 6);   // 0..7
  int dirw = wave >> 2;                                  // 0=fwd, 1=bwd
  int w4 = wave & 3;
  int ns = bx & 3, q = (bx >> 2) & 15, zz = bx >> 6;     // zz = b*NH_+h
  int h = zz & 7, b = zz >> 3;
  int n0 = __builtin_amdgcn_readfirstlane(ns*32 + w4*8);
  int chunk = dirw ? (NCHUNK_ - 1 - q) : q;

  float hst[8];
  size_t cb = (size_t)((zz*2 + dirw)*NCHUNK_ + chunk);
#pragma unroll
  for (int i = 0; i < 8; ++i)
    hst[i] = h0buf[cb*(NQ_*HD_) + (size_t)(n0 + i)*HD_ + hd];

  size_t awbase = (size_t)zz * LSEQ_ * (NQ_*2);
  int tbase = dirw ? (q*CT_ + CT_ - 1) : (q*CT_);   // bwd chunk 15-q descends
  int tstep = dirw ? -1 : 1;                        // through [q*128, q*128+127]
  int t = tbase;
  for (int s = 0; s < CT_; ++s, t += tstep) {
    const float* awt = aw + awbase + (size_t)t*(NQ_*2) + n0*2;
    const float* ct = carr + ((size_t)(b*LSEQ_ + t))*NQ_ + n0;
    float xv = xact[((size_t)(b*LSEQ_ + t))*DCV_ + (h << 6) + hd];
    float ys = 0.f;
#pragma unroll
    for (int i = 0; i < 8; ++i) {
      hst[i] = fmaf(hst[i], awt[2*i], awt[2*i + 1] * xv);
      ys = fmaf(hst[i], ct[i], ys);
    }
    int p = s & 1;
    ybuf[p][wave][hd] = ys;
    __syncthreads();
    if (wave == 0) {
      float yv = ybuf[p][0][hd] + ybuf[p][1][hd] + ybuf[p][2][hd] + ybuf[p][3][hd];
      atomicAdd(&yacc[((size_t)(b*LSEQ_ + t))*DI_ + (h << 6) + hd], 0.5f * yv);
    } else if (wave == 4) {
      float yv = ybuf[p][4][hd] + ybuf[p][5][hd] + ybuf[p][6][hd] + ybuf[p][7][hd];
      atomicAdd(&yacc[((size_t)(b*LSEQ_ + t))*DI_ + (h << 6) + hd], 0.5f * yv);
    }
  }
}

// ---------------- block reduction helper ----------------
__device__ __forceinline__ float block_sum256(float v, float* red) {
#pragma unroll
  for (int off = 32; off; off >>= 1) v += __shfl_xor(v, off, 64);
  int wv = threadIdx.x >> 6;
  if ((threadIdx.x & 63) == 0) red[wv] = v;
  __syncthreads();
  float t = red[0] + red[1] + red[2] + red[3];
  __syncthreads();
  return t;
}

// ---------------- g (gated RMSNorm) + lnq (fused) ----------------
template<bool F32>
__device__ void g_body(const float* yacc, const float* xact, const float* kp,
                       const void* Dv, const void* knw, u16* gbuf) {
  int row = blockIdx.x, tid = threadIdx.x;
  __shared__ float red[4];
  float gg[2];
  float ss = 0.f;
#pragma unroll
  for (int ii = 0; ii < 2; ++ii) {
    int ch = tid + ii*256;
    float yv = yacc[(size_t)row*DI_ + ch];
    float xv = xact[(size_t)row*DCV_ + ch];
    float zv = kp[(size_t)row*DKEY_ + ch];
    float Dh = ldi<F32>(Dv, ch >> 6);
    float yf = yv + 2.f * Dh * xv;
    float g = yf * (zv * sigmoidf_(zv));
    gg[ii] = g;
    ss += g * g;
  }
  float tot = block_sum256(ss, red);
  float r = rsqrtf(tot / (float)DI_ + 1e-5f);
#pragma unroll
  for (int ii = 0; ii < 2; ++ii) {
    int ch = tid + ii*256;
    gbuf[(size_t)row*DI_ + ch] = f2bf(gg[ii] * r * ldi<F32>(knw, ch));
  }
}
template<bool F32>
__device__ void lnq_body(const float* hbuf, const void* qnw, const void* qnb,
                         u16* lnq) {
  int row = blockIdx.x - 4096;
  int b = row >> 7, n = row & 127;
  int tid = threadIdx.x;
  __shared__ float red[4];
  float hv[2];
  float s1 = 0.f, s2 = 0.f;
#pragma unroll
  for (int ii = 0; ii < 2; ++ii) {
    int ch = tid + ii*256;
    int h = ch >> 6, hd = ch & 63;
    size_t base = ((size_t)((b*NH_ + h)*2))*(NQ_*HD_) + (size_t)n*HD_ + hd;
    float v = 0.5f * (hbuf[base] + hbuf[base + (size_t)NQ_*HD_]);
    hv[ii] = v;
    s1 += v;
    s2 += v * v;
  }
  s1 = block_sum256(s1, red);
  s2 = block_sum256(s2, red);
  float mean = s1 / (float)DI_;
  float var = fmaxf(s2 / (float)DI_ - mean * mean, 0.f);
  float rstd = rsqrtf(var + 1e-5f);
#pragma unroll
  for (int ii = 0; ii < 2; ++ii) {
    int ch = tid + ii*256;
    lnq[(size_t)row*DI_ + ch] =
        f2bf((hv[ii] - mean) * rstd * ldi<F32>(qnw, ch) + ldi<F32>(qnb, ch));
  }
}
__global__ __launch_bounds__(256) void glnq_kernel(
    const int* fl, const float* yacc, const float* xact, const float* kp,
    const void* Dv, const void* knw, u16* gbuf,
    const float* hbuf, const void* qnw, const void* qnb, u16* lnq)
{
  if (blockIdx.x < 4096) {
    if (*fl) g_body<true>(yacc, xact, kp, Dv, knw, gbuf);
    else     g_body<false>(yacc, xact, kp, Dv, knw, gbuf);
  } else {
    if (*fl) lnq_body<true>(hbuf, qnw, qnb, lnq);
    else     lnq_body<false>(hbuf, qnw, qnb, lnq);
  }
}

// ---------------- out_feat GEMM + outq GEMM (fused) ----------------
template<bool F32>
__device__ void ofoq_body(const u16* gbuf, const u16* bok, void* out_feat,
                          const void* features, const u16* lnq, const u16* boq,
                          float* outqf, const void* queries) {
  int bx = blockIdx.x;
  if (bx < 256) {   // out_feat: M=4096 (64 tiles) x N=256 (4 tiles), K=512
    gemm_body<1,1,1,1,0,0,F32>((bx>>2)*64, (bx&3)*64, gbuf, nullptr, bok,
                               nullptr, out_feat, features, nullptr, nullptr,
                               4096, DM_, DI_);
  } else {          // outq: M=256 (4) x N=256 (4), K=512
    int i = bx - 256;
    gemm_body<1,1,0,1,0,0,F32>((i&3)*64, (i>>2)*64, lnq, nullptr, boq,
                               outqf, nullptr, queries, nullptr, nullptr,
                               BSZ_*NQ_, DM_, DI_);
  }
}
__global__ __launch_bounds__(256) void ofoq_kernel(
    const int* fl, const u16* gbuf, const u16* bok,
    void* out_feat_f32, void* out_feat_bf16, const void* features,
    const u16* lnq, const u16* boq, float* outqf, const void* queries) {
  if (*fl) ofoq_body<true>(gbuf, bok, out_feat_f32, features, lnq, boq, outqf, queries);
  else     ofoq_body<false>(gbuf, bok, out_feat_bf16, features, lnq, boq, outqf, queries);
}

// ---------------- FFN LN -> lnf ----------------
template<bool F32>
__device__ void lnf_body(const float* outqf, const void* fnw, const void* fnb,
                         u16* lnf) {
  int row = blockIdx.x, tid = threadIdx.x;
  __shared__ float red[4];
  float x = outqf[(size_t)row*DM_ + tid];
  float s1 = block_sum256(x, red);
  float s2 = block_sum256(x * x, red);
  float mean = s1 / (float)DM_;
  float var = fmaxf(s2 / (float)DM_ - mean * mean, 0.f);
  float rstd = rsqrtf(var + 1e-5f);
  lnf[(size_t)row*DM_ + tid] =
      f2bf((x - mean) * rstd * ldi<F32>(fnw, tid) + ldi<F32>(fnb, tid));
}
__global__ __launch_bounds__(256) void lnf_kernel(
    const int* fl, const float* outqf, const void* fnw, const void* fnb, u16* lnf) {
  if (*fl) lnf_body<true>(outqf, fnw, fnb, lnf);
  else     lnf_body<false>(outqf, fnw, fnb, lnf);
}

// ---------------- fc1 + gelu fused: ug = gelu(lnf@W1a + b1a) * (lnf@W1v + b1v) ----
template<bool F32>
__device__ void fc1g_body(const u16* lnf, const u16* b1w, const void* b1, u16* ug) {
  __shared__ u16 As[64][40];
  __shared__ u16 BsA[64][40];
  __shared__ u16 BsV[64][40];
  int tid = threadIdx.x;
  int w = tid >> 6, lane = tid & 63;
  int bm = blockIdx.x * 64, bn = blockIdx.y * 64;   // bn in [0,1024)
  f32x4 accA[4], accV[4];
#pragma unroll
  for (int j = 0; j < 4; ++j) {
    accA[j] = (f32x4){0.f, 0.f, 0.f, 0.f};
    accV[j] = (f32x4){0.f, 0.f, 0.f, 0.f};
  }
  int arow = tid >> 2, aseg = (tid & 3) * 8;
  int bkl = tid >> 3, bns = (tid & 7) * 8;

  for (int k0 = 0; k0 < DM_; k0 += 32) {
    {
      size_t abase = (size_t)(bm + arow) * DM_ + k0 + aseg;
      const u16* pa = lnf + abase;
      u16x8 tv;
#pragma unroll
      for (int i = 0; i < 8; ++i) tv[i] = pa[i];
      *(u16x8*)&As[arow][aseg] = tv;
    }
    {
      size_t bbase = (size_t)(k0 + bkl) * 2048 + bn + bns;
#pragma unroll
      for (int i = 0; i < 8; ++i) {
        BsA[bns + i][bkl] = b1w[bbase + i];
        BsV[bns + i][bkl] = b1w[bbase + 1024 + i];
      }
    }
    __syncthreads();
    int mrow = w * 16 + (lane & 15);
    int kq = (lane >> 4) * 8;
    bf16x8 af = __builtin_bit_cast(bf16x8, *(const u16x8*)&As[mrow][kq]);
#pragma unroll
    for (int j = 0; j < 4; ++j) {
      bf16x8 ba = __builtin_bit_cast(bf16x8, *(const u16x8*)&BsA[j*16 + (lane & 15)][kq]);
      bf16x8 bv = __builtin_bit_cast(bf16x8, *(const u16x8*)&BsV[j*16 + (lane & 15)][kq]);
      accA[j] = __builtin_amdgcn_mfma_f32_16x16x32_bf16(af, ba, accA[j], 0, 0, 0);
      accV[j] = __builtin_amdgcn_mfma_f32_16x16x32_bf16(af, bv, accV[j], 0, 0, 0);
    }
    __syncthreads();
  }
  int col0 = lane & 15, rbase = (lane >> 4) * 4;
#pragma unroll
  for (int j = 0; j < 4; ++j) {
#pragma unroll
    for (int r = 0; r < 4; ++r) {
      int row = bm + w * 16 + rbase + r;
      int col = bn + j * 16 + col0;
      float a = accA[j][r] + ldi<F32>(b1, col);
      float v = accV[j][r] + ldi<F32>(b1, col + 1024);
      float ge = 0.5f * a * (1.f + erff(a * 0.70710678118f));
      ug[(size_t)row*1024 + col] = f2bf(ge * v);
    }
  }
}
__global__ __launch_bounds__(256) void fc1g_kernel(
    const int* fl, const u16* lnf, const u16* b1w, const void* b1, u16* ug) {
  if (*fl) fc1g_body<true>(lnf, b1w, b1, ug);
  else     fc1g_body<false>(lnf, b1w, b1, ug);
}

// ---------------- launch ----------------
extern "C" void kernel_launch(void* const* d_in, const int* in_sizes, int n_in,
                              void* d_out, int out_size, void* d_ws, size_t ws_size,
                              hipStream_t stream) {
  const void* queries        = d_in[0];
  const void* anchors        = d_in[1];
  const void* features       = d_in[2];
  const void* pos_embed      = d_in[3];
  const void* key_pos        = d_in[4];
  const void* query_pos      = d_in[5];
  const void* key_proj_w     = d_in[6];
  const void* key_conv_w     = d_in[7];
  const void* key_conv_b     = d_in[8];
  const void* query_proj_w   = d_in[9];
  const void* dist_w1        = d_in[10];
  const void* dist_b1        = d_in[11];
  const void* dist_w2        = d_in[12];
  const void* bc_proj_w      = d_in[13];
  const void* dt_proj_w      = d_in[14];
  const void* dt_bias        = d_in[15];
  const void* A_log          = d_in[16];
  const void* Dvec           = d_in[17];
  const void* key_norm_w     = d_in[18];
  const void* out_key_proj_w = d_in[19];
  const void* query_norm_w   = d_in[20];
  const void* query_norm_b   = d_in[21];
  const void* out_query_proj_w = d_in[22];
  const void* ffn_norm_w     = d_in[23];
  const void* ffn_norm_b     = d_in[24];
  const void* ffn_fc1_w      = d_in[25];
  const void* ffn_fc1_b      = d_in[26];
  const void* ffn_fc2_w      = d_in[27];
  const void* ffn_fc2_b      = d_in[28];

  if (ws_size < WS_FLOATS * sizeof(float)) return;

  float* ws    = (float*)d_ws;
  float* kp    = ws + OFF_KP;
  float* xact  = ws + OFF_XACT;
  float* aw    = ws + OFF_AW;
  float* carr  = ws + OFF_CARR;
  float* qproj = ws + OFF_QPROJ;
  float* yacc  = ws + OFF_YACC;
  float* send  = ws + OFF_SEND;
  float* ptot  = ws + OFF_PTOT;
  float* h0buf = ws + OFF_H0;
  float* hbuf  = ws + OFF_HB;
  u16*   gbuf  = (u16*)(ws + OFF_GBUF);
  float* outqf = ws + OFF_OUTQF;
  float* wprep = ws + OFF_WPREP;
  int*   flag  = (int*)(wprep + 1536);
  u16*   ugbuf = (u16*)(ws + OFF_UG);
  u16*   lnq   = (u16*)(ws + OFF_LNQ);
  u16*   lnf   = (u16*)(ws + OFF_LNF);
  u16*   abuf  = (u16*)(ws + OFF_ABUF);
  u16*   aq    = (u16*)(ws + OFF_AQ);
  u16*   bkey  = (u16*)(ws + OFF_BKEY);
  u16*   bq    = (u16*)(ws + OFF_BQ);
  u16*   bok   = (u16*)(ws + OFF_BOK);
  u16*   boq   = (u16*)(ws + OFF_BOQ);
  u16*   b1w   = (u16*)(ws + OFF_B1W);
  u16*   b2w   = (u16*)(ws + OFF_B2W);

  void* out_q = d_out;
  void* out_feat_bf16 = (void*)((u16*)d_out + (size_t)BSZ_*NQ_*DM_);
  void* out_feat_f32  = (void*)((float*)d_out + (size_t)BSZ_*NQ_*DM_);

  // 1. setup: yacc zero + cast0 + detect/prep
  setup_kernel<<<1249, 256, 0, stream>>>(
      features, pos_embed, abuf, queries, query_pos, aq,
      key_proj_w, bkey, query_proj_w, bq,
      A_log, dt_bias, dist_w1, dist_b1, dist_w2, bc_proj_w, dt_proj_w, wprep,
      yacc, flag);

  // 2. kp = abuf @ bkey : (4096 x 1034), K=256
  kp_gemm_kernel<<<dim3(64, 17), 256, 0, stream>>>(abuf, bkey, kp);

  // 3. conv + qproj GEMM
  convqp_kernel<<<4096 + 32, 256, 0, stream>>>(
      flag, kp, key_conv_w, key_conv_b, xact, aq, bq, qproj);

  // 4. dist
  dist_kernel<<<BSZ_*LSEQ_/2, 256, 0, stream>>>(flag, anchors, key_pos, kp, xact,
                                                wprep, aw, carr);

  // 5. s1 merged
  s1m_kernel<<<dim3(4, NCHUNK_, BSZ_*NH_), 256, 0, stream>>>(aw, xact, send, ptot);

  // 6. s2
  s2_kernel<<<1024, 256, 0, stream>>>(qproj, ptot, send, h0buf, hbuf);

  // 7. s3 (dual-direction blocks, R9 inner loop) + cast1
  s3cast_kernel<<<1024 + 256, 512, 0, stream>>>(
      flag, aw, carr, xact, h0buf, yacc,
      out_key_proj_w, bok, out_query_proj_w, boq, ffn_fc1_w, b1w, ffn_fc2_w, b2w);

  // 8. g + lnq
  glnq_kernel<<<4096 + 256, 256, 0, stream>>>(
      flag, yacc, xact, kp, Dvec, key_norm_w, gbuf,
      hbuf, query_norm_w, query_norm_b, lnq);

  // 9. out_feat GEMM + outq GEMM
  ofoq_kernel<<<256 + 16, 256, 0, stream>>>(
      flag, gbuf, bok, out_feat_f32, out_feat_bf16, features,
      lnq, boq, outqf, queries);

  // 10. lnf
  lnf_kernel<<<BSZ_*NQ_, 256, 0, stream>>>(flag, outqf, ffn_norm_w, ffn_norm_b, lnf);

  // 11. fc1 + gelu fused: ug = gelu(a)*v
  fc1g_kernel<<<dim3(4, 16), 256, 0, stream>>>(flag, lnf, b1w, ffn_fc1_b, ugbuf);

  // 12. fc2: out_q = outqf + ug @ b2w + b2
  fc2_kernel<<<16, 256, 0, stream>>>(flag, ugbuf, b2w, out_q, outqf, ffn_fc2_b);
}

// Round 13
// 443.411 us; speedup vs baseline: 1.2920x; 1.0073x over previous
//
#include <hip/hip_runtime.h>

typedef unsigned short u16;
typedef __bf16 bf16x8 __attribute__((ext_vector_type(8)));
typedef u16 u16x8 __attribute__((ext_vector_type(8)));
typedef float f32x4 __attribute__((ext_vector_type(4)));

#define BSZ_ 2
#define NQ_ 128
#define LSEQ_ 2048
#define DM_ 256
#define DI_ 512
#define NH_ 8
#define HD_ 64
#define DKEY_ 1034
#define DCV_ 514
#define NCHUNK_ 16
#define CT_ 128   // chunk length

__device__ __forceinline__ float bf2f(u16 u) {
  unsigned v = ((unsigned)u) << 16;
  return __builtin_bit_cast(float, v);
}
__device__ __forceinline__ u16 f2bf(float f) {
  unsigned u = __builtin_bit_cast(unsigned, f);
  u += 0x7fffu + ((u >> 16) & 1u);
  return (u16)(u >> 16);
}
__device__ __forceinline__ float sigmoidf_(float x) { return 1.f / (1.f + expf(-x)); }
__device__ __forceinline__ float softplusf_(float x) {
  return (x > 20.f) ? x : log1pf(expf(x));
}

template<bool F32>
__device__ __forceinline__ float ldi(const void* p, size_t i) {
  return F32 ? ((const float*)p)[i] : bf2f(((const u16*)p)[i]);
}
template<bool F32>
__device__ __forceinline__ void sto(void* p, size_t i, float v) {
  if (F32) ((float*)p)[i] = v;
  else ((u16*)p)[i] = f2bf(v);
}

// per-wave dtype detection (all waves read same 64 u16s -> uniform result)
__device__ __forceinline__ bool detect_f32(const void* feat) {
  int lane = threadIdx.x & 63;
  float a = fabsf(bf2f(((const u16*)feat)[2*lane]));
  bool plaus = (a > 1e-6f) && (a < 1e6f);
  unsigned long long m = __ballot(plaus);
  return __popcll(m) < 32;   // true => fp32 storage
}

// ---------------- workspace layout (float units) ----------------
constexpr size_t SZ_KP    = (size_t)BSZ_*LSEQ_*DKEY_;
constexpr size_t SZ_XACT  = (size_t)BSZ_*LSEQ_*DCV_;
constexpr size_t SZ_AW    = (size_t)BSZ_*NH_*LSEQ_*NQ_*2;
constexpr size_t SZ_CARR  = (size_t)BSZ_*LSEQ_*NQ_;
constexpr size_t SZ_QPROJ = (size_t)BSZ_*NQ_*DI_;
constexpr size_t SZ_YACC  = (size_t)BSZ_*LSEQ_*DI_;
constexpr size_t SZ_SEND  = (size_t)BSZ_*NH_*2*NCHUNK_*NQ_*HD_;
constexpr size_t SZ_PTOT  = (size_t)BSZ_*NH_*2*NCHUNK_*NQ_;
constexpr size_t SZ_H0    = SZ_SEND;
constexpr size_t SZ_HB    = (size_t)BSZ_*NH_*2*NQ_*HD_;
constexpr size_t SZ_GBUF  = (size_t)BSZ_*LSEQ_*DI_/2;
constexpr size_t SZ_OUTQF = (size_t)BSZ_*NQ_*DM_;
constexpr size_t SZ_WPREP = 2048;

constexpr size_t OFF_KP    = 0;
constexpr size_t OFF_XACT  = OFF_KP + SZ_KP;
constexpr size_t OFF_AW    = OFF_XACT + SZ_XACT;
constexpr size_t OFF_CARR  = OFF_AW + SZ_AW;
constexpr size_t OFF_QPROJ = OFF_CARR + SZ_CARR;
constexpr size_t OFF_YACC  = OFF_QPROJ + SZ_QPROJ;
constexpr size_t OFF_SEND  = OFF_YACC + SZ_YACC;
constexpr size_t OFF_PTOT  = OFF_SEND + SZ_SEND;
constexpr size_t OFF_H0    = OFF_PTOT + SZ_PTOT;
constexpr size_t OFF_HB    = OFF_H0 + SZ_H0;
constexpr size_t OFF_GBUF  = OFF_HB + SZ_HB;
constexpr size_t OFF_OUTQF = OFF_GBUF + SZ_GBUF;
constexpr size_t OFF_WPREP = OFF_OUTQF + SZ_OUTQF;
constexpr size_t WS_FLOATS = OFF_WPREP + SZ_WPREP;

// FFN/outq scratch aliases into AW (dead after s3):
constexpr size_t OFF_UG  = OFF_AW;                         // 256x1024 bf16
constexpr size_t OFF_LNQ = OFF_UG + (size_t)256*1024/2;    // 256x512 bf16
constexpr size_t OFF_LNF = OFF_LNQ + (size_t)256*512/2;    // 256x256 bf16

// Transient bf16 cast buffers alias SEND (dead until s1 writes it):
constexpr size_t OFF_ABUF = OFF_SEND;                         // 4096x256 bf16
constexpr size_t OFF_AQ   = OFF_ABUF + (size_t)4096*256/2;
constexpr size_t OFF_BKEY = OFF_AQ + (size_t)256*256/2;
constexpr size_t OFF_BQ   = OFF_BKEY + (size_t)(256*1034+1)/2 + 1;
// Late bf16 weight casts alias SEND (dead after s2):
constexpr size_t OFF_BOK  = OFF_SEND;
constexpr size_t OFF_BOQ  = OFF_BOK + (size_t)512*256/2;
constexpr size_t OFF_B1W  = OFF_BOQ + (size_t)512*256/2;
constexpr size_t OFF_B2W  = OFF_B1W + (size_t)256*2048/2;

// wprep layout: [0..7] A=-exp(A_log); [8..15] dt_bias; [32..287] w1b; [288..1311] w2;
// [1312..1343] bc_proj; [1344..1471] dt_proj
template<bool F32>
__device__ void prep_body(const void* A_log, const void* dt_bias,
                          const void* w1, const void* b1, const void* w2,
                          const void* bcw, const void* dtw, float* wp) {
  int t = threadIdx.x;
  if (t < 8) {
    wp[t]     = -expf(ldi<F32>(A_log, t));
    wp[8 + t] = ldi<F32>(dt_bias, t);
  }
  if (t < 64) {
    wp[32 + t*4 + 0] = ldi<F32>(w1, 0*64 + t);
    wp[32 + t*4 + 1] = ldi<F32>(w1, 1*64 + t);
    wp[32 + t*4 + 2] = ldi<F32>(w1, 2*64 + t);
    wp[32 + t*4 + 3] = ldi<F32>(b1, t);
  }
  for (int i = t; i < 1024; i += 256) wp[288 + i] = ldi<F32>(w2, i);
  if (t < 32)  wp[1312 + t] = ldi<F32>(bcw, t);
  if (t < 128) wp[1344 + t] = ldi<F32>(dtw, t);
}

// cast helper: d[i] = bf16(s0[i] (+ s1_[i]))
__device__ __forceinline__ void cast_job(bool F32, const void* s0, const void* s1_,
                                         u16* d, size_t n, size_t base, size_t stride) {
  for (size_t i = base; i < n; i += stride) {
    float v = F32 ? ((const float*)s0)[i] : bf2f(((const u16*)s0)[i]);
    if (s1_) v += F32 ? ((const float*)s1_)[i] : bf2f(((const u16*)s1_)[i]);
    d[i] = f2bf(v);
  }
}

// ---------------- setup: yacc zero + cast0 + detect/prep (fused) ----------------
__global__ __launch_bounds__(256) void setup_kernel(
    const void* feat, const void* pe, u16* abuf,
    const void* q, const void* qp, u16* aq,
    const void* kw, u16* bkey, const void* qw, u16* bq,
    const void* A_log, const void* dt_bias, const void* w1, const void* b1,
    const void* w2, const void* bcw, const void* dtw, float* wp,
    float* yacc, int* flag)
{
  int bx = blockIdx.x, tid = threadIdx.x;
  if (bx < 512) {                       // yacc zero: 512 blocks x 4096 floats
    size_t base = (size_t)bx * 4096 + tid;
#pragma unroll
    for (int k = 0; k < 16; ++k) yacc[base + (size_t)k*256] = 0.f;
    return;
  }
  bool F32 = detect_f32(feat);
  if (bx < 1024) {                      // abuf = bf16(features + pos_embed)
    cast_job(F32, feat, pe, abuf, (size_t)4096*256,
             (size_t)(bx-512)*256 + tid, (size_t)512*256);
  } else if (bx < 1056) {               // aq = bf16(queries + query_pos)
    cast_job(F32, q, qp, aq, (size_t)256*256,
             (size_t)(bx-1024)*256 + tid, (size_t)32*256);
  } else if (bx < 1184) {               // bkey = bf16(key_proj_w)
    cast_job(F32, kw, nullptr, bkey, (size_t)256*1034,
             (size_t)(bx-1056)*256 + tid, (size_t)128*256);
  } else if (bx < 1248) {               // bq = bf16(query_proj_w)
    cast_job(F32, qw, nullptr, bq, (size_t)256*512,
             (size_t)(bx-1184)*256 + tid, (size_t)64*256);
  } else {                              // detect-store + prep
    if (tid == 0) *flag = F32 ? 1 : 0;
    if (F32) prep_body<true>(A_log, dt_bias, w1, b1, w2, bcw, dtw, wp);
    else     prep_body<false>(A_log, dt_bias, w1, b1, w2, bcw, dtw, wp);
  }
}

// ---------------- MFMA GEMM body (Bs padded 40->42: kills 8-way bank conflict
// on B-tile staging stores; write stride 21 banks -> 2-way aliasing = free) ----
template<int A_MODE, int B_MODE, int OUT_EXT, int RES_EXT, int RES_F32, int BIAS, bool F32>
__device__ void gemm_body(int bm, int bn,
                          const void* A0, const void* A1, const void* Bw,
                          float* Cf, void* Cext, const void* ResE,
                          const float* ResF, const void* Bias,
                          int M, int N, int K) {
  __shared__ u16 As[64][40];
  __shared__ u16 Bs[64][42];
  int tid = threadIdx.x;
  int w = tid >> 6, lane = tid & 63;
  f32x4 acc[4];
#pragma unroll
  for (int j = 0; j < 4; ++j) acc[j] = (f32x4){0.f, 0.f, 0.f, 0.f};

  int arow = tid >> 2, aseg = (tid & 3) * 8;
  int bkl = tid >> 3, bns = (tid & 7) * 8;

  for (int k0 = 0; k0 < K; k0 += 32) {
    {
      size_t abase = (size_t)(bm + arow) * K + k0 + aseg;
      u16x8 tv;
      if (A_MODE == 0) {
#pragma unroll
        for (int i = 0; i < 8; ++i)
          tv[i] = f2bf(ldi<F32>(A0, abase + i) + ldi<F32>(A1, abase + i));
      } else {
        const u16* pa = (const u16*)A0 + abase;
#pragma unroll
        for (int i = 0; i < 8; ++i) tv[i] = pa[i];
      }
      *(u16x8*)&As[arow][aseg] = tv;
    }
    {
      size_t bbase = (size_t)(k0 + bkl) * N + bn + bns;
#pragma unroll
      for (int i = 0; i < 8; ++i) {
        u16 v;
        if (bn + bns + i < N) {
          if (B_MODE == 1) v = ((const u16*)Bw)[bbase + i];
          else             v = f2bf(ldi<F32>(Bw, bbase + i));
        } else v = (u16)0;
        Bs[bns + i][bkl] = v;
      }
    }
    __syncthreads();
    int mrow = w * 16 + (lane & 15);
    int kq = (lane >> 4) * 8;
    bf16x8 af = __builtin_bit_cast(bf16x8, *(const u16x8*)&As[mrow][kq]);
#pragma unroll
    for (int j = 0; j < 4; ++j) {
      bf16x8 bfv = __builtin_bit_cast(bf16x8, *(const u16x8*)&Bs[j*16 + (lane & 15)][kq]);
      acc[j] = __builtin_amdgcn_mfma_f32_16x16x32_bf16(af, bfv, acc[j], 0, 0, 0);
    }
    __syncthreads();
  }
  int col0 = lane & 15, rbase = (lane >> 4) * 4;
#pragma unroll
  for (int j = 0; j < 4; ++j) {
#pragma unroll
    for (int r = 0; r < 4; ++r) {
      int row = bm + w * 16 + rbase + r;
      int col = bn + j * 16 + col0;
      if (col < N) {
        size_t idx = (size_t)row * N + col;
        float v = acc[j][r];
        if (BIAS)    v += ldi<F32>(Bias, col);
        if (RES_EXT) v += ldi<F32>(ResE, idx);
        if (RES_F32) v += ResF[idx];
        if (OUT_EXT) sto<F32>(Cext, idx, v);
        else         Cf[idx] = v;
      }
    }
  }
}

// kp = abuf @ bkey (all-internal bf16, fp32 out)
__global__ __launch_bounds__(256) void kp_gemm_kernel(
    const u16* abuf, const u16* bkey, float* kp) {
  gemm_body<1,1,0,0,0,0,false>(blockIdx.x*64, blockIdx.y*64, abuf, nullptr, bkey,
                               kp, nullptr, nullptr, nullptr, nullptr,
                               4096, DKEY_, DM_);
}

// fc2: out_q = outqf + ug @ b2w + b2
template<bool F32>
__device__ void fc2_body(const u16* ug, const u16* b2w, void* out_q,
                         const float* outqf, const void* b2) {
  gemm_body<1,1,1,0,1,1,F32>((blockIdx.x&3)*64, (blockIdx.x>>2)*64, ug, nullptr,
                             b2w, nullptr, out_q, nullptr, outqf, b2,
                             BSZ_*NQ_, DM_, 1024);
}
__global__ __launch_bounds__(256) void fc2_kernel(
    const int* fl, const u16* ug, const u16* b2w, void* out_q,
    const float* outqf, const void* b2) {
  if (*fl) fc2_body<true>(ug, b2w, out_q, outqf, b2);
  else     fc2_body<false>(ug, b2w, out_q, outqf, b2);
}

// ---------------- conv + qproj GEMM (fused, independent blocks) ----------------
template<bool F32>
__device__ void conv_body(const float* kp, const void* cw, const void* cb,
                          float* xact) {
  int row = blockIdx.x;
  int l = row & (LSEQ_ - 1);
  for (int ch = threadIdx.x; ch < DCV_; ch += 256) {
    float acc = ldi<F32>(cb, ch);
#pragma unroll
    for (int k = 0; k < 4; ++k) {
      int ll = l - 3 + k;
      if (ll >= 0)
        acc = fmaf(ldi<F32>(cw, ch*4 + k), kp[(size_t)(row - 3 + k)*DKEY_ + DI_ + ch], acc);
    }
    xact[(size_t)row*DCV_ + ch] = acc * sigmoidf_(acc);
  }
}
__global__ __launch_bounds__(256) void convqp_kernel(
    const int* fl, const float* kp, const void* cw, const void* cb, float* xact,
    const u16* aq, const u16* bq, float* qproj)
{
  int bx = blockIdx.x;
  if (bx < 4096) {
    if (*fl) conv_body<true>(kp, cw, cb, xact);
    else     conv_body<false>(kp, cw, cb, xact);
  } else {
    int i = bx - 4096;   // 32 blocks: M=256 (4 tiles) x N=512 (8 tiles)
    gemm_body<1,1,0,0,0,0,false>((i&3)*64, (i>>2)*64, aq, nullptr, bq,
                                 qproj, nullptr, nullptr, nullptr, nullptr,
                                 BSZ_*NQ_, DI_, DM_);
  }
}

// ---------------- dist MLP -> a, w, c ----------------
template<bool F32>
__device__ void dist_body(const void* anchors, const void* key_pos,
                          const float* kp, const float* xact, const float* wp,
                          float* aw, float* carr) {
  int tid = threadIdx.x;
  int n = tid & 127;
  int idx = blockIdx.x;
  int b = idx >> 10;
  int l = ((idx & 1023) << 1) | (tid >> 7);
  size_t row = (size_t)b * LSEQ_ + l;

  float enc0, enc1, enc2;
  {
    float e[3];
#pragma unroll
    for (int d = 0; d < 3; ++d) {
      float delta = ldi<F32>(anchors, (b*NQ_ + n)*3 + d) - ldi<F32>(key_pos, row*3 + d);
      float s = delta < 0.f ? -1.f : 1.f;
      e[d] = s * log2f(fabsf(delta) * 20.f + 1.f) * (1.f/12.f);
    }
    enc0 = e[0]; enc1 = e[1]; enc2 = e[2];
  }
  float feat[16];
#pragma unroll
  for (int f = 0; f < 16; ++f) feat[f] = 0.f;
  for (int j = 0; j < 64; ++j) {
    float w0 = wp[32 + j*4], w1v = wp[33 + j*4], w2v = wp[34 + j*4], bb = wp[35 + j*4];
    float hj = fmaxf(fmaf(enc0, w0, fmaf(enc1, w1v, fmaf(enc2, w2v, bb))), 0.f);
#pragma unroll
    for (int f = 0; f < 16; ++f) feat[f] = fmaf(hj, wp[288 + j*16 + f], feat[f]);
  }
  float bc0 = 0.f, bc1 = 0.f;
#pragma unroll
  for (int f = 0; f < 16; ++f) {
    bc0 = fmaf(feat[f], wp[1312 + f*2], bc0);
    bc1 = fmaf(feat[f], wp[1313 + f*2], bc1);
  }
  float bb_ = xact[row*DCV_ + DI_];
  float cb_ = xact[row*DCV_ + DI_ + 1];
  float Bs = bc0 + bb_, Cs = bc1 + cb_;
  carr[row*NQ_ + n] = Cs;

  float dtb[8];
#pragma unroll
  for (int h = 0; h < 8; ++h) dtb[h] = 0.f;
#pragma unroll
  for (int f = 0; f < 16; ++f)
#pragma unroll
    for (int h = 0; h < 8; ++h) dtb[h] = fmaf(feat[f], wp[1344 + f*8 + h], dtb[h]);

#pragma unroll
  for (int h = 0; h < 8; ++h) {
    float xln = dtb[h] + kp[row*DKEY_ + (DI_*2 + 2) + h] + wp[8 + h];
    float dtv = softplusf_(xln);
    float a = expf(dtv * wp[h]);
    float wv = dtv * Bs;
    size_t o = (((size_t)(b*NH_ + h)*LSEQ_ + l)*NQ_ + n)*2;
    aw[o] = a;
    aw[o + 1] = wv;
  }
}
__global__ __launch_bounds__(256) void dist_kernel(
    const int* fl, const void* anchors, const void* key_pos, const float* kp,
    const float* xact, const float* wp, float* aw, float* carr) {
  if (*fl) dist_body<true>(anchors, key_pos, kp, xact, wp, aw, carr);
  else     dist_body<false>(anchors, key_pos, kp, xact, wp, aw, carr);
}

// ---------------- scan phase 1 MERGED (R6-proven) ----------------
__global__ __launch_bounds__(256) void s1m_kernel(
    const float* __restrict__ aw, const float* __restrict__ xact,
    float* __restrict__ send, float* __restrict__ ptot)
{
  int tid = threadIdx.x;
  int hd = tid & 63;
  int w = __builtin_amdgcn_readfirstlane(tid >> 6);
  int ns = blockIdx.x, q = blockIdx.y, z = blockIdx.z;
  int h = z & 7, b = z >> 3;
  int n0 = __builtin_amdgcn_readfirstlane(ns*32 + w*8);

  float hf[8], hb[8], pr[8];
#pragma unroll
  for (int i = 0; i < 8; ++i) { hf[i] = 0.f; hb[i] = 0.f; pr[i] = 1.f; }

  size_t awbase = (size_t)z * LSEQ_ * (NQ_*2);
  int t = q*CT_;
  for (int s = 0; s < CT_; ++s, ++t) {
    const float* awt = aw + awbase + (size_t)t*(NQ_*2) + n0*2;
    float xv = xact[((size_t)(b*LSEQ_ + t))*DCV_ + (h << 6) + hd];
#pragma unroll
    for (int i = 0; i < 8; ++i) {
      float a = awt[2*i], wv = awt[2*i + 1];
      float wx = wv * xv;
      hf[i] = fmaf(hf[i], a, wx);
      hb[i] = fmaf(pr[i], wx, hb[i]);
      pr[i] *= a;
    }
  }
  size_t cbf = (size_t)((z*2 + 0)*NCHUNK_ + q);
  size_t cbb = (size_t)((z*2 + 1)*NCHUNK_ + (NCHUNK_ - 1 - q));
#pragma unroll
  for (int i = 0; i < 8; ++i) {
    send[cbf*(NQ_*HD_) + (size_t)(n0 + i)*HD_ + hd] = hf[i];
    send[cbb*(NQ_*HD_) + (size_t)(n0 + i)*HD_ + hd] = hb[i];
  }
  if (hd == 0) {
#pragma unroll
    for (int i = 0; i < 8; ++i) {
      ptot[cbf*NQ_ + n0 + i] = pr[i];
      ptot[cbb*NQ_ + n0 + i] = pr[i];
    }
  }
}

// ---------------- scan phase 2 ----------------
__global__ __launch_bounds__(256) void s2_kernel(
    const float* __restrict__ qproj, const float* __restrict__ ptot,
    const float* __restrict__ send, float* __restrict__ h0buf,
    float* __restrict__ hbuf)
{
  int g = blockIdx.x*256 + threadIdx.x;
  int hd = g & 63;
  int n = (g >> 6) & 127;
  int dir = (g >> 13) & 1;
  int h = (g >> 14) & 7;
  int b = g >> 17;
  float hcur = qproj[((size_t)(b*NQ_ + n))*DI_ + h*HD_ + hd];
  size_t base = (size_t)((b*NH_ + h)*2 + dir) * NCHUNK_;
  for (int q = 0; q < NCHUNK_; ++q) {
    size_t cb = base + q;
    h0buf[cb*(NQ_*HD_) + (size_t)n*HD_ + hd] = hcur;
    hcur = fmaf(hcur, ptot[cb*NQ_ + n], send[cb*(NQ_*HD_) + (size_t)n*HD_ + hd]);
  }
  hbuf[((size_t)((b*NH_ + h)*2 + dir))*(NQ_*HD_) + (size_t)n*HD_ + hd] = hcur;
}

// ---------------- scan phase 3 (R9-exact: the proven optimum) + cast1 ----------
template<bool F32>
__device__ void cast1_part(const void* okw, u16* bok, const void* oqw, u16* boq,
                           const void* w1, u16* b1w, const void* w2, u16* b2w) {
  int i = blockIdx.x - 2048;
  int job = i >> 7, bj = i & 127;
  size_t base = (size_t)bj*256 + threadIdx.x, stride = (size_t)128*256;
  switch (job) {
    case 0: cast_job(F32, okw, nullptr, bok, (size_t)512*256, base, stride); break;
    case 1: cast_job(F32, oqw, nullptr, boq, (size_t)512*256, base, stride); break;
    case 2: cast_job(F32, w1, nullptr, b1w, (size_t)256*2048, base, stride); break;
    default: cast_job(F32, w2, nullptr, b2w, (size_t)1024*256, base, stride); break;
  }
}
__global__ __launch_bounds__(256) void s3cast_kernel(
    const int* fl, const float* __restrict__ aw, const float* __restrict__ carr,
    const float* __restrict__ xact, const float* __restrict__ h0buf,
    float* __restrict__ yacc,
    const void* okw, u16* bok, const void* oqw, u16* boq,
    const void* w1, u16* b1w, const void* w2, u16* b2w)
{
  int bx = blockIdx.x;
  if (bx >= 2048) {
    if (*fl) cast1_part<true>(okw, bok, oqw, boq, w1, b1w, w2, b2w);
    else     cast1_part<false>(okw, bok, oqw, boq, w1, b1w, w2, b2w);
    return;
  }
  int tid = threadIdx.x;
  int hd = tid & 63;
  int w = __builtin_amdgcn_readfirstlane(tid >> 6);
  int ns = bx & 3, q = (bx >> 2) & 15, zz = bx >> 6;
  int dir = zz & 1, h = (zz >> 1) & 7, b = zz >> 4;
  int n0 = __builtin_amdgcn_readfirstlane(ns*32 + w*8);

  float hst[8];
  size_t cb = (size_t)(((b*NH_ + h)*2 + dir)*NCHUNK_ + q);
#pragma unroll
  for (int i = 0; i < 8; ++i)
    hst[i] = h0buf[cb*(NQ_*HD_) + (size_t)(n0 + i)*HD_ + hd];

  __shared__ float ybuf[2][4][64];
  size_t awbase = (size_t)(b*NH_ + h) * LSEQ_ * (NQ_*2);
  int tbase = dir ? (LSEQ_ - 1 - q*CT_) : (q*CT_);
  int tstep = dir ? -1 : 1;
  int t = tbase;
  for (int s = 0; s < CT_; ++s, t += tstep) {
    const float* awt = aw + awbase + (size_t)t*(NQ_*2) + n0*2;
    const float* ct = carr + ((size_t)(b*LSEQ_ + t))*NQ_ + n0;
    float xv = xact[((size_t)(b*LSEQ_ + t))*DCV_ + (h << 6) + hd];
    float ys = 0.f;
#pragma unroll
    for (int i = 0; i < 8; ++i) {
      hst[i] = fmaf(hst[i], awt[2*i], awt[2*i + 1] * xv);
      ys = fmaf(hst[i], ct[i], ys);
    }
    int p = s & 1;
    ybuf[p][w][hd] = ys;
    __syncthreads();
    if (w == 0) {
      float yv = ybuf[p][0][hd] + ybuf[p][1][hd] + ybuf[p][2][hd] + ybuf[p][3][hd];
      atomicAdd(&yacc[((size_t)(b*LSEQ_ + t))*DI_ + (h << 6) + hd], 0.5f * yv);
    }
  }
}

// ---------------- block reduction helper ----------------
__device__ __forceinline__ float block_sum256(float v, float* red) {
#pragma unroll
  for (int off = 32; off; off >>= 1) v += __shfl_xor(v, off, 64);
  int wv = threadIdx.x >> 6;
  if ((threadIdx.x & 63) == 0) red[wv] = v;
  __syncthreads();
  float t = red[0] + red[1] + red[2] + red[3];
  __syncthreads();
  return t;
}

// ---------------- g (gated RMSNorm) + lnq (fused) ----------------
template<bool F32>
__device__ void g_body(const float* yacc, const float* xact, const float* kp,
                       const void* Dv, const void* knw, u16* gbuf) {
  int row = blockIdx.x, tid = threadIdx.x;
  __shared__ float red[4];
  float gg[2];
  float ss = 0.f;
#pragma unroll
  for (int ii = 0; ii < 2; ++ii) {
    int ch = tid + ii*256;
    float yv = yacc[(size_t)row*DI_ + ch];
    float xv = xact[(size_t)row*DCV_ + ch];
    float zv = kp[(size_t)row*DKEY_ + ch];
    float Dh = ldi<F32>(Dv, ch >> 6);
    float yf = yv + 2.f * Dh * xv;
    float g = yf * (zv * sigmoidf_(zv));
    gg[ii] = g;
    ss += g * g;
  }
  float tot = block_sum256(ss, red);
  float r = rsqrtf(tot / (float)DI_ + 1e-5f);
#pragma unroll
  for (int ii = 0; ii < 2; ++ii) {
    int ch = tid + ii*256;
    gbuf[(size_t)row*DI_ + ch] = f2bf(gg[ii] * r * ldi<F32>(knw, ch));
  }
}
template<bool F32>
__device__ void lnq_body(const float* hbuf, const void* qnw, const void* qnb,
                         u16* lnq) {
  int row = blockIdx.x - 4096;
  int b = row >> 7, n = row & 127;
  int tid = threadIdx.x;
  __shared__ float red[4];
  float hv[2];
  float s1 = 0.f, s2 = 0.f;
#pragma unroll
  for (int ii = 0; ii < 2; ++ii) {
    int ch = tid + ii*256;
    int h = ch >> 6, hd = ch & 63;
    size_t base = ((size_t)((b*NH_ + h)*2))*(NQ_*HD_) + (size_t)n*HD_ + hd;
    float v = 0.5f * (hbuf[base] + hbuf[base + (size_t)NQ_*HD_]);
    hv[ii] = v;
    s1 += v;
    s2 += v * v;
  }
  s1 = block_sum256(s1, red);
  s2 = block_sum256(s2, red);
  float mean = s1 / (float)DI_;
  float var = fmaxf(s2 / (float)DI_ - mean * mean, 0.f);
  float rstd = rsqrtf(var + 1e-5f);
#pragma unroll
  for (int ii = 0; ii < 2; ++ii) {
    int ch = tid + ii*256;
    lnq[(size_t)row*DI_ + ch] =
        f2bf((hv[ii] - mean) * rstd * ldi<F32>(qnw, ch) + ldi<F32>(qnb, ch));
  }
}
__global__ __launch_bounds__(256) void glnq_kernel(
    const int* fl, const float* yacc, const float* xact, const float* kp,
    const void* Dv, const void* knw, u16* gbuf,
    const float* hbuf, const void* qnw, const void* qnb, u16* lnq)
{
  if (blockIdx.x < 4096) {
    if (*fl) g_body<true>(yacc, xact, kp, Dv, knw, gbuf);
    else     g_body<false>(yacc, xact, kp, Dv, knw, gbuf);
  } else {
    if (*fl) lnq_body<true>(hbuf, qnw, qnb, lnq);
    else     lnq_body<false>(hbuf, qnw, qnb, lnq);
  }
}

// ---------------- out_feat GEMM + outq GEMM (fused) ----------------
template<bool F32>
__device__ void ofoq_body(const u16* gbuf, const u16* bok, void* out_feat,
                          const void* features, const u16* lnq, const u16* boq,
                          float* outqf, const void* queries) {
  int bx = blockIdx.x;
  if (bx < 256) {   // out_feat: M=4096 (64 tiles) x N=256 (4 tiles), K=512
    gemm_body<1,1,1,1,0,0,F32>((bx>>2)*64, (bx&3)*64, gbuf, nullptr, bok,
                               nullptr, out_feat, features, nullptr, nullptr,
                               4096, DM_, DI_);
  } else {          // outq: M=256 (4) x N=256 (4), K=512
    int i = bx - 256;
    gemm_body<1,1,0,1,0,0,F32>((i&3)*64, (i>>2)*64, lnq, nullptr, boq,
                               outqf, nullptr, queries, nullptr, nullptr,
                               BSZ_*NQ_, DM_, DI_);
  }
}
__global__ __launch_bounds__(256) void ofoq_kernel(
    const int* fl, const u16* gbuf, const u16* bok,
    void* out_feat_f32, void* out_feat_bf16, const void* features,
    const u16* lnq, const u16* boq, float* outqf, const void* queries) {
  if (*fl) ofoq_body<true>(gbuf, bok, out_feat_f32, features, lnq, boq, outqf, queries);
  else     ofoq_body<false>(gbuf, bok, out_feat_bf16, features, lnq, boq, outqf, queries);
}

// ---------------- FFN LN -> lnf ----------------
template<bool F32>
__device__ void lnf_body(const float* outqf, const void* fnw, const void* fnb,
                         u16* lnf) {
  int row = blockIdx.x, tid = threadIdx.x;
  __shared__ float red[4];
  float x = outqf[(size_t)row*DM_ + tid];
  float s1 = block_sum256(x, red);
  float s2 = block_sum256(x * x, red);
  float mean = s1 / (float)DM_;
  float var = fmaxf(s2 / (float)DM_ - mean * mean, 0.f);
  float rstd = rsqrtf(var + 1e-5f);
  lnf[(size_t)row*DM_ + tid] =
      f2bf((x - mean) * rstd * ldi<F32>(fnw, tid) + ldi<F32>(fnb, tid));
}
__global__ __launch_bounds__(256) void lnf_kernel(
    const int* fl, const float* outqf, const void* fnw, const void* fnb, u16* lnf) {
  if (*fl) lnf_body<true>(outqf, fnw, fnb, lnf);
  else     lnf_body<false>(outqf, fnw, fnb, lnf);
}

// ---------------- fc1 + gelu fused: ug = gelu(lnf@W1a + b1a) * (lnf@W1v + b1v) ----
template<bool F32>
__device__ void fc1g_body(const u16* lnf, const u16* b1w, const void* b1, u16* ug) {
  __shared__ u16 As[64][40];
  __shared__ u16 BsA[64][42];
  __shared__ u16 BsV[64][42];
  int tid = threadIdx.x;
  int w = tid >> 6, lane = tid & 63;
  int bm = blockIdx.x * 64, bn = blockIdx.y * 64;   // bn in [0,1024)
  f32x4 accA[4], accV[4];
#pragma unroll
  for (int j = 0; j < 4; ++j) {
    accA[j] = (f32x4){0.f, 0.f, 0.f, 0.f};
    accV[j] = (f32x4){0.f, 0.f, 0.f, 0.f};
  }
  int arow = tid >> 2, aseg = (tid & 3) * 8;
  int bkl = tid >> 3, bns = (tid & 7) * 8;

  for (int k0 = 0; k0 < DM_; k0 += 32) {
    {
      size_t abase = (size_t)(bm + arow) * DM_ + k0 + aseg;
      const u16* pa = lnf + abase;
      u16x8 tv;
#pragma unroll
      for (int i = 0; i < 8; ++i) tv[i] = pa[i];
      *(u16x8*)&As[arow][aseg] = tv;
    }
    {
      size_t bbase = (size_t)(k0 + bkl) * 2048 + bn + bns;
#pragma unroll
      for (int i = 0; i < 8; ++i) {
        BsA[bns + i][bkl] = b1w[bbase + i];
        BsV[bns + i][bkl] = b1w[bbase + 1024 + i];
      }
    }
    __syncthreads();
    int mrow = w * 16 + (lane & 15);
    int kq = (lane >> 4) * 8;
    bf16x8 af = __builtin_bit_cast(bf16x8, *(const u16x8*)&As[mrow][kq]);
#pragma unroll
    for (int j = 0; j < 4; ++j) {
      bf16x8 ba = __builtin_bit_cast(bf16x8, *(const u16x8*)&BsA[j*16 + (lane & 15)][kq]);
      bf16x8 bv = __builtin_bit_cast(bf16x8, *(const u16x8*)&BsV[j*16 + (lane & 15)][kq]);
      accA[j] = __builtin_amdgcn_mfma_f32_16x16x32_bf16(af, ba, accA[j], 0, 0, 0);
      accV[j] = __builtin_amdgcn_mfma_f32_16x16x32_bf16(af, bv, accV[j], 0, 0, 0);
    }
    __syncthreads();
  }
  int col0 = lane & 15, rbase = (lane >> 4) * 4;
#pragma unroll
  for (int j = 0; j < 4; ++j) {
#pragma unroll
    for (int r = 0; r < 4; ++r) {
      int row = bm + w * 16 + rbase + r;
      int col = bn + j * 16 + col0;
      float a = accA[j][r] + ldi<F32>(b1, col);
      float v = accV[j][r] + ldi<F32>(b1, col + 1024);
      float ge = 0.5f * a * (1.f + erff(a * 0.70710678118f));
      ug[(size_t)row*1024 + col] = f2bf(ge * v);
    }
  }
}
__global__ __launch_bounds__(256) void fc1g_kernel(
    const int* fl, const u16* lnf, const u16* b1w, const void* b1, u16* ug) {
  if (*fl) fc1g_body<true>(lnf, b1w, b1, ug);
  else     fc1g_body<false>(lnf, b1w, b1, ug);
}

// ---------------- launch ----------------
extern "C" void kernel_launch(void* const* d_in, const int* in_sizes, int n_in,
                              void* d_out, int out_size, void* d_ws, size_t ws_size,
                              hipStream_t stream) {
  const void* queries        = d_in[0];
  const void* anchors        = d_in[1];
  const void* features       = d_in[2];
  const void* pos_embed      = d_in[3];
  const void* key_pos        = d_in[4];
  const void* query_pos      = d_in[5];
  const void* key_proj_w     = d_in[6];
  const void* key_conv_w     = d_in[7];
  const void* key_conv_b     = d_in[8];
  const void* query_proj_w   = d_in[9];
  const void* dist_w1        = d_in[10];
  const void* dist_b1        = d_in[11];
  const void* dist_w2        = d_in[12];
  const void* bc_proj_w      = d_in[13];
  const void* dt_proj_w      = d_in[14];
  const void* dt_bias        = d_in[15];
  const void* A_log          = d_in[16];
  const void* Dvec           = d_in[17];
  const void* key_norm_w     = d_in[18];
  const void* out_key_proj_w = d_in[19];
  const void* query_norm_w   = d_in[20];
  const void* query_norm_b   = d_in[21];
  const void* out_query_proj_w = d_in[22];
  const void* ffn_norm_w     = d_in[23];
  const void* ffn_norm_b     = d_in[24];
  const void* ffn_fc1_w      = d_in[25];
  const void* ffn_fc1_b      = d_in[26];
  const void* ffn_fc2_w      = d_in[27];
  const void* ffn_fc2_b      = d_in[28];

  if (ws_size < WS_FLOATS * sizeof(float)) return;

  float* ws    = (float*)d_ws;
  float* kp    = ws + OFF_KP;
  float* xact  = ws + OFF_XACT;
  float* aw    = ws + OFF_AW;
  float* carr  = ws + OFF_CARR;
  float* qproj = ws + OFF_QPROJ;
  float* yacc  = ws + OFF_YACC;
  float* send  = ws + OFF_SEND;
  float* ptot  = ws + OFF_PTOT;
  float* h0buf = ws + OFF_H0;
  float* hbuf  = ws + OFF_HB;
  u16*   gbuf  = (u16*)(ws + OFF_GBUF);
  float* outqf = ws + OFF_OUTQF;
  float* wprep = ws + OFF_WPREP;
  int*   flag  = (int*)(wprep + 1536);
  u16*   ugbuf = (u16*)(ws + OFF_UG);
  u16*   lnq   = (u16*)(ws + OFF_LNQ);
  u16*   lnf   = (u16*)(ws + OFF_LNF);
  u16*   abuf  = (u16*)(ws + OFF_ABUF);
  u16*   aq    = (u16*)(ws + OFF_AQ);
  u16*   bkey  = (u16*)(ws + OFF_BKEY);
  u16*   bq    = (u16*)(ws + OFF_BQ);
  u16*   bok   = (u16*)(ws + OFF_BOK);
  u16*   boq   = (u16*)(ws + OFF_BOQ);
  u16*   b1w   = (u16*)(ws + OFF_B1W);
  u16*   b2w   = (u16*)(ws + OFF_B2W);

  void* out_q = d_out;
  void* out_feat_bf16 = (void*)((u16*)d_out + (size_t)BSZ_*NQ_*DM_);
  void* out_feat_f32  = (void*)((float*)d_out + (size_t)BSZ_*NQ_*DM_);

  // 1. setup: yacc zero + cast0 + detect/prep
  setup_kernel<<<1249, 256, 0, stream>>>(
      features, pos_embed, abuf, queries, query_pos, aq,
      key_proj_w, bkey, query_proj_w, bq,
      A_log, dt_bias, dist_w1, dist_b1, dist_w2, bc_proj_w, dt_proj_w, wprep,
      yacc, flag);

  // 2. kp = abuf @ bkey : (4096 x 1034), K=256
  kp_gemm_kernel<<<dim3(64, 17), 256, 0, stream>>>(abuf, bkey, kp);

  // 3. conv + qproj GEMM
  convqp_kernel<<<4096 + 32, 256, 0, stream>>>(
      flag, kp, key_conv_w, key_conv_b, xact, aq, bq, qproj);

  // 4. dist
  dist_kernel<<<BSZ_*LSEQ_/2, 256, 0, stream>>>(flag, anchors, key_pos, kp, xact,
                                                wprep, aw, carr);

  // 5. s1 merged
  s1m_kernel<<<dim3(4, NCHUNK_, BSZ_*NH_), 256, 0, stream>>>(aw, xact, send, ptot);

  // 6. s2
  s2_kernel<<<1024, 256, 0, stream>>>(qproj, ptot, send, h0buf, hbuf);

  // 7. s3 (R9-exact) + cast1
  s3cast_kernel<<<2048 + 512, 256, 0, stream>>>(
      flag, aw, carr, xact, h0buf, yacc,
      out_key_proj_w, bok, out_query_proj_w, boq, ffn_fc1_w, b1w, ffn_fc2_w, b2w);

  // 8. g + lnq
  glnq_kernel<<<4096 + 256, 256, 0, stream>>>(
      flag, yacc, xact, kp, Dvec, key_norm_w, gbuf,
      hbuf, query_norm_w, query_norm_b, lnq);

  // 9. out_feat GEMM + outq GEMM
  ofoq_kernel<<<256 + 16, 256, 0, stream>>>(
      flag, gbuf, bok, out_feat_f32, out_feat_bf16, features,
      lnq, boq, outqf, queries);

  // 10. lnf
  lnf_kernel<<<BSZ_*NQ_, 256, 0, stream>>>(flag, outqf, ffn_norm_w, ffn_norm_b, lnf);

  // 11. fc1 + gelu fused: ug = gelu(a)*v
  fc1g_kernel<<<dim3(4, 16), 256, 0, stream>>>(flag, lnf, b1w, ffn_fc1_b, ugbuf);

  // 12. fc2: out_q = outqf + ug @ b2w + b2
  fc2_kernel<<<16, 256, 0, stream>>>(flag, ugbuf, b2w, out_q, outqf, ffn_fc2_b);
}

// Round 14
// 435.489 us; speedup vs baseline: 1.3155x; 1.0182x over previous
//
#include <hip/hip_runtime.h>

typedef unsigned short u16;
typedef __bf16 bf16x8 __attribute__((ext_vector_type(8)));
typedef u16 u16x8 __attribute__((ext_vector_type(8)));
typedef float f32x4 __attribute__((ext_vector_type(4)));

#define BSZ_ 2
#define NQ_ 128
#define LSEQ_ 2048
#define DM_ 256
#define DI_ 512
#define NH_ 8
#define HD_ 64
#define DKEY_ 1034
#define DCV_ 514
#define NCHUNK_ 16
#define CT_ 128   // chunk length

__device__ __forceinline__ float bf2f(u16 u) {
  unsigned v = ((unsigned)u) << 16;
  return __builtin_bit_cast(float, v);
}
__device__ __forceinline__ u16 f2bf(float f) {
  unsigned u = __builtin_bit_cast(unsigned, f);
  u += 0x7fffu + ((u >> 16) & 1u);
  return (u16)(u >> 16);
}
__device__ __forceinline__ float sigmoidf_(float x) { return 1.f / (1.f + expf(-x)); }
__device__ __forceinline__ float softplusf_(float x) {
  return (x > 20.f) ? x : log1pf(expf(x));
}

template<bool F32>
__device__ __forceinline__ float ldi(const void* p, size_t i) {
  return F32 ? ((const float*)p)[i] : bf2f(((const u16*)p)[i]);
}
template<bool F32>
__device__ __forceinline__ void sto(void* p, size_t i, float v) {
  if (F32) ((float*)p)[i] = v;
  else ((u16*)p)[i] = f2bf(v);
}

// per-wave dtype detection (all waves read same 64 u16s -> uniform result)
__device__ __forceinline__ bool detect_f32(const void* feat) {
  int lane = threadIdx.x & 63;
  float a = fabsf(bf2f(((const u16*)feat)[2*lane]));
  bool plaus = (a > 1e-6f) && (a < 1e6f);
  unsigned long long m = __ballot(plaus);
  return __popcll(m) < 32;   // true => fp32 storage
}

// ---------------- workspace layout (float units) ----------------
constexpr size_t SZ_KP    = (size_t)BSZ_*LSEQ_*DKEY_;
constexpr size_t SZ_XACT  = (size_t)BSZ_*LSEQ_*DCV_;
constexpr size_t SZ_AW    = (size_t)BSZ_*NH_*LSEQ_*NQ_*2;
constexpr size_t SZ_CARR  = (size_t)BSZ_*LSEQ_*NQ_;
constexpr size_t SZ_QPROJ = (size_t)BSZ_*NQ_*DI_;
constexpr size_t SZ_YACC  = (size_t)BSZ_*LSEQ_*DI_;
constexpr size_t SZ_SEND  = (size_t)BSZ_*NH_*2*NCHUNK_*NQ_*HD_;
constexpr size_t SZ_PTOT  = (size_t)BSZ_*NH_*2*NCHUNK_*NQ_;
constexpr size_t SZ_H0    = SZ_SEND;
constexpr size_t SZ_HB    = (size_t)BSZ_*NH_*2*NQ_*HD_;
constexpr size_t SZ_GBUF  = (size_t)BSZ_*LSEQ_*DI_/2;
constexpr size_t SZ_OUTQF = (size_t)BSZ_*NQ_*DM_;
constexpr size_t SZ_WPREP = 2048;

constexpr size_t OFF_KP    = 0;
constexpr size_t OFF_XACT  = OFF_KP + SZ_KP;
constexpr size_t OFF_AW    = OFF_XACT + SZ_XACT;
constexpr size_t OFF_CARR  = OFF_AW + SZ_AW;
constexpr size_t OFF_QPROJ = OFF_CARR + SZ_CARR;
constexpr size_t OFF_YACC  = OFF_QPROJ + SZ_QPROJ;
constexpr size_t OFF_SEND  = OFF_YACC + SZ_YACC;
constexpr size_t OFF_PTOT  = OFF_SEND + SZ_SEND;
constexpr size_t OFF_H0    = OFF_PTOT + SZ_PTOT;
constexpr size_t OFF_HB    = OFF_H0 + SZ_H0;
constexpr size_t OFF_GBUF  = OFF_HB + SZ_HB;
constexpr size_t OFF_OUTQF = OFF_GBUF + SZ_GBUF;
constexpr size_t OFF_WPREP = OFF_OUTQF + SZ_OUTQF;
constexpr size_t WS_FLOATS = OFF_WPREP + SZ_WPREP;

// FFN/outq scratch aliases into AW (dead after s3):
constexpr size_t OFF_UG  = OFF_AW;                         // 256x1024 bf16
constexpr size_t OFF_LNQ = OFF_UG + (size_t)256*1024/2;    // 256x512 bf16
constexpr size_t OFF_LNF = OFF_LNQ + (size_t)256*512/2;    // 256x256 bf16

// Transient bf16 cast buffers alias SEND (dead until s1 writes it):
constexpr size_t OFF_ABUF = OFF_SEND;                         // 4096x256 bf16
constexpr size_t OFF_AQ   = OFF_ABUF + (size_t)4096*256/2;
constexpr size_t OFF_BKEY = OFF_AQ + (size_t)256*256/2;
constexpr size_t OFF_BQ   = OFF_BKEY + (size_t)(256*1034+1)/2 + 1;
// Late bf16 weight casts alias SEND (dead after s2):
constexpr size_t OFF_BOK  = OFF_SEND;
constexpr size_t OFF_BOQ  = OFF_BOK + (size_t)512*256/2;
constexpr size_t OFF_B1W  = OFF_BOQ + (size_t)512*256/2;
constexpr size_t OFF_B2W  = OFF_B1W + (size_t)256*2048/2;

// wprep layout: [0..7] A=-exp(A_log); [8..15] dt_bias; [32..287] w1b; [288..1311] w2;
// [1312..1343] bc_proj; [1344..1471] dt_proj
template<bool F32>
__device__ void prep_body(const void* A_log, const void* dt_bias,
                          const void* w1, const void* b1, const void* w2,
                          const void* bcw, const void* dtw, float* wp) {
  int t = threadIdx.x;
  if (t < 8) {
    wp[t]     = -expf(ldi<F32>(A_log, t));
    wp[8 + t] = ldi<F32>(dt_bias, t);
  }
  if (t < 64) {
    wp[32 + t*4 + 0] = ldi<F32>(w1, 0*64 + t);
    wp[32 + t*4 + 1] = ldi<F32>(w1, 1*64 + t);
    wp[32 + t*4 + 2] = ldi<F32>(w1, 2*64 + t);
    wp[32 + t*4 + 3] = ldi<F32>(b1, t);
  }
  for (int i = t; i < 1024; i += 256) wp[288 + i] = ldi<F32>(w2, i);
  if (t < 32)  wp[1312 + t] = ldi<F32>(bcw, t);
  if (t < 128) wp[1344 + t] = ldi<F32>(dtw, t);
}

// cast helper: d[i] = bf16(s0[i] (+ s1_[i]))
__device__ __forceinline__ void cast_job(bool F32, const void* s0, const void* s1_,
                                         u16* d, size_t n, size_t base, size_t stride) {
  for (size_t i = base; i < n; i += stride) {
    float v = F32 ? ((const float*)s0)[i] : bf2f(((const u16*)s0)[i]);
    if (s1_) v += F32 ? ((const float*)s1_)[i] : bf2f(((const u16*)s1_)[i]);
    d[i] = f2bf(v);
  }
}

// ---------------- setup: yacc zero + cast0 + detect/prep (fused) ----------------
__global__ __launch_bounds__(256) void setup_kernel(
    const void* feat, const void* pe, u16* abuf,
    const void* q, const void* qp, u16* aq,
    const void* kw, u16* bkey, const void* qw, u16* bq,
    const void* A_log, const void* dt_bias, const void* w1, const void* b1,
    const void* w2, const void* bcw, const void* dtw, float* wp,
    float* yacc, int* flag)
{
  int bx = blockIdx.x, tid = threadIdx.x;
  if (bx < 512) {                       // yacc zero: 512 blocks x 4096 floats
    size_t base = (size_t)bx * 4096 + tid;
#pragma unroll
    for (int k = 0; k < 16; ++k) yacc[base + (size_t)k*256] = 0.f;
    return;
  }
  bool F32 = detect_f32(feat);
  if (bx < 1024) {                      // abuf = bf16(features + pos_embed)
    cast_job(F32, feat, pe, abuf, (size_t)4096*256,
             (size_t)(bx-512)*256 + tid, (size_t)512*256);
  } else if (bx < 1056) {               // aq = bf16(queries + query_pos)
    cast_job(F32, q, qp, aq, (size_t)256*256,
             (size_t)(bx-1024)*256 + tid, (size_t)32*256);
  } else if (bx < 1184) {               // bkey = bf16(key_proj_w)
    cast_job(F32, kw, nullptr, bkey, (size_t)256*1034,
             (size_t)(bx-1056)*256 + tid, (size_t)128*256);
  } else if (bx < 1248) {               // bq = bf16(query_proj_w)
    cast_job(F32, qw, nullptr, bq, (size_t)256*512,
             (size_t)(bx-1184)*256 + tid, (size_t)64*256);
  } else {                              // detect-store + prep
    if (tid == 0) *flag = F32 ? 1 : 0;
    if (F32) prep_body<true>(A_log, dt_bias, w1, b1, w2, bcw, dtw, wp);
    else     prep_body<false>(A_log, dt_bias, w1, b1, w2, bcw, dtw, wp);
  }
}

// ---------------- MFMA GEMM body (Bs padded to 42: bank-conflict-free) ----------
template<int A_MODE, int B_MODE, int OUT_EXT, int RES_EXT, int RES_F32, int BIAS, bool F32>
__device__ void gemm_body(int bm, int bn,
                          const void* A0, const void* A1, const void* Bw,
                          float* Cf, void* Cext, const void* ResE,
                          const float* ResF, const void* Bias,
                          int M, int N, int K) {
  __shared__ u16 As[64][40];
  __shared__ u16 Bs[64][42];
  int tid = threadIdx.x;
  int w = tid >> 6, lane = tid & 63;
  f32x4 acc[4];
#pragma unroll
  for (int j = 0; j < 4; ++j) acc[j] = (f32x4){0.f, 0.f, 0.f, 0.f};

  int arow = tid >> 2, aseg = (tid & 3) * 8;
  int bkl = tid >> 3, bns = (tid & 7) * 8;

  for (int k0 = 0; k0 < K; k0 += 32) {
    {
      size_t abase = (size_t)(bm + arow) * K + k0 + aseg;
      u16x8 tv;
      if (A_MODE == 0) {
#pragma unroll
        for (int i = 0; i < 8; ++i)
          tv[i] = f2bf(ldi<F32>(A0, abase + i) + ldi<F32>(A1, abase + i));
      } else {
        const u16* pa = (const u16*)A0 + abase;
#pragma unroll
        for (int i = 0; i < 8; ++i) tv[i] = pa[i];
      }
      *(u16x8*)&As[arow][aseg] = tv;
    }
    {
      size_t bbase = (size_t)(k0 + bkl) * N + bn + bns;
#pragma unroll
      for (int i = 0; i < 8; ++i) {
        u16 v;
        if (bn + bns + i < N) {
          if (B_MODE == 1) v = ((const u16*)Bw)[bbase + i];
          else             v = f2bf(ldi<F32>(Bw, bbase + i));
        } else v = (u16)0;
        Bs[bns + i][bkl] = v;
      }
    }
    __syncthreads();
    int mrow = w * 16 + (lane & 15);
    int kq = (lane >> 4) * 8;
    bf16x8 af = __builtin_bit_cast(bf16x8, *(const u16x8*)&As[mrow][kq]);
#pragma unroll
    for (int j = 0; j < 4; ++j) {
      bf16x8 bfv = __builtin_bit_cast(bf16x8, *(const u16x8*)&Bs[j*16 + (lane & 15)][kq]);
      acc[j] = __builtin_amdgcn_mfma_f32_16x16x32_bf16(af, bfv, acc[j], 0, 0, 0);
    }
    __syncthreads();
  }
  int col0 = lane & 15, rbase = (lane >> 4) * 4;
#pragma unroll
  for (int j = 0; j < 4; ++j) {
#pragma unroll
    for (int r = 0; r < 4; ++r) {
      int row = bm + w * 16 + rbase + r;
      int col = bn + j * 16 + col0;
      if (col < N) {
        size_t idx = (size_t)row * N + col;
        float v = acc[j][r];
        if (BIAS)    v += ldi<F32>(Bias, col);
        if (RES_EXT) v += ldi<F32>(ResE, idx);
        if (RES_F32) v += ResF[idx];
        if (OUT_EXT) sto<F32>(Cext, idx, v);
        else         Cf[idx] = v;
      }
    }
  }
}

// kp = abuf @ bkey (all-internal bf16, fp32 out)
__global__ __launch_bounds__(256) void kp_gemm_kernel(
    const u16* abuf, const u16* bkey, float* kp) {
  gemm_body<1,1,0,0,0,0,false>(blockIdx.x*64, blockIdx.y*64, abuf, nullptr, bkey,
                               kp, nullptr, nullptr, nullptr, nullptr,
                               4096, DKEY_, DM_);
}

// fc2: out_q = outqf + ug @ b2w + b2
template<bool F32>
__device__ void fc2_body(const u16* ug, const u16* b2w, void* out_q,
                         const float* outqf, const void* b2) {
  gemm_body<1,1,1,0,1,1,F32>((blockIdx.x&3)*64, (blockIdx.x>>2)*64, ug, nullptr,
                             b2w, nullptr, out_q, nullptr, outqf, b2,
                             BSZ_*NQ_, DM_, 1024);
}
__global__ __launch_bounds__(256) void fc2_kernel(
    const int* fl, const u16* ug, const u16* b2w, void* out_q,
    const float* outqf, const void* b2) {
  if (*fl) fc2_body<true>(ug, b2w, out_q, outqf, b2);
  else     fc2_body<false>(ug, b2w, out_q, outqf, b2);
}

// ---------------- conv + qproj GEMM (fused, independent blocks) ----------------
template<bool F32>
__device__ void conv_body(const float* kp, const void* cw, const void* cb,
                          float* xact) {
  int row = blockIdx.x;
  int l = row & (LSEQ_ - 1);
  for (int ch = threadIdx.x; ch < DCV_; ch += 256) {
    float acc = ldi<F32>(cb, ch);
#pragma unroll
    for (int k = 0; k < 4; ++k) {
      int ll = l - 3 + k;
      if (ll >= 0)
        acc = fmaf(ldi<F32>(cw, ch*4 + k), kp[(size_t)(row - 3 + k)*DKEY_ + DI_ + ch], acc);
    }
    xact[(size_t)row*DCV_ + ch] = acc * sigmoidf_(acc);
  }
}
__global__ __launch_bounds__(256) void convqp_kernel(
    const int* fl, const float* kp, const void* cw, const void* cb, float* xact,
    const u16* aq, const u16* bq, float* qproj)
{
  int bx = blockIdx.x;
  if (bx < 4096) {
    if (*fl) conv_body<true>(kp, cw, cb, xact);
    else     conv_body<false>(kp, cw, cb, xact);
  } else {
    int i = bx - 4096;   // 32 blocks: M=256 (4 tiles) x N=512 (8 tiles)
    gemm_body<1,1,0,0,0,0,false>((i&3)*64, (i>>2)*64, aq, nullptr, bq,
                                 qproj, nullptr, nullptr, nullptr, nullptr,
                                 BSZ_*NQ_, DI_, DM_);
  }
}

// ---------------- dist MLP -> a, w, c ----------------
template<bool F32>
__device__ void dist_body(const void* anchors, const void* key_pos,
                          const float* kp, const float* xact, const float* wp,
                          float* aw, float* carr) {
  int tid = threadIdx.x;
  int n = tid & 127;
  int idx = blockIdx.x;
  int b = idx >> 10;
  int l = ((idx & 1023) << 1) | (tid >> 7);
  size_t row = (size_t)b * LSEQ_ + l;

  float enc0, enc1, enc2;
  {
    float e[3];
#pragma unroll
    for (int d = 0; d < 3; ++d) {
      float delta = ldi<F32>(anchors, (b*NQ_ + n)*3 + d) - ldi<F32>(key_pos, row*3 + d);
      float s = delta < 0.f ? -1.f : 1.f;
      e[d] = s * log2f(fabsf(delta) * 20.f + 1.f) * (1.f/12.f);
    }
    enc0 = e[0]; enc1 = e[1]; enc2 = e[2];
  }
  float feat[16];
#pragma unroll
  for (int f = 0; f < 16; ++f) feat[f] = 0.f;
  for (int j = 0; j < 64; ++j) {
    float w0 = wp[32 + j*4], w1v = wp[33 + j*4], w2v = wp[34 + j*4], bb = wp[35 + j*4];
    float hj = fmaxf(fmaf(enc0, w0, fmaf(enc1, w1v, fmaf(enc2, w2v, bb))), 0.f);
#pragma unroll
    for (int f = 0; f < 16; ++f) feat[f] = fmaf(hj, wp[288 + j*16 + f], feat[f]);
  }
  float bc0 = 0.f, bc1 = 0.f;
#pragma unroll
  for (int f = 0; f < 16; ++f) {
    bc0 = fmaf(feat[f], wp[1312 + f*2], bc0);
    bc1 = fmaf(feat[f], wp[1313 + f*2], bc1);
  }
  float bb_ = xact[row*DCV_ + DI_];
  float cb_ = xact[row*DCV_ + DI_ + 1];
  float Bs = bc0 + bb_, Cs = bc1 + cb_;
  carr[row*NQ_ + n] = Cs;

  float dtb[8];
#pragma unroll
  for (int h = 0; h < 8; ++h) dtb[h] = 0.f;
#pragma unroll
  for (int f = 0; f < 16; ++f)
#pragma unroll
    for (int h = 0; h < 8; ++h) dtb[h] = fmaf(feat[f], wp[1344 + f*8 + h], dtb[h]);

#pragma unroll
  for (int h = 0; h < 8; ++h) {
    float xln = dtb[h] + kp[row*DKEY_ + (DI_*2 + 2) + h] + wp[8 + h];
    float dtv = softplusf_(xln);
    float a = expf(dtv * wp[h]);
    float wv = dtv * Bs;
    size_t o = (((size_t)(b*NH_ + h)*LSEQ_ + l)*NQ_ + n)*2;
    aw[o] = a;
    aw[o + 1] = wv;
  }
}
__global__ __launch_bounds__(256) void dist_kernel(
    const int* fl, const void* anchors, const void* key_pos, const float* kp,
    const float* xact, const float* wp, float* aw, float* carr) {
  if (*fl) dist_body<true>(anchors, key_pos, kp, xact, wp, aw, carr);
  else     dist_body<false>(anchors, key_pos, kp, xact, wp, aw, carr);
}

// ---------------- scan phase 1 MERGED, full occupancy (8 n-slices x 4 n/wave) ----
// 2048 blocks = 8 blocks/CU = 32 waves/CU (was 1024 = half capacity).
__global__ __launch_bounds__(256) void s1m_kernel(
    const float* __restrict__ aw, const float* __restrict__ xact,
    float* __restrict__ send, float* __restrict__ ptot)
{
  int tid = threadIdx.x;
  int hd = tid & 63;
  int w = __builtin_amdgcn_readfirstlane(tid >> 6);
  int ns = blockIdx.x, q = blockIdx.y, z = blockIdx.z;   // z = b*NH_ + h
  int h = z & 7, b = z >> 3;
  int n0 = __builtin_amdgcn_readfirstlane(ns*16 + w*4);

  float hf[4], hb[4], pr[4];
#pragma unroll
  for (int i = 0; i < 4; ++i) { hf[i] = 0.f; hb[i] = 0.f; pr[i] = 1.f; }

  size_t awbase = (size_t)z * LSEQ_ * (NQ_*2);
  int t = q*CT_;
  for (int s = 0; s < CT_; ++s, ++t) {
    const float* awt = aw + awbase + (size_t)t*(NQ_*2) + n0*2;
    float xv = xact[((size_t)(b*LSEQ_ + t))*DCV_ + (h << 6) + hd];
#pragma unroll
    for (int i = 0; i < 4; ++i) {
      float a = awt[2*i], wv = awt[2*i + 1];
      float wx = wv * xv;
      hf[i] = fmaf(hf[i], a, wx);
      hb[i] = fmaf(pr[i], wx, hb[i]);
      pr[i] *= a;
    }
  }
  size_t cbf = (size_t)((z*2 + 0)*NCHUNK_ + q);
  size_t cbb = (size_t)((z*2 + 1)*NCHUNK_ + (NCHUNK_ - 1 - q));
#pragma unroll
  for (int i = 0; i < 4; ++i) {
    send[cbf*(NQ_*HD_) + (size_t)(n0 + i)*HD_ + hd] = hf[i];
    send[cbb*(NQ_*HD_) + (size_t)(n0 + i)*HD_ + hd] = hb[i];
  }
  if (hd == 0) {
#pragma unroll
    for (int i = 0; i < 4; ++i) {
      ptot[cbf*NQ_ + n0 + i] = pr[i];
      ptot[cbb*NQ_ + n0 + i] = pr[i];
    }
  }
}

// ---------------- scan phase 2 ----------------
__global__ __launch_bounds__(256) void s2_kernel(
    const float* __restrict__ qproj, const float* __restrict__ ptot,
    const float* __restrict__ send, float* __restrict__ h0buf,
    float* __restrict__ hbuf)
{
  int g = blockIdx.x*256 + threadIdx.x;
  int hd = g & 63;
  int n = (g >> 6) & 127;
  int dir = (g >> 13) & 1;
  int h = (g >> 14) & 7;
  int b = g >> 17;
  float hcur = qproj[((size_t)(b*NQ_ + n))*DI_ + h*HD_ + hd];
  size_t base = (size_t)((b*NH_ + h)*2 + dir) * NCHUNK_;
  for (int q = 0; q < NCHUNK_; ++q) {
    size_t cb = base + q;
    h0buf[cb*(NQ_*HD_) + (size_t)n*HD_ + hd] = hcur;
    hcur = fmaf(hcur, ptot[cb*NQ_ + n], send[cb*(NQ_*HD_) + (size_t)n*HD_ + hd]);
  }
  hbuf[((size_t)((b*NH_ + h)*2 + dir))*(NQ_*HD_) + (size_t)n*HD_ + hd] = hcur;
}

// ---------------- scan phase 3 (R9-exact proven optimum) + cast1 ----------
template<bool F32>
__device__ void cast1_part(const void* okw, u16* bok, const void* oqw, u16* boq,
                           const void* w1, u16* b1w, const void* w2, u16* b2w) {
  int i = blockIdx.x - 2048;
  int job = i >> 7, bj = i & 127;
  size_t base = (size_t)bj*256 + threadIdx.x, stride = (size_t)128*256;
  switch (job) {
    case 0: cast_job(F32, okw, nullptr, bok, (size_t)512*256, base, stride); break;
    case 1: cast_job(F32, oqw, nullptr, boq, (size_t)512*256, base, stride); break;
    case 2: cast_job(F32, w1, nullptr, b1w, (size_t)256*2048, base, stride); break;
    default: cast_job(F32, w2, nullptr, b2w, (size_t)1024*256, base, stride); break;
  }
}
__global__ __launch_bounds__(256) void s3cast_kernel(
    const int* fl, const float* __restrict__ aw, const float* __restrict__ carr,
    const float* __restrict__ xact, const float* __restrict__ h0buf,
    float* __restrict__ yacc,
    const void* okw, u16* bok, const void* oqw, u16* boq,
    const void* w1, u16* b1w, const void* w2, u16* b2w)
{
  int bx = blockIdx.x;
  if (bx >= 2048) {
    if (*fl) cast1_part<true>(okw, bok, oqw, boq, w1, b1w, w2, b2w);
    else     cast1_part<false>(okw, bok, oqw, boq, w1, b1w, w2, b2w);
    return;
  }
  int tid = threadIdx.x;
  int hd = tid & 63;
  int w = __builtin_amdgcn_readfirstlane(tid >> 6);
  int ns = bx & 3, q = (bx >> 2) & 15, zz = bx >> 6;
  int dir = zz & 1, h = (zz >> 1) & 7, b = zz >> 4;
  int n0 = __builtin_amdgcn_readfirstlane(ns*32 + w*8);

  float hst[8];
  size_t cb = (size_t)(((b*NH_ + h)*2 + dir)*NCHUNK_ + q);
#pragma unroll
  for (int i = 0; i < 8; ++i)
    hst[i] = h0buf[cb*(NQ_*HD_) + (size_t)(n0 + i)*HD_ + hd];

  __shared__ float ybuf[2][4][64];
  size_t awbase = (size_t)(b*NH_ + h) * LSEQ_ * (NQ_*2);
  int tbase = dir ? (LSEQ_ - 1 - q*CT_) : (q*CT_);
  int tstep = dir ? -1 : 1;
  int t = tbase;
  for (int s = 0; s < CT_; ++s, t += tstep) {
    const float* awt = aw + awbase + (size_t)t*(NQ_*2) + n0*2;
    const float* ct = carr + ((size_t)(b*LSEQ_ + t))*NQ_ + n0;
    float xv = xact[((size_t)(b*LSEQ_ + t))*DCV_ + (h << 6) + hd];
    float ys = 0.f;
#pragma unroll
    for (int i = 0; i < 8; ++i) {
      hst[i] = fmaf(hst[i], awt[2*i], awt[2*i + 1] * xv);
      ys = fmaf(hst[i], ct[i], ys);
    }
    int p = s & 1;
    ybuf[p][w][hd] = ys;
    __syncthreads();
    if (w == 0) {
      float yv = ybuf[p][0][hd] + ybuf[p][1][hd] + ybuf[p][2][hd] + ybuf[p][3][hd];
      atomicAdd(&yacc[((size_t)(b*LSEQ_ + t))*DI_ + (h << 6) + hd], 0.5f * yv);
    }
  }
}

// ---------------- block reduction helper ----------------
__device__ __forceinline__ float block_sum256(float v, float* red) {
#pragma unroll
  for (int off = 32; off; off >>= 1) v += __shfl_xor(v, off, 64);
  int wv = threadIdx.x >> 6;
  if ((threadIdx.x & 63) == 0) red[wv] = v;
  __syncthreads();
  float t = red[0] + red[1] + red[2] + red[3];
  __syncthreads();
  return t;
}

// ---------------- g (gated RMSNorm) + lnq (fused) ----------------
template<bool F32>
__device__ void g_body(const float* yacc, const float* xact, const float* kp,
                       const void* Dv, const void* knw, u16* gbuf) {
  int row = blockIdx.x, tid = threadIdx.x;
  __shared__ float red[4];
  float gg[2];
  float ss = 0.f;
#pragma unroll
  for (int ii = 0; ii < 2; ++ii) {
    int ch = tid + ii*256;
    float yv = yacc[(size_t)row*DI_ + ch];
    float xv = xact[(size_t)row*DCV_ + ch];
    float zv = kp[(size_t)row*DKEY_ + ch];
    float Dh = ldi<F32>(Dv, ch >> 6);
    float yf = yv + 2.f * Dh * xv;
    float g = yf * (zv * sigmoidf_(zv));
    gg[ii] = g;
    ss += g * g;
  }
  float tot = block_sum256(ss, red);
  float r = rsqrtf(tot / (float)DI_ + 1e-5f);
#pragma unroll
  for (int ii = 0; ii < 2; ++ii) {
    int ch = tid + ii*256;
    gbuf[(size_t)row*DI_ + ch] = f2bf(gg[ii] * r * ldi<F32>(knw, ch));
  }
}
template<bool F32>
__device__ void lnq_body(const float* hbuf, const void* qnw, const void* qnb,
                         u16* lnq) {
  int row = blockIdx.x - 4096;
  int b = row >> 7, n = row & 127;
  int tid = threadIdx.x;
  __shared__ float red[4];
  float hv[2];
  float s1 = 0.f, s2 = 0.f;
#pragma unroll
  for (int ii = 0; ii < 2; ++ii) {
    int ch = tid + ii*256;
    int h = ch >> 6, hd = ch & 63;
    size_t base = ((size_t)((b*NH_ + h)*2))*(NQ_*HD_) + (size_t)n*HD_ + hd;
    float v = 0.5f * (hbuf[base] + hbuf[base + (size_t)NQ_*HD_]);
    hv[ii] = v;
    s1 += v;
    s2 += v * v;
  }
  s1 = block_sum256(s1, red);
  s2 = block_sum256(s2, red);
  float mean = s1 / (float)DI_;
  float var = fmaxf(s2 / (float)DI_ - mean * mean, 0.f);
  float rstd = rsqrtf(var + 1e-5f);
#pragma unroll
  for (int ii = 0; ii < 2; ++ii) {
    int ch = tid + ii*256;
    lnq[(size_t)row*DI_ + ch] =
        f2bf((hv[ii] - mean) * rstd * ldi<F32>(qnw, ch) + ldi<F32>(qnb, ch));
  }
}
__global__ __launch_bounds__(256) void glnq_kernel(
    const int* fl, const float* yacc, const float* xact, const float* kp,
    const void* Dv, const void* knw, u16* gbuf,
    const float* hbuf, const void* qnw, const void* qnb, u16* lnq)
{
  if (blockIdx.x < 4096) {
    if (*fl) g_body<true>(yacc, xact, kp, Dv, knw, gbuf);
    else     g_body<false>(yacc, xact, kp, Dv, knw, gbuf);
  } else {
    if (*fl) lnq_body<true>(hbuf, qnw, qnb, lnq);
    else     lnq_body<false>(hbuf, qnw, qnb, lnq);
  }
}

// ---------------- out_feat GEMM + outq GEMM (fused) ----------------
template<bool F32>
__device__ void ofoq_body(const u16* gbuf, const u16* bok, void* out_feat,
                          const void* features, const u16* lnq, const u16* boq,
                          float* outqf, const void* queries) {
  int bx = blockIdx.x;
  if (bx < 256) {   // out_feat: M=4096 (64 tiles) x N=256 (4 tiles), K=512
    gemm_body<1,1,1,1,0,0,F32>((bx>>2)*64, (bx&3)*64, gbuf, nullptr, bok,
                               nullptr, out_feat, features, nullptr, nullptr,
                               4096, DM_, DI_);
  } else {          // outq: M=256 (4) x N=256 (4), K=512
    int i = bx - 256;
    gemm_body<1,1,0,1,0,0,F32>((i&3)*64, (i>>2)*64, lnq, nullptr, boq,
                               outqf, nullptr, queries, nullptr, nullptr,
                               BSZ_*NQ_, DM_, DI_);
  }
}
__global__ __launch_bounds__(256) void ofoq_kernel(
    const int* fl, const u16* gbuf, const u16* bok,
    void* out_feat_f32, void* out_feat_bf16, const void* features,
    const u16* lnq, const u16* boq, float* outqf, const void* queries) {
  if (*fl) ofoq_body<true>(gbuf, bok, out_feat_f32, features, lnq, boq, outqf, queries);
  else     ofoq_body<false>(gbuf, bok, out_feat_bf16, features, lnq, boq, outqf, queries);
}

// ---------------- FFN LN -> lnf ----------------
template<bool F32>
__device__ void lnf_body(const float* outqf, const void* fnw, const void* fnb,
                         u16* lnf) {
  int row = blockIdx.x, tid = threadIdx.x;
  __shared__ float red[4];
  float x = outqf[(size_t)row*DM_ + tid];
  float s1 = block_sum256(x, red);
  float s2 = block_sum256(x * x, red);
  float mean = s1 / (float)DM_;
  float var = fmaxf(s2 / (float)DM_ - mean * mean, 0.f);
  float rstd = rsqrtf(var + 1e-5f);
  lnf[(size_t)row*DM_ + tid] =
      f2bf((x - mean) * rstd * ldi<F32>(fnw, tid) + ldi<F32>(fnb, tid));
}
__global__ __launch_bounds__(256) void lnf_kernel(
    const int* fl, const float* outqf, const void* fnw, const void* fnb, u16* lnf) {
  if (*fl) lnf_body<true>(outqf, fnw, fnb, lnf);
  else     lnf_body<false>(outqf, fnw, fnb, lnf);
}

// ---------------- fc1 + gelu fused: ug = gelu(lnf@W1a + b1a) * (lnf@W1v + b1v) ----
template<bool F32>
__device__ void fc1g_body(const u16* lnf, const u16* b1w, const void* b1, u16* ug) {
  __shared__ u16 As[64][40];
  __shared__ u16 BsA[64][42];
  __shared__ u16 BsV[64][42];
  int tid = threadIdx.x;
  int w = tid >> 6, lane = tid & 63;
  int bm = blockIdx.x * 64, bn = blockIdx.y * 64;   // bn in [0,1024)
  f32x4 accA[4], accV[4];
#pragma unroll
  for (int j = 0; j < 4; ++j) {
    accA[j] = (f32x4){0.f, 0.f, 0.f, 0.f};
    accV[j] = (f32x4){0.f, 0.f, 0.f, 0.f};
  }
  int arow = tid >> 2, aseg = (tid & 3) * 8;
  int bkl = tid >> 3, bns = (tid & 7) * 8;

  for (int k0 = 0; k0 < DM_; k0 += 32) {
    {
      size_t abase = (size_t)(bm + arow) * DM_ + k0 + aseg;
      const u16* pa = lnf + abase;
      u16x8 tv;
#pragma unroll
      for (int i = 0; i < 8; ++i) tv[i] = pa[i];
      *(u16x8*)&As[arow][aseg] = tv;
    }
    {
      size_t bbase = (size_t)(k0 + bkl) * 2048 + bn + bns;
#pragma unroll
      for (int i = 0; i < 8; ++i) {
        BsA[bns + i][bkl] = b1w[bbase + i];
        BsV[bns + i][bkl] = b1w[bbase + 1024 + i];
      }
    }
    __syncthreads();
    int mrow = w * 16 + (lane & 15);
    int kq = (lane >> 4) * 8;
    bf16x8 af = __builtin_bit_cast(bf16x8, *(const u16x8*)&As[mrow][kq]);
#pragma unroll
    for (int j = 0; j < 4; ++j) {
      bf16x8 ba = __builtin_bit_cast(bf16x8, *(const u16x8*)&BsA[j*16 + (lane & 15)][kq]);
      bf16x8 bv = __builtin_bit_cast(bf16x8, *(const u16x8*)&BsV[j*16 + (lane & 15)][kq]);
      accA[j] = __builtin_amdgcn_mfma_f32_16x16x32_bf16(af, ba, accA[j], 0, 0, 0);
      accV[j] = __builtin_amdgcn_mfma_f32_16x16x32_bf16(af, bv, accV[j], 0, 0, 0);
    }
    __syncthreads();
  }
  int col0 = lane & 15, rbase = (lane >> 4) * 4;
#pragma unroll
  for (int j = 0; j < 4; ++j) {
#pragma unroll
    for (int r = 0; r < 4; ++r) {
      int row = bm + w * 16 + rbase + r;
      int col = bn + j * 16 + col0;
      float a = accA[j][r] + ldi<F32>(b1, col);
      float v = accV[j][r] + ldi<F32>(b1, col + 1024);
      float ge = 0.5f * a * (1.f + erff(a * 0.70710678118f));
      ug[(size_t)row*1024 + col] = f2bf(ge * v);
    }
  }
}
__global__ __launch_bounds__(256) void fc1g_kernel(
    const int* fl, const u16* lnf, const u16* b1w, const void* b1, u16* ug) {
  if (*fl) fc1g_body<true>(lnf, b1w, b1, ug);
  else     fc1g_body<false>(lnf, b1w, b1, ug);
}

// ---------------- launch ----------------
extern "C" void kernel_launch(void* const* d_in, const int* in_sizes, int n_in,
                              void* d_out, int out_size, void* d_ws, size_t ws_size,
                              hipStream_t stream) {
  const void* queries        = d_in[0];
  const void* anchors        = d_in[1];
  const void* features       = d_in[2];
  const void* pos_embed      = d_in[3];
  const void* key_pos        = d_in[4];
  const void* query_pos      = d_in[5];
  const void* key_proj_w     = d_in[6];
  const void* key_conv_w     = d_in[7];
  const void* key_conv_b     = d_in[8];
  const void* query_proj_w   = d_in[9];
  const void* dist_w1        = d_in[10];
  const void* dist_b1        = d_in[11];
  const void* dist_w2        = d_in[12];
  const void* bc_proj_w      = d_in[13];
  const void* dt_proj_w      = d_in[14];
  const void* dt_bias        = d_in[15];
  const void* A_log          = d_in[16];
  const void* Dvec           = d_in[17];
  const void* key_norm_w     = d_in[18];
  const void* out_key_proj_w = d_in[19];
  const void* query_norm_w   = d_in[20];
  const void* query_norm_b   = d_in[21];
  const void* out_query_proj_w = d_in[22];
  const void* ffn_norm_w     = d_in[23];
  const void* ffn_norm_b     = d_in[24];
  const void* ffn_fc1_w      = d_in[25];
  const void* ffn_fc1_b      = d_in[26];
  const void* ffn_fc2_w      = d_in[27];
  const void* ffn_fc2_b      = d_in[28];

  if (ws_size < WS_FLOATS * sizeof(float)) return;

  float* ws    = (float*)d_ws;
  float* kp    = ws + OFF_KP;
  float* xact  = ws + OFF_XACT;
  float* aw    = ws + OFF_AW;
  float* carr  = ws + OFF_CARR;
  float* qproj = ws + OFF_QPROJ;
  float* yacc  = ws + OFF_YACC;
  float* send  = ws + OFF_SEND;
  float* ptot  = ws + OFF_PTOT;
  float* h0buf = ws + OFF_H0;
  float* hbuf  = ws + OFF_HB;
  u16*   gbuf  = (u16*)(ws + OFF_GBUF);
  float* outqf = ws + OFF_OUTQF;
  float* wprep = ws + OFF_WPREP;
  int*   flag  = (int*)(wprep + 1536);
  u16*   ugbuf = (u16*)(ws + OFF_UG);
  u16*   lnq   = (u16*)(ws + OFF_LNQ);
  u16*   lnf   = (u16*)(ws + OFF_LNF);
  u16*   abuf  = (u16*)(ws + OFF_ABUF);
  u16*   aq    = (u16*)(ws + OFF_AQ);
  u16*   bkey  = (u16*)(ws + OFF_BKEY);
  u16*   bq    = (u16*)(ws + OFF_BQ);
  u16*   bok   = (u16*)(ws + OFF_BOK);
  u16*   boq   = (u16*)(ws + OFF_BOQ);
  u16*   b1w   = (u16*)(ws + OFF_B1W);
  u16*   b2w   = (u16*)(ws + OFF_B2W);

  void* out_q = d_out;
  void* out_feat_bf16 = (void*)((u16*)d_out + (size_t)BSZ_*NQ_*DM_);
  void* out_feat_f32  = (void*)((float*)d_out + (size_t)BSZ_*NQ_*DM_);

  // 1. setup: yacc zero + cast0 + detect/prep
  setup_kernel<<<1249, 256, 0, stream>>>(
      features, pos_embed, abuf, queries, query_pos, aq,
      key_proj_w, bkey, query_proj_w, bq,
      A_log, dt_bias, dist_w1, dist_b1, dist_w2, bc_proj_w, dt_proj_w, wprep,
      yacc, flag);

  // 2. kp = abuf @ bkey : (4096 x 1034), K=256
  kp_gemm_kernel<<<dim3(64, 17), 256, 0, stream>>>(abuf, bkey, kp);

  // 3. conv + qproj GEMM
  convqp_kernel<<<4096 + 32, 256, 0, stream>>>(
      flag, kp, key_conv_w, key_conv_b, xact, aq, bq, qproj);

  // 4. dist
  dist_kernel<<<BSZ_*LSEQ_/2, 256, 0, stream>>>(flag, anchors, key_pos, kp, xact,
                                                wprep, aw, carr);

  // 5. s1 merged, full occupancy (8 n-slices)
  s1m_kernel<<<dim3(8, NCHUNK_, BSZ_*NH_), 256, 0, stream>>>(aw, xact, send, ptot);

  // 6. s2
  s2_kernel<<<1024, 256, 0, stream>>>(qproj, ptot, send, h0buf, hbuf);

  // 7. s3 (R9-exact) + cast1
  s3cast_kernel<<<2048 + 512, 256, 0, stream>>>(
      flag, aw, carr, xact, h0buf, yacc,
      out_key_proj_w, bok, out_query_proj_w, boq, ffn_fc1_w, b1w, ffn_fc2_w, b2w);

  // 8. g + lnq
  glnq_kernel<<<4096 + 256, 256, 0, stream>>>(
      flag, yacc, xact, kp, Dvec, key_norm_w, gbuf,
      hbuf, query_norm_w, query_norm_b, lnq);

  // 9. out_feat GEMM + outq GEMM
  ofoq_kernel<<<256 + 16, 256, 0, stream>>>(
      flag, gbuf, bok, out_feat_f32, out_feat_bf16, features,
      lnq, boq, outqf, queries);

  // 10. lnf
  lnf_kernel<<<BSZ_*NQ_, 256, 0, stream>>>(flag, outqf, ffn_norm_w, ffn_norm_b, lnf);

  // 11. fc1 + gelu fused: ug = gelu(a)*v
  fc1g_kernel<<<dim3(4, 16), 256, 0, stream>>>(flag, lnf, b1w, ffn_fc1_b, ugbuf);

  // 12. fc2: out_q = outqf + ug @ b2w + b2
  fc2_kernel<<<16, 256, 0, stream>>>(flag, ugbuf, b2w, out_q, outqf, ffn_fc2_b);
}